// Round 2
// baseline (43974.908 us; speedup 1.0000x reference)
//
#include <hip/hip_runtime.h>
#include <hip/hip_bf16.h>

// B=128, T=256, V=50000, D=300, H=300. 256 sample-rows (0..127 = s1, 128..255 = s2).
// Time-chunked (TC=32) xp generation + chunked LSTM scan; peak ws ~231 MB.

typedef unsigned short u16;

__device__ __forceinline__ float us2f(u16 u){
  unsigned int x = ((unsigned int)u) << 16;
  float f; __builtin_memcpy(&f, &x, 4); return f;
}
__device__ __forceinline__ u16 f2us(float f){
  unsigned int x; __builtin_memcpy(&x, &f, 4);
  unsigned int r = x + 0x7fffu + ((x >> 16) & 1u);
  return (u16)(r >> 16);
}
__device__ __forceinline__ float sigmf(float x){ return 1.0f/(1.0f + __expf(-x)); }
__device__ __forceinline__ float tanhfast(float x){ return 1.0f - 2.0f/(__expf(2.0f*x) + 1.0f); }

// ---------------- embedding gather -> p bf16 [65536][300] ----------------
__global__ __launch_bounds__(256) void k_embed(const int* __restrict__ s1, const int* __restrict__ s2,
                                               const float* __restrict__ emb, u16* __restrict__ p)
{
  int id = blockIdx.x*256 + threadIdx.x;          // group-of-4 id
  if (id >= 65536*75) return;
  int row = id / 75;
  int c4 = (id - row*75) * 4;
  int tok = (row < 32768) ? s1[row] : s2[row - 32768];
  float4 v = *(const float4*)(emb + (size_t)tok*300 + c4);
  ushort4 o; o.x=f2us(v.x); o.y=f2us(v.y); o.z=f2us(v.z); o.w=f2us(v.w);
  *(ushort4*)(p + (size_t)row*300 + c4) = o;
}

// ------------- transpose Whh [1200][300] f32 -> WT [300][1200] bf16 -------------
__global__ __launch_bounds__(256) void k_transpose(const float* __restrict__ W, u16* __restrict__ WT)
{
  int id = blockIdx.x*256 + threadIdx.x;
  if (id >= 360000) return;
  int k = id / 1200, n = id - k*1200;
  WT[id] = f2us(W[(size_t)n*300 + k]);
}

// ------------- xp chunk GEMM: xp[m_local][1200] = p[r*256+s][0..300] @ Wih^T + bih + bhh -------------
// m_local = r*32 + tl (8192 rows per chunk), tg = c*32+tl, s = dir ? (tg<L ? L-1-tg : tg) : tg
__global__ __launch_bounds__(256) void k_gemm_xpc(
    const u16* __restrict__ A,            // [65536][300] bf16 (p or pc)
    const float* __restrict__ Bw,         // [1200][300] f32
    const float* __restrict__ b1, const float* __restrict__ b2,
    const int* __restrict__ l1, const int* __restrict__ l2,
    u16* __restrict__ xp,                 // this-dir chunk base: [8192][1200] bf16
    int dir, int c)
{
  __shared__ float As[32][132];
  __shared__ float Bs[32][132];
  const int tid = threadIdx.x;
  const int m0 = blockIdx.y << 7;         // 0..8064
  const int n0 = blockIdx.x << 7;
  const int r0 = m0 >> 5;                 // multiple of 4
  const int La0 = (r0   < 128) ? l1[r0  ] : l2[r0  -128];
  const int La1 = (r0+1 < 128) ? l1[r0+1] : l2[r0+1-128];
  const int La2 = (r0+2 < 128) ? l1[r0+2] : l2[r0+2-128];
  const int La3 = (r0+3 < 128) ? l1[r0+3] : l2[r0+3-128];
  const int tx = tid & 15, ty = tid >> 4;
  float acc[8][8];
#pragma unroll
  for (int i = 0; i < 8; ++i)
#pragma unroll
    for (int j = 0; j < 8; ++j) acc[i][j] = 0.0f;

  for (int kt = 0; kt < 10; ++kt){
    const int k0 = kt << 5;
#pragma unroll
    for (int q = 0; q < 4; ++q){
      const int f4 = tid + (q << 8);
      const int row = f4 >> 3;            // 0..127
      const int c4 = (f4 & 7) << 2;
      const int k = k0 + c4;
      const int ml = m0 + row;
      const int r  = ml >> 5;             // global sample-row 0..255
      const int tl = ml & 31;
      const int tg = (c << 5) + tl;
      const int rsel = r - r0;            // 0..3
      const int L = (rsel & 2) ? ((rsel & 1) ? La3 : La2) : ((rsel & 1) ? La1 : La0);
      const int s = dir ? ((tg < L) ? (L-1-tg) : tg) : tg;
      const u16* ap = A + (size_t)(r*256 + s)*300 + k;
      float vx=0.f, vy=0.f, vz=0.f, vw=0.f;
      if (k + 3 < 300){
        ushort4 t4 = *(const ushort4*)ap;
        vx=us2f(t4.x); vy=us2f(t4.y); vz=us2f(t4.z); vw=us2f(t4.w);
      } else {
        if (k   < 300) vx = us2f(ap[0]);
        if (k+1 < 300) vy = us2f(ap[1]);
        if (k+2 < 300) vz = us2f(ap[2]);
      }
      As[c4  ][row] = vx; As[c4+1][row] = vy; As[c4+2][row] = vz; As[c4+3][row] = vw;
      const int n = n0 + row;
      float wx=0.f, wy=0.f, wz=0.f, ww=0.f;
      if (n < 1200){
        const float* bp = Bw + (size_t)n*300 + k;
        if (k + 3 < 300){ float4 t = *(const float4*)bp; wx=t.x; wy=t.y; wz=t.z; ww=t.w; }
        else {
          if (k   < 300) wx = bp[0];
          if (k+1 < 300) wy = bp[1];
          if (k+2 < 300) wz = bp[2];
        }
      }
      Bs[c4  ][row] = wx; Bs[c4+1][row] = wy; Bs[c4+2][row] = wz; Bs[c4+3][row] = ww;
    }
    __syncthreads();
#pragma unroll 8
    for (int kk = 0; kk < 32; ++kk){
      float4 a0 = *(const float4*)&As[kk][ty*8];
      float4 a1 = *(const float4*)&As[kk][ty*8+4];
      float4 c0 = *(const float4*)&Bs[kk][tx*8];
      float4 c1 = *(const float4*)&Bs[kk][tx*8+4];
      float av[8] = {a0.x,a0.y,a0.z,a0.w,a1.x,a1.y,a1.z,a1.w};
      float bv[8] = {c0.x,c0.y,c0.z,c0.w,c1.x,c1.y,c1.z,c1.w};
#pragma unroll
      for (int i = 0; i < 8; ++i)
#pragma unroll
        for (int j = 0; j < 8; ++j)
          acc[i][j] = fmaf(av[i], bv[j], acc[i][j]);
    }
    __syncthreads();
  }
#pragma unroll
  for (int i = 0; i < 8; ++i){
    const int m = m0 + ty*8 + i;
#pragma unroll
    for (int j = 0; j < 8; ++j){
      const int n = n0 + tx*8 + j;
      if (n < 1200)
        xp[(size_t)m*1200 + n] = f2us(acc[i][j] + b1[n] + b2[n]);
    }
  }
}

// ------------- LSTM scan over one 32-step chunk, both dirs (blockIdx>>7), 2 rows/WG -------------
__global__ __launch_bounds__(256) void k_scan_chunk(
    const u16* __restrict__ xp,           // [2][8192][1200] bf16
    const u16* __restrict__ wTf, const u16* __restrict__ wTb,
    const int* __restrict__ l1, const int* __restrict__ l2,
    u16* __restrict__ u,                  // [65536][600] bf16 out
    float* __restrict__ hc,               // h [2][256][300] then c [2][256][300]
    int c)
{
  const int g = blockIdx.x;
  const int dir = g >> 7;
  const int pr = g & 127;
  const int r0 = pr*2, r1 = r0+1;
  const int La = (r0 < 128) ? l1[r0] : l2[r0-128];
  const int Lb = (r1 < 128) ? l1[r1] : l2[r1-128];
  const u16* xpd = xp + (size_t)dir*9830400;
  const u16* wT = dir ? wTb : wTf;
  float* hcH = hc;
  float* hcC = hc + 153600;
  __shared__ float hs[2][304];
  __shared__ float cs[2][304];
  __shared__ float gs[2][1200];
  const int tid = threadIdx.x;
  for (int i = tid; i < 300; i += 256){
    if (c == 0){
      hs[0][i]=0.f; hs[1][i]=0.f; cs[0][i]=0.f; cs[1][i]=0.f;
    } else {
      hs[0][i]=hcH[(size_t)(dir*256+r0)*300+i]; hs[1][i]=hcH[(size_t)(dir*256+r1)*300+i];
      cs[0][i]=hcC[(size_t)(dir*256+r0)*300+i]; cs[1][i]=hcC[(size_t)(dir*256+r1)*300+i];
    }
  }
  __syncthreads();
  const int Lm = (La > Lb) ? La : Lb;
  const int t0 = c << 5;
  int nt = Lm - t0; if (nt > 32) nt = 32;
  const int nv = (tid < 176) ? 5 : 4;
  for (int tl = 0; tl < nt; ++tl){
    const int tg = t0 + tl;
    const bool a0 = tg < La, a1 = tg < Lb;
    float acc0[5], acc1[5];
#pragma unroll
    for (int j = 0; j < 5; ++j){
      const int n = tid + (j << 8);
      const bool ok = (j < nv);
      acc0[j] = (ok && a0) ? us2f(xpd[(size_t)(r0*32 + tl)*1200 + n]) : 0.0f;
      acc1[j] = (ok && a1) ? us2f(xpd[(size_t)(r1*32 + tl)*1200 + n]) : 0.0f;
    }
    const u16* w0 = wT + tid;
#pragma unroll 4
    for (int kk = 0; kk < 300; ++kk){
      const float h0 = hs[0][kk], h1 = hs[1][kk];
      const u16* wr = w0 + kk*1200;
#pragma unroll
      for (int j = 0; j < 5; ++j){
        if (j < nv){
          const float wv = us2f(wr[j << 8]);
          acc0[j] = fmaf(wv, h0, acc0[j]);
          acc1[j] = fmaf(wv, h1, acc1[j]);
        }
      }
    }
#pragma unroll
    for (int j = 0; j < 5; ++j){
      if (j < nv){
        const int n = tid + (j << 8);
        gs[0][n] = acc0[j];
        gs[1][n] = acc1[j];
      }
    }
    __syncthreads();
#pragma unroll
    for (int jj = 0; jj < 3; ++jj){
      const int idx = tid + (jj << 8);
      if (idx < 600){
        const int sH = (idx >= 300) ? 1 : 0;
        const int d = idx - sH*300;
        const bool act = sH ? a1 : a0;
        if (act){
          const float gi = gs[sH][d], gf = gs[sH][300+d], gg = gs[sH][600+d], go = gs[sH][900+d];
          const float cn = sigmf(gf)*cs[sH][d] + sigmf(gi)*tanhfast(gg);
          const float hn = sigmf(go)*tanhfast(cn);
          cs[sH][d] = cn; hs[sH][d] = hn;
          const int rr = sH ? r1 : r0;
          const int Lr = sH ? Lb : La;
          const int wpos = dir ? (Lr-1-tg) : tg;
          u[(size_t)(rr*256 + wpos)*600 + dir*300 + d] = f2us(hn);
        }
      }
    }
    __syncthreads();
  }
  for (int i = tid; i < 300; i += 256){
    hcH[(size_t)(dir*256+r0)*300+i] = hs[0][i]; hcH[(size_t)(dir*256+r1)*300+i] = hs[1][i];
    hcC[(size_t)(dir*256+r0)*300+i] = cs[0][i]; hcC[(size_t)(dir*256+r1)*300+i] = cs[1][i];
  }
}

// ------------- batched S = u1 @ u2^T per b (u bf16): [256,600]x[256,600]^T -> f32 -------------
__global__ __launch_bounds__(256) void k_gemm_s(const u16* __restrict__ U, float* __restrict__ S)
{
  __shared__ float As[32][132];
  __shared__ float Bs[32][132];
  const int tid = threadIdx.x;
  const int bz = blockIdx.z;
  const u16* A = U + (size_t)bz*153600;
  const u16* B = U + (size_t)(128+bz)*153600;
  float* C = S + (size_t)bz*65536;
  const int m0 = blockIdx.y << 7;
  const int n0 = blockIdx.x << 7;
  const int tx = tid & 15, ty = tid >> 4;
  float acc[8][8];
#pragma unroll
  for (int i = 0; i < 8; ++i)
#pragma unroll
    for (int j = 0; j < 8; ++j) acc[i][j] = 0.0f;

  for (int kt = 0; kt < 19; ++kt){
    const int k0 = kt << 5;
#pragma unroll
    for (int q = 0; q < 4; ++q){
      const int f4 = tid + (q << 8);
      const int row = f4 >> 3;
      const int c4 = (f4 & 7) << 2;
      const int k = k0 + c4;
      float vx=0.f, vy=0.f, vz=0.f, vw=0.f;
      const u16* ap = A + (size_t)(m0 + row)*600 + k;
      if (k + 3 < 600){
        ushort4 t4 = *(const ushort4*)ap;
        vx=us2f(t4.x); vy=us2f(t4.y); vz=us2f(t4.z); vw=us2f(t4.w);
      } else {
        if (k   < 600) vx = us2f(ap[0]);
        if (k+1 < 600) vy = us2f(ap[1]);
        if (k+2 < 600) vz = us2f(ap[2]);
      }
      As[c4  ][row] = vx; As[c4+1][row] = vy; As[c4+2][row] = vz; As[c4+3][row] = vw;
      float wx=0.f, wy=0.f, wz=0.f, ww=0.f;
      const u16* bp = B + (size_t)(n0 + row)*600 + k;
      if (k + 3 < 600){
        ushort4 t4 = *(const ushort4*)bp;
        wx=us2f(t4.x); wy=us2f(t4.y); wz=us2f(t4.z); ww=us2f(t4.w);
      } else {
        if (k   < 600) wx = us2f(bp[0]);
        if (k+1 < 600) wy = us2f(bp[1]);
        if (k+2 < 600) wz = us2f(bp[2]);
      }
      Bs[c4  ][row] = wx; Bs[c4+1][row] = wy; Bs[c4+2][row] = wz; Bs[c4+3][row] = ww;
    }
    __syncthreads();
#pragma unroll 8
    for (int kk = 0; kk < 32; ++kk){
      float4 a0 = *(const float4*)&As[kk][ty*8];
      float4 a1 = *(const float4*)&As[kk][ty*8+4];
      float4 c0 = *(const float4*)&Bs[kk][tx*8];
      float4 c1 = *(const float4*)&Bs[kk][tx*8+4];
      float av[8] = {a0.x,a0.y,a0.z,a0.w,a1.x,a1.y,a1.z,a1.w};
      float bv[8] = {c0.x,c0.y,c0.z,c0.w,c1.x,c1.y,c1.z,c1.w};
#pragma unroll
      for (int i = 0; i < 8; ++i)
#pragma unroll
        for (int j = 0; j < 8; ++j)
          acc[i][j] = fmaf(av[i], bv[j], acc[i][j]);
    }
    __syncthreads();
  }
#pragma unroll
  for (int i = 0; i < 8; ++i)
#pragma unroll
    for (int j = 0; j < 8; ++j)
      C[(size_t)(m0 + ty*8 + i)*256 + n0 + tx*8 + j] = acc[i][j];
}

// ------------- softmax stats -------------
__global__ __launch_bounds__(256) void k_row_stats(const float* __restrict__ S, const int* __restrict__ l2,
                                                   float* __restrict__ rmax, float* __restrict__ rinv)
{
  const int wid = threadIdx.x >> 6, lane = threadIdx.x & 63;
  const int row = blockIdx.x*4 + wid;           // b*256 + i
  const int b = row >> 8;
  const int L2b = l2[b];
  float4 v = *(const float4*)(S + (size_t)row*256 + lane*4);
  const int j = lane*4;
  float m = -INFINITY;
  if (j   < L2b) m = fmaxf(m, v.x);
  if (j+1 < L2b) m = fmaxf(m, v.y);
  if (j+2 < L2b) m = fmaxf(m, v.z);
  if (j+3 < L2b) m = fmaxf(m, v.w);
  for (int off = 32; off; off >>= 1) m = fmaxf(m, __shfl_xor(m, off));
  float s = 0.f;
  if (j   < L2b) s += __expf(v.x - m);
  if (j+1 < L2b) s += __expf(v.y - m);
  if (j+2 < L2b) s += __expf(v.z - m);
  if (j+3 < L2b) s += __expf(v.w - m);
  for (int off = 32; off; off >>= 1) s += __shfl_xor(s, off);
  if (lane == 0){ rmax[row] = m; rinv[row] = 1.0f/s; }
}

__global__ __launch_bounds__(256) void k_col_stats(const float* __restrict__ S, const int* __restrict__ l1,
                                                   float* __restrict__ cmax, float* __restrict__ cinv)
{
  const int b = blockIdx.x;
  const int j = threadIdx.x;
  const int L1b = l1[b];
  const float* Sb = S + (size_t)b*65536;
  float m = -INFINITY;
  for (int i = 0; i < L1b; ++i) m = fmaxf(m, Sb[(size_t)i*256 + j]);
  float s = 0.f;
  for (int i = 0; i < L1b; ++i) s += __expf(Sb[(size_t)i*256 + j] - m);
  cmax[b*256 + j] = m;
  cinv[b*256 + j] = 1.0f/s;
}

// ------------- A1 = softmax_rows(S) @ u2 -> att bf16 -------------
__global__ __launch_bounds__(256) void k_av_row(
    const float* __restrict__ S, const u16* __restrict__ U,
    const int* __restrict__ l1, const int* __restrict__ l2,
    const float* __restrict__ rmax, const float* __restrict__ rinv,
    u16* __restrict__ ATT)
{
  __shared__ float Ps[32][68];  // [j][i]
  __shared__ float Us[32][68];  // [j][d]
  const int tid = threadIdx.x;
  const int b = blockIdx.z;
  const int i0 = blockIdx.y << 6;
  const int d0 = blockIdx.x << 6;
  const int L1b = l1[b], L2b = l2[b];
  const float* Sb = S + (size_t)b*65536;
  const u16* u2 = U + (size_t)(128+b)*153600;
  const int tx = tid & 15, ty = tid >> 4;
  float acc[4][4];
#pragma unroll
  for (int i = 0; i < 4; ++i)
#pragma unroll
    for (int j = 0; j < 4; ++j) acc[i][j] = 0.0f;

  for (int kt = 0; kt < 8; ++kt){
    const int j0 = kt << 5;
#pragma unroll
    for (int q = 0; q < 2; ++q){
      const int f4 = tid + (q << 8);
      {
        const int row = f4 >> 3;            // i 0..63
        const int c4 = (f4 & 7) << 2;       // j
        const int i = i0 + row;
        float4 s4 = *(const float4*)(Sb + (size_t)i*256 + j0 + c4);
        const float rm = rmax[(b<<8) + i];
        const float ri = rinv[(b<<8) + i];
        const int jb = j0 + c4;
        Ps[c4  ][row] = (jb   < L2b) ? __expf(s4.x - rm)*ri : 0.0f;
        Ps[c4+1][row] = (jb+1 < L2b) ? __expf(s4.y - rm)*ri : 0.0f;
        Ps[c4+2][row] = (jb+2 < L2b) ? __expf(s4.z - rm)*ri : 0.0f;
        Ps[c4+3][row] = (jb+3 < L2b) ? __expf(s4.w - rm)*ri : 0.0f;
      }
      {
        const int row = f4 >> 4;            // j 0..31
        const int c4 = (f4 & 15) << 2;      // d
        const int d = d0 + c4;
        float4 v = make_float4(0.f,0.f,0.f,0.f);
        if (j0 + row < L2b){
          const u16* up = u2 + (size_t)(j0+row)*600 + d;
          if (d + 3 < 600){
            ushort4 t4 = *(const ushort4*)up;
            v.x=us2f(t4.x); v.y=us2f(t4.y); v.z=us2f(t4.z); v.w=us2f(t4.w);
          } else {
            if (d   < 600) v.x = us2f(up[0]);
            if (d+1 < 600) v.y = us2f(up[1]);
            if (d+2 < 600) v.z = us2f(up[2]);
          }
        }
        *(float4*)&Us[row][c4] = v;
      }
    }
    __syncthreads();
#pragma unroll
    for (int kk = 0; kk < 32; ++kk){
      float4 a = *(const float4*)&Ps[kk][ty<<2];
      float4 bb = *(const float4*)&Us[kk][tx<<2];
      float av[4] = {a.x,a.y,a.z,a.w};
      float bv[4] = {bb.x,bb.y,bb.z,bb.w};
#pragma unroll
      for (int ii = 0; ii < 4; ++ii)
#pragma unroll
        for (int jj = 0; jj < 4; ++jj)
          acc[ii][jj] = fmaf(av[ii], bv[jj], acc[ii][jj]);
    }
    __syncthreads();
  }
#pragma unroll
  for (int ii = 0; ii < 4; ++ii){
    const int i = i0 + (ty<<2) + ii;
#pragma unroll
    for (int jj = 0; jj < 4; ++jj){
      const int d = d0 + (tx<<2) + jj;
      if (d < 600)
        ATT[(size_t)b*153600 + (size_t)i*600 + d] = f2us((i < L1b) ? acc[ii][jj] : 0.0f);
    }
  }
}

// ------------- A2 = softmax_cols(S)^T @ u1 -> att bf16 -------------
__global__ __launch_bounds__(256) void k_av_col(
    const float* __restrict__ S, const u16* __restrict__ U,
    const int* __restrict__ l1, const int* __restrict__ l2,
    const float* __restrict__ cmax, const float* __restrict__ cinv,
    u16* __restrict__ ATT)
{
  __shared__ float Ps[32][68];  // [i][j]
  __shared__ float Us[32][68];  // [i][d]
  const int tid = threadIdx.x;
  const int b = blockIdx.z;
  const int j0v = blockIdx.y << 6;
  const int d0 = blockIdx.x << 6;
  const int L1b = l1[b], L2b = l2[b];
  const float* Sb = S + (size_t)b*65536;
  const u16* u1 = U + (size_t)b*153600;
  const int tx = tid & 15, ty = tid >> 4;
  float acc[4][4];
#pragma unroll
  for (int i = 0; i < 4; ++i)
#pragma unroll
    for (int j = 0; j < 4; ++j) acc[i][j] = 0.0f;

  for (int kt = 0; kt < 8; ++kt){
    const int i0k = kt << 5;
#pragma unroll
    for (int q = 0; q < 2; ++q){
      const int f4 = tid + (q << 8);
      const int row = f4 >> 4;              // i 0..31
      const int c4 = (f4 & 15) << 2;        // j or d
      {
        const int i = i0k + row;
        const int j = j0v + c4;
        float4 s4 = *(const float4*)(Sb + (size_t)i*256 + j);
        const bool iok = i < L1b;
        Ps[row][c4  ] = iok ? __expf(s4.x - cmax[(b<<8)+j  ])*cinv[(b<<8)+j  ] : 0.0f;
        Ps[row][c4+1] = iok ? __expf(s4.y - cmax[(b<<8)+j+1])*cinv[(b<<8)+j+1] : 0.0f;
        Ps[row][c4+2] = iok ? __expf(s4.z - cmax[(b<<8)+j+2])*cinv[(b<<8)+j+2] : 0.0f;
        Ps[row][c4+3] = iok ? __expf(s4.w - cmax[(b<<8)+j+3])*cinv[(b<<8)+j+3] : 0.0f;
      }
      {
        const int d = d0 + c4;
        float4 v = make_float4(0.f,0.f,0.f,0.f);
        if (i0k + row < L1b){
          const u16* up = u1 + (size_t)(i0k+row)*600 + d;
          if (d + 3 < 600){
            ushort4 t4 = *(const ushort4*)up;
            v.x=us2f(t4.x); v.y=us2f(t4.y); v.z=us2f(t4.z); v.w=us2f(t4.w);
          } else {
            if (d   < 600) v.x = us2f(up[0]);
            if (d+1 < 600) v.y = us2f(up[1]);
            if (d+2 < 600) v.z = us2f(up[2]);
          }
        }
        *(float4*)&Us[row][c4] = v;
      }
    }
    __syncthreads();
#pragma unroll
    for (int kk = 0; kk < 32; ++kk){
      float4 a = *(const float4*)&Ps[kk][ty<<2];
      float4 bb = *(const float4*)&Us[kk][tx<<2];
      float av[4] = {a.x,a.y,a.z,a.w};
      float bv[4] = {bb.x,bb.y,bb.z,bb.w};
#pragma unroll
      for (int ii = 0; ii < 4; ++ii)
#pragma unroll
        for (int jj = 0; jj < 4; ++jj)
          acc[ii][jj] = fmaf(av[ii], bv[jj], acc[ii][jj]);
    }
    __syncthreads();
  }
#pragma unroll
  for (int ii = 0; ii < 4; ++ii){
    const int j = j0v + (ty<<2) + ii;
#pragma unroll
    for (int jj = 0; jj < 4; ++jj){
      const int d = d0 + (tx<<2) + jj;
      if (d < 600)
        ATT[(size_t)(128+b)*153600 + (size_t)j*600 + d] = f2us((j < L2b) ? acc[ii][jj] : 0.0f);
    }
  }
}

// ------------- fused projection: pc = relu([u,A,u-A,u*A] @ projW^T + projB) (bf16 in/out) -------------
__global__ __launch_bounds__(256) void k_gemm_proj(
    const u16* __restrict__ U, const u16* __restrict__ ATT,
    const float* __restrict__ Bw, const float* __restrict__ bias,
    u16* __restrict__ C)
{
  __shared__ float As[32][132];
  __shared__ float Bs[32][132];
  const int tid = threadIdx.x;
  const int m0 = blockIdx.y << 7;
  const int n0 = blockIdx.x << 7;
  const int tx = tid & 15, ty = tid >> 4;
  float acc[8][8];
#pragma unroll
  for (int i = 0; i < 8; ++i)
#pragma unroll
    for (int j = 0; j < 8; ++j) acc[i][j] = 0.0f;

  for (int kt = 0; kt < 75; ++kt){
    const int k0 = kt << 5;
#pragma unroll
    for (int q = 0; q < 4; ++q){
      const int f4 = tid + (q << 8);
      const int row = f4 >> 3;
      const int c4 = (f4 & 7) << 2;
      const int k = k0 + c4;
      const int seg = k / 600;
      const int kk2 = k - seg*600;
      const size_t base = (size_t)(m0 + row)*600 + kk2;
      ushort4 uv4 = *(const ushort4*)(U + base);
      ushort4 av4 = *(const ushort4*)(ATT + base);
      float ux=us2f(uv4.x), uy=us2f(uv4.y), uz=us2f(uv4.z), uw=us2f(uv4.w);
      float ax=us2f(av4.x), ay=us2f(av4.y), az=us2f(av4.z), aw=us2f(av4.w);
      float vx, vy, vz, vw;
      if (seg == 0){ vx=ux; vy=uy; vz=uz; vw=uw; }
      else if (seg == 1){ vx=ax; vy=ay; vz=az; vw=aw; }
      else if (seg == 2){ vx=ux-ax; vy=uy-ay; vz=uz-az; vw=uw-aw; }
      else { vx=ux*ax; vy=uy*ay; vz=uz*az; vw=uw*aw; }
      As[c4  ][row] = vx; As[c4+1][row] = vy; As[c4+2][row] = vz; As[c4+3][row] = vw;
      const int n = n0 + row;
      float wx=0.f, wy=0.f, wz=0.f, ww=0.f;
      if (n < 300){
        float4 t = *(const float4*)(Bw + (size_t)n*2400 + k);
        wx=t.x; wy=t.y; wz=t.z; ww=t.w;
      }
      Bs[c4  ][row] = wx; Bs[c4+1][row] = wy; Bs[c4+2][row] = wz; Bs[c4+3][row] = ww;
    }
    __syncthreads();
#pragma unroll 8
    for (int kk = 0; kk < 32; ++kk){
      float4 a0 = *(const float4*)&As[kk][ty*8];
      float4 a1 = *(const float4*)&As[kk][ty*8+4];
      float4 c0 = *(const float4*)&Bs[kk][tx*8];
      float4 c1 = *(const float4*)&Bs[kk][tx*8+4];
      float av2[8] = {a0.x,a0.y,a0.z,a0.w,a1.x,a1.y,a1.z,a1.w};
      float bv2[8] = {c0.x,c0.y,c0.z,c0.w,c1.x,c1.y,c1.z,c1.w};
#pragma unroll
      for (int i = 0; i < 8; ++i)
#pragma unroll
        for (int j = 0; j < 8; ++j)
          acc[i][j] = fmaf(av2[i], bv2[j], acc[i][j]);
    }
    __syncthreads();
  }
#pragma unroll
  for (int i = 0; i < 8; ++i){
    const int m = m0 + ty*8 + i;
#pragma unroll
    for (int j = 0; j < 8; ++j){
      const int n = n0 + tx*8 + j;
      if (n < 300)
        C[(size_t)m*300 + n] = f2us(fmaxf(acc[i][j] + bias[n], 0.0f));
    }
  }
}

// ------------- masked max over time + feature build (y bf16) -------------
__global__ __launch_bounds__(256) void k_maxfeat(const u16* __restrict__ y,
                                                 const int* __restrict__ l1, const int* __restrict__ l2,
                                                 float* __restrict__ feat)
{
  const int b = blockIdx.x;
  const int La = l1[b], Lb = l2[b];
  for (int c = threadIdx.x; c < 600; c += 256){
    float m1 = -INFINITY, m2 = -INFINITY;
    const u16* y1 = y + (size_t)b*153600 + c;
    for (int t = 0; t < La; ++t) m1 = fmaxf(m1, us2f(y1[(size_t)t*600]));
    const u16* y2 = y + (size_t)(128+b)*153600 + c;
    for (int t = 0; t < Lb; ++t) m2 = fmaxf(m2, us2f(y2[(size_t)t*600]));
    feat[(size_t)b*2400 + c]        = m1;
    feat[(size_t)b*2400 + 600 + c]  = m2;
    feat[(size_t)b*2400 + 1200 + c] = fabsf(m1 - m2);
    feat[(size_t)b*2400 + 1800 + c] = m1*m2;
  }
}

// ------------- per-row MLP: h = relu(feat @ mlpW^T + mlpB) -------------
__global__ __launch_bounds__(256) void k_rowgemm(const float* __restrict__ feat, const float* __restrict__ W,
                                                 const float* __restrict__ bias, float* __restrict__ out)
{
  const int b = blockIdx.x;
  __shared__ float ff[2400];
  for (int i = threadIdx.x; i < 2400; i += 256) ff[i] = feat[(size_t)b*2400 + i];
  __syncthreads();
  for (int n = threadIdx.x; n < 300; n += 256){
    const float* w = W + (size_t)n*2400;
    float acc = bias[n];
    for (int k = 0; k < 2400; k += 4){
      float4 wv = *(const float4*)(w + k);
      acc += ff[k]*wv.x + ff[k+1]*wv.y + ff[k+2]*wv.z + ff[k+3]*wv.w;
    }
    out[(size_t)b*300 + n] = fmaxf(acc, 0.0f);
  }
}

// ------------- final: out = h @ smW^T + smB -------------
__global__ __launch_bounds__(192) void k_final(const float* __restrict__ h, const float* __restrict__ smW,
                                               const float* __restrict__ smB, float* __restrict__ out)
{
  const int b = blockIdx.x;
  const int n = threadIdx.x >> 6, lane = threadIdx.x & 63;
  float acc = 0.f;
  for (int k = lane; k < 300; k += 64) acc += h[(size_t)b*300 + k]*smW[(size_t)n*300 + k];
  for (int off = 32; off; off >>= 1) acc += __shfl_xor(acc, off);
  if (lane == 0) out[b*3 + n] = acc + smB[n];
}

extern "C" void kernel_launch(void* const* d_in, const int* in_sizes, int n_in,
                              void* d_out, int out_size, void* d_ws, size_t ws_size,
                              hipStream_t stream)
{
  (void)in_sizes; (void)n_in; (void)out_size;
  // Workspace layout (bytes), peak ~231 MB:
  static const size_t OFF_P  = 0;            // p bf16 [65536][300]          39,321,600
  static const size_t OFF_B  = 39321600;     // xp1 [2][8192][1200] bf16 (39,321,600) -> S f32 [128][256][256] -> pc bf16
  static const size_t OFF_U  = 78643200;     // u bf16 [65536][600]          78,643,200  -> y
  static const size_t OFF_D  = 157286400;    // att bf16 [65536][600]        78,643,200  -> xp2
  static const size_t OFF_WT = 235929600;    // wT bf16 4 x 360000            2,880,000
  static const size_t OFF_ST = 238809600;    // stats f32 4 x 32768             524,288
  static const size_t OFF_FE = 239333888;    // feat f32 [128][2400]          1,228,800
  static const size_t OFF_HM = 240562688;    // hml f32 [128][300]              153,600
  static const size_t OFF_HC = 240716288;    // h,c f32 [2][2][256][300]      1,228,800
  static const size_t WS_NEEDED = 241945088;
  if (ws_size < WS_NEEDED) return;           // diagnostic guard: fail cleanly (absmax), not a fault

  const int* s1 = (const int*)d_in[0];
  const int* l1 = (const int*)d_in[1];
  const int* s2 = (const int*)d_in[2];
  const int* l2 = (const int*)d_in[3];
  const float* emb    = (const float*)d_in[4];
  const float* w1f_ih = (const float*)d_in[5];
  const float* w1f_hh = (const float*)d_in[6];
  const float* b1f_ih = (const float*)d_in[7];
  const float* b1f_hh = (const float*)d_in[8];
  const float* w1b_ih = (const float*)d_in[9];
  const float* w1b_hh = (const float*)d_in[10];
  const float* b1b_ih = (const float*)d_in[11];
  const float* b1b_hh = (const float*)d_in[12];
  const float* w2f_ih = (const float*)d_in[13];
  const float* w2f_hh = (const float*)d_in[14];
  const float* b2f_ih = (const float*)d_in[15];
  const float* b2f_hh = (const float*)d_in[16];
  const float* w2b_ih = (const float*)d_in[17];
  const float* w2b_hh = (const float*)d_in[18];
  const float* b2b_ih = (const float*)d_in[19];
  const float* b2b_hh = (const float*)d_in[20];
  const float* projW  = (const float*)d_in[21];
  const float* projB  = (const float*)d_in[22];
  const float* mlpW   = (const float*)d_in[23];
  const float* mlpB   = (const float*)d_in[24];
  const float* smW    = (const float*)d_in[25];
  const float* smB    = (const float*)d_in[26];

  char* ws = (char*)d_ws;
  u16*   p    = (u16*)(ws + OFF_P);
  u16*   xp1  = (u16*)(ws + OFF_B);
  float* Smat = (float*)(ws + OFF_B);
  u16*   pc   = (u16*)(ws + OFF_B);
  u16*   uu   = (u16*)(ws + OFF_U);
  u16*   att  = (u16*)(ws + OFF_D);
  u16*   xp2  = (u16*)(ws + OFF_D);
  u16*   wT   = (u16*)(ws + OFF_WT);
  float* st   = (float*)(ws + OFF_ST);
  float* feat = (float*)(ws + OFF_FE);
  float* hml  = (float*)(ws + OFF_HM);
  float* hc   = (float*)(ws + OFF_HC);

  k_embed<<<19200, 256, 0, stream>>>(s1, s2, emb, p);
  k_transpose<<<1407, 256, 0, stream>>>(w1f_hh, wT);
  k_transpose<<<1407, 256, 0, stream>>>(w1b_hh, wT + 360000);
  k_transpose<<<1407, 256, 0, stream>>>(w2f_hh, wT + 720000);
  k_transpose<<<1407, 256, 0, stream>>>(w2b_hh, wT + 1080000);

  const dim3 gxp(10, 64, 1);
  for (int c = 0; c < 8; ++c){
    k_gemm_xpc<<<gxp, 256, 0, stream>>>(p, w1f_ih, b1f_ih, b1f_hh, l1, l2, xp1,           0, c);
    k_gemm_xpc<<<gxp, 256, 0, stream>>>(p, w1b_ih, b1b_ih, b1b_hh, l1, l2, xp1 + 9830400, 1, c);
    k_scan_chunk<<<256, 256, 0, stream>>>(xp1, wT, wT + 360000, l1, l2, uu, hc, c);
  }

  k_gemm_s<<<dim3(2,2,128), 256, 0, stream>>>(uu, Smat);
  k_row_stats<<<8192, 256, 0, stream>>>(Smat, l2, st, st + 32768);
  k_col_stats<<<128, 256, 0, stream>>>(Smat, l1, st + 65536, st + 98304);
  k_av_row<<<dim3(10,4,128), 256, 0, stream>>>(Smat, uu, l1, l2, st, st + 32768, att);
  k_av_col<<<dim3(10,4,128), 256, 0, stream>>>(Smat, uu, l1, l2, st + 65536, st + 98304, att);

  k_gemm_proj<<<dim3(3,512,1), 256, 0, stream>>>(uu, att, projW, projB, pc);

  for (int c = 0; c < 8; ++c){
    k_gemm_xpc<<<gxp, 256, 0, stream>>>(pc, w2f_ih, b2f_ih, b2f_hh, l1, l2, xp2,           0, c);
    k_gemm_xpc<<<gxp, 256, 0, stream>>>(pc, w2b_ih, b2b_ih, b2b_hh, l1, l2, xp2 + 9830400, 1, c);
    k_scan_chunk<<<256, 256, 0, stream>>>(xp2, wT + 720000, wT + 1080000, l1, l2, uu, hc, c);
  }

  k_maxfeat<<<128, 256, 0, stream>>>(uu, l1, l2, feat);
  k_rowgemm<<<128, 256, 0, stream>>>(feat, mlpW, mlpB, hml);
  k_final<<<128, 192, 0, stream>>>(hml, smW, smB, (float*)d_out);
}

// Round 3
// 14940.622 us; speedup vs baseline: 2.9433x; 2.9433x over previous
//
#include <hip/hip_runtime.h>
#include <hip/hip_bf16.h>

// B=128, T=256, V=50000, D=300, H=300. 256 sample-rows (0..127 = s1, 128..255 = s2).
// MFMA bf16 pipeline; time-chunked (TC=32) xp + streaming-weight MFMA scan.

typedef unsigned short u16;
typedef float fx4 __attribute__((ext_vector_type(4)));
typedef short s16x8 __attribute__((ext_vector_type(8)));

__device__ __forceinline__ float us2f(u16 u){
  unsigned int x = ((unsigned int)u) << 16;
  float f; __builtin_memcpy(&f, &x, 4); return f;
}
__device__ __forceinline__ u16 f2us(float f){
  unsigned int x; __builtin_memcpy(&x, &f, 4);
  unsigned int r = x + 0x7fffu + ((x >> 16) & 1u);
  return (u16)(r >> 16);
}
__device__ __forceinline__ float sigmf(float x){ return 1.0f/(1.0f + __expf(-x)); }
__device__ __forceinline__ float tanhfast(float x){ return 1.0f - 2.0f/(__expf(2.0f*x) + 1.0f); }

// ---------------- embedding gather -> p bf16 [65536][300] ----------------
__global__ __launch_bounds__(256) void k_embed(const int* __restrict__ s1, const int* __restrict__ s2,
                                               const float* __restrict__ emb, u16* __restrict__ p)
{
  int id = blockIdx.x*256 + threadIdx.x;
  if (id >= 65536*75) return;
  int row = id / 75;
  int c4 = (id - row*75) * 4;
  int tok = (row < 32768) ? s1[row] : s2[row - 32768];
  float4 v = *(const float4*)(emb + (size_t)tok*300 + c4);
  ushort4 o; o.x=f2us(v.x); o.y=f2us(v.y); o.z=f2us(v.z); o.w=f2us(v.w);
  *(ushort4*)(p + (size_t)row*300 + c4) = o;
}

// ---------------- f32 -> bf16 convert ----------------
__global__ __launch_bounds__(256) void k_cvt(const float* __restrict__ in, u16* __restrict__ out, int n)
{
  int id = blockIdx.x*256 + threadIdx.x;
  if (id < n) out[id] = f2us(in[id]);
}

// ---------------- pack Whh [1200][300] f32 into MFMA B-fragment stream ----------------
// pack[ntile(80)][ktile(10)][lane(64)][8] : value = W^T[k][n] = whh[n][k], zeros beyond.
__global__ __launch_bounds__(256) void k_pack(const float* __restrict__ W, u16* __restrict__ pack)
{
  int id = blockIdx.x*256 + threadIdx.x;       // 51200 total
  if (id >= 51200) return;
  const int lane = id & 63;
  const int kt2 = (id >> 6) % 10;
  const int nt2 = id / 640;
  const int n = nt2*16 + (lane & 15);
  u16 tmp[8];
#pragma unroll
  for (int j = 0; j < 8; ++j){
    const int k = kt2*32 + (lane >> 4)*8 + j;
    tmp[j] = (n < 1200 && k < 300) ? f2us(W[(size_t)n*300 + k]) : (u16)0;
  }
  *(s16x8*)(pack + (size_t)id*8) = *(const s16x8*)tmp;
}

// ---------------- MFMA GEMM: xp chunk ----------------
// xp[dir][m_local][1200] = gather(p)[.,300] @ wih_bf^T + bih + bhh ; m_local = r*32+tl
__global__ __launch_bounds__(256) void k_mm_xpc(
    const u16* __restrict__ A,                 // [65536][300] bf16 (p or pc)
    const u16* __restrict__ WFb, const u16* __restrict__ WBb,  // [1200][300] bf16
    const float* __restrict__ bF1, const float* __restrict__ bF2,
    const float* __restrict__ bB1, const float* __restrict__ bB2,
    const int* __restrict__ l1, const int* __restrict__ l2,
    u16* __restrict__ xp, int c)
{
  const int dir = blockIdx.z;
  const u16* Bw = dir ? WBb : WFb;
  const float* b1 = dir ? bB1 : bF1;
  const float* b2 = dir ? bB2 : bF2;
  u16* xpd = xp + (size_t)dir*9830400;
  __shared__ u16 As[128][40];
  __shared__ u16 Bs[128][40];
  const int tid = threadIdx.x;
  const int m0 = blockIdx.y << 7;
  const int n0 = blockIdx.x << 7;
  const int srow0 = tid >> 2;                  // 0..63
  const int kcol = (tid & 3) << 3;             // 0,8,16,24
  int src[2];
#pragma unroll
  for (int p = 0; p < 2; ++p){
    const int row = srow0 + (p << 6);
    const int ml = m0 + row;
    const int r = ml >> 5, tl = ml & 31;
    const int L = (r < 128) ? l1[r] : l2[r-128];
    const int tg = (c << 5) + tl;
    const int s = dir ? ((tg < L) ? (L-1-tg) : tg) : tg;
    src[p] = r*256 + s;
  }
  const int wv = tid >> 6;
  const int wm = (wv >> 1) << 6, wn = (wv & 1) << 6;
  const int lq = (tid >> 4) & 3;
  const int lr = tid & 15;
  fx4 acc[4][4];
#pragma unroll
  for (int i = 0; i < 4; ++i)
#pragma unroll
    for (int j = 0; j < 4; ++j) acc[i][j] = (fx4){0.f,0.f,0.f,0.f};

  for (int kt = 0; kt < 10; ++kt){
    const int k = (kt << 5) + kcol;
#pragma unroll
    for (int p = 0; p < 2; ++p){
      u16 tmp[8];
      const u16* ap = A + (size_t)src[p]*300 + k;
      if (k + 8 <= 300){
        *(ushort4*)&tmp[0] = *(const ushort4*)ap;
        *(ushort4*)&tmp[4] = *(const ushort4*)(ap + 4);
      } else {
#pragma unroll
        for (int j = 0; j < 8; ++j) tmp[j] = (k + j < 300) ? ap[j] : (u16)0;
      }
      *(s16x8*)&As[srow0 + (p << 6)][kcol] = *(const s16x8*)tmp;

      const int n = n0 + srow0 + (p << 6);
      u16 tmb[8] = {0,0,0,0,0,0,0,0};
      if (n < 1200){
        const u16* bp = Bw + (size_t)n*300 + k;
        if (k + 8 <= 300){
          *(ushort4*)&tmb[0] = *(const ushort4*)bp;
          *(ushort4*)&tmb[4] = *(const ushort4*)(bp + 4);
        } else {
#pragma unroll
          for (int j = 0; j < 8; ++j) tmb[j] = (k + j < 300) ? bp[j] : (u16)0;
        }
      }
      *(s16x8*)&Bs[srow0 + (p << 6)][kcol] = *(const s16x8*)tmb;
    }
    __syncthreads();
    s16x8 af[4], bf[4];
#pragma unroll
    for (int mi = 0; mi < 4; ++mi) af[mi] = *(const s16x8*)&As[wm + mi*16 + lr][lq << 3];
#pragma unroll
    for (int ni = 0; ni < 4; ++ni) bf[ni] = *(const s16x8*)&Bs[wn + ni*16 + lr][lq << 3];
#pragma unroll
    for (int mi = 0; mi < 4; ++mi)
#pragma unroll
      for (int ni = 0; ni < 4; ++ni)
        acc[mi][ni] = __builtin_amdgcn_mfma_f32_16x16x32_bf16(af[mi], bf[ni], acc[mi][ni], 0, 0, 0);
    __syncthreads();
  }
#pragma unroll
  for (int ni = 0; ni < 4; ++ni){
    const int n = n0 + wn + ni*16 + lr;
    if (n < 1200){
      const float bias = b1[n] + b2[n];
#pragma unroll
      for (int mi = 0; mi < 4; ++mi){
        const int m = m0 + wm + mi*16 + (lq << 2);
#pragma unroll
        for (int reg = 0; reg < 4; ++reg)
          xpd[(size_t)(m + reg)*1200 + n] = f2us(acc[mi][ni][reg] + bias);
      }
    }
  }
}

// ---------------- MFMA GEMM: S = u1 @ u2^T per b ----------------
__global__ __launch_bounds__(256) void k_mm_s(const u16* __restrict__ U, float* __restrict__ S)
{
  __shared__ u16 As[128][40];
  __shared__ u16 Bs[128][40];
  const int tid = threadIdx.x;
  const int bz = blockIdx.z;
  const u16* Ap = U + (size_t)bz*153600;
  const u16* Bp = U + (size_t)(128+bz)*153600;
  float* C = S + (size_t)bz*65536;
  const int m0 = blockIdx.y << 7;
  const int n0 = blockIdx.x << 7;
  const int srow0 = tid >> 2;
  const int kcol = (tid & 3) << 3;
  const int wv = tid >> 6;
  const int wm = (wv >> 1) << 6, wn = (wv & 1) << 6;
  const int lq = (tid >> 4) & 3;
  const int lr = tid & 15;
  fx4 acc[4][4];
#pragma unroll
  for (int i = 0; i < 4; ++i)
#pragma unroll
    for (int j = 0; j < 4; ++j) acc[i][j] = (fx4){0.f,0.f,0.f,0.f};

  for (int kt = 0; kt < 19; ++kt){
    const int k = (kt << 5) + kcol;
#pragma unroll
    for (int p = 0; p < 2; ++p){
      const int row = srow0 + (p << 6);
      u16 tma[8] = {0,0,0,0,0,0,0,0};
      u16 tmb[8] = {0,0,0,0,0,0,0,0};
      if (k + 8 <= 600){
        *(s16x8*)tma = *(const s16x8*)(Ap + (size_t)(m0 + row)*600 + k);
        *(s16x8*)tmb = *(const s16x8*)(Bp + (size_t)(n0 + row)*600 + k);
      }
      *(s16x8*)&As[row][kcol] = *(const s16x8*)tma;
      *(s16x8*)&Bs[row][kcol] = *(const s16x8*)tmb;
    }
    __syncthreads();
    s16x8 af[4], bf[4];
#pragma unroll
    for (int mi = 0; mi < 4; ++mi) af[mi] = *(const s16x8*)&As[wm + mi*16 + lr][lq << 3];
#pragma unroll
    for (int ni = 0; ni < 4; ++ni) bf[ni] = *(const s16x8*)&Bs[wn + ni*16 + lr][lq << 3];
#pragma unroll
    for (int mi = 0; mi < 4; ++mi)
#pragma unroll
      for (int ni = 0; ni < 4; ++ni)
        acc[mi][ni] = __builtin_amdgcn_mfma_f32_16x16x32_bf16(af[mi], bf[ni], acc[mi][ni], 0, 0, 0);
    __syncthreads();
  }
#pragma unroll
  for (int mi = 0; mi < 4; ++mi){
    const int m = m0 + wm + mi*16 + (lq << 2);
#pragma unroll
    for (int ni = 0; ni < 4; ++ni){
      const int n = n0 + wn + ni*16 + lr;
#pragma unroll
      for (int reg = 0; reg < 4; ++reg)
        C[(size_t)(m + reg)*256 + n] = acc[mi][ni][reg];
    }
  }
}

// ---------------- MFMA GEMM: pc = relu([u,A,u-A,u*A] @ projW^T + projB) ----------------
__global__ __launch_bounds__(256) void k_mm_proj(
    const u16* __restrict__ U, const u16* __restrict__ ATT,
    const u16* __restrict__ Bw,                // projW bf16 [300][2400]
    const float* __restrict__ bias,
    u16* __restrict__ C)
{
  __shared__ u16 As[128][40];
  __shared__ u16 Bs[128][40];
  const int tid = threadIdx.x;
  const int m0 = blockIdx.y << 7;
  const int n0 = blockIdx.x << 7;
  const int srow0 = tid >> 2;
  const int kcol = (tid & 3) << 3;
  const int wv = tid >> 6;
  const int wm = (wv >> 1) << 6, wn = (wv & 1) << 6;
  const int lq = (tid >> 4) & 3;
  const int lr = tid & 15;
  fx4 acc[4][4];
#pragma unroll
  for (int i = 0; i < 4; ++i)
#pragma unroll
    for (int j = 0; j < 4; ++j) acc[i][j] = (fx4){0.f,0.f,0.f,0.f};

  for (int kt = 0; kt < 75; ++kt){
    const int k = (kt << 5) + kcol;
    const int seg = k / 600;
    const int off = k - seg*600;
#pragma unroll
    for (int p = 0; p < 2; ++p){
      const int row = srow0 + (p << 6);
      const size_t base = (size_t)(m0 + row)*600 + off;
      u16 uu8[8], aa8[8], tma[8];
      *(s16x8*)uu8 = *(const s16x8*)(U + base);
      *(s16x8*)aa8 = *(const s16x8*)(ATT + base);
      if (seg == 0){
#pragma unroll
        for (int j = 0; j < 8; ++j) tma[j] = uu8[j];
      } else if (seg == 1){
#pragma unroll
        for (int j = 0; j < 8; ++j) tma[j] = aa8[j];
      } else if (seg == 2){
#pragma unroll
        for (int j = 0; j < 8; ++j) tma[j] = f2us(us2f(uu8[j]) - us2f(aa8[j]));
      } else {
#pragma unroll
        for (int j = 0; j < 8; ++j) tma[j] = f2us(us2f(uu8[j]) * us2f(aa8[j]));
      }
      *(s16x8*)&As[row][kcol] = *(const s16x8*)tma;

      const int n = n0 + row;
      u16 tmb[8] = {0,0,0,0,0,0,0,0};
      if (n < 300)
        *(s16x8*)tmb = *(const s16x8*)(Bw + (size_t)n*2400 + k);
      *(s16x8*)&Bs[row][kcol] = *(const s16x8*)tmb;
    }
    __syncthreads();
    s16x8 af[4], bf[4];
#pragma unroll
    for (int mi = 0; mi < 4; ++mi) af[mi] = *(const s16x8*)&As[wm + mi*16 + lr][lq << 3];
#pragma unroll
    for (int ni = 0; ni < 4; ++ni) bf[ni] = *(const s16x8*)&Bs[wn + ni*16 + lr][lq << 3];
#pragma unroll
    for (int mi = 0; mi < 4; ++mi)
#pragma unroll
      for (int ni = 0; ni < 4; ++ni)
        acc[mi][ni] = __builtin_amdgcn_mfma_f32_16x16x32_bf16(af[mi], bf[ni], acc[mi][ni], 0, 0, 0);
    __syncthreads();
  }
#pragma unroll
  for (int ni = 0; ni < 4; ++ni){
    const int n = n0 + wn + ni*16 + lr;
    if (n < 300){
      const float bs = bias[n];
#pragma unroll
      for (int mi = 0; mi < 4; ++mi){
        const int m = m0 + wm + mi*16 + (lq << 2);
#pragma unroll
        for (int reg = 0; reg < 4; ++reg)
          C[(size_t)(m + reg)*300 + n] = f2us(fmaxf(acc[mi][ni][reg] + bs, 0.0f));
      }
    }
  }
}

// ---------------- MFMA streaming scan: 32 WGs x 512 threads, 16 samples x 1 dir each ----------------
__global__ __launch_bounds__(512) void k_scan_mf(
    const u16* __restrict__ xp,                // [2][8192][1200] bf16 (chunk-gathered)
    const u16* __restrict__ packF, const u16* __restrict__ packB, // [80][10][64][8]
    const int* __restrict__ l1, const int* __restrict__ l2,
    u16* __restrict__ uo,                      // [65536][600] bf16
    u16* __restrict__ hG, float* __restrict__ cG,  // [2][256][328] bf16 ; [2][256][304] f32
    int c)
{
  __shared__ u16 h_s[16][328];
  __shared__ float c_s[16][304];
  __shared__ float gs[16][1200];
  __shared__ int L_s[16];
  const int bid = blockIdx.x;
  const int dir = bid & 1, sg = bid >> 1;
  const int r0 = sg << 4;
  const u16* pack = dir ? packB : packF;
  const u16* xpd = xp + (size_t)dir*9830400;
  const int tid = threadIdx.x;
  if (tid < 16) L_s[tid] = (r0 + tid < 128) ? l1[r0 + tid] : l2[r0 + tid - 128];
  for (int i = tid; i < 16*328; i += 512){
    const int q = i / 328, d = i - q*328;
    h_s[q][d] = (c > 0) ? hG[(size_t)(dir*256 + r0 + q)*328 + d] : (u16)0;
  }
  for (int i = tid; i < 16*300; i += 512){
    const int q = i / 300, d = i - q*300;
    c_s[q][d] = (c > 0) ? cG[(size_t)(dir*256 + r0 + q)*304 + d] : 0.0f;
  }
  __syncthreads();
  int Lmax = 0;
#pragma unroll
  for (int q = 0; q < 16; ++q) Lmax = max(Lmax, L_s[q]);

  const int w = tid >> 6, lane = tid & 63;
  const int lq = lane >> 4, lr = lane & 15;
  const int tile0 = w * 10;
  const u16* pw = pack + (size_t)tile0*5120 + (size_t)lane*8;
  int xrow[4];
#pragma unroll
  for (int reg = 0; reg < 4; ++reg)
    xrow[reg] = (r0 + (lq << 2) + reg) << 5;   // chunk-local row base

  const int t0 = c << 5;
  for (int tl = 0; tl < 32; ++tl){
    const int t = t0 + tl;
    if (t >= Lmax) break;
    // A-frags from h
    s16x8 af[10];
#pragma unroll
    for (int kt = 0; kt < 10; ++kt)
      af[kt] = *(const s16x8*)&h_s[lr][kt*32 + (lq << 3)];
    // C-init from xp (includes Wih x + biases)
    fx4 acc[10];
#pragma unroll
    for (int nt = 0; nt < 10; ++nt){
      const int n = (tile0 + nt)*16 + lr;
#pragma unroll
      for (int reg = 0; reg < 4; ++reg){
        float v = 0.0f;
        if (n < 1200) v = us2f(xpd[(size_t)(xrow[reg] + tl)*1200 + n]);
        acc[nt][reg] = v;
      }
    }
    // streamed MFMA: gates += Whh^T-packed x h
#pragma unroll
    for (int nt = 0; nt < 10; ++nt){
#pragma unroll
      for (int kt = 0; kt < 10; ++kt){
        s16x8 bfr = *(const s16x8*)(pw + (size_t)(nt*10 + kt)*512);
        acc[nt] = __builtin_amdgcn_mfma_f32_16x16x32_bf16(af[kt], bfr, acc[nt], 0, 0, 0);
      }
    }
    // gates -> LDS
#pragma unroll
    for (int nt = 0; nt < 10; ++nt){
      const int n = (tile0 + nt)*16 + lr;
      if (n < 1200){
#pragma unroll
        for (int reg = 0; reg < 4; ++reg)
          gs[(lq << 2) + reg][n] = acc[nt][reg];
      }
    }
    __syncthreads();
    // nonlinearity + state update + output
#pragma unroll
    for (int j = 0; j < 10; ++j){
      const int u0 = tid + (j << 9);
      if (u0 < 4800){
        const int q = u0 / 300, d = u0 - q*300;
        const int L = L_s[q];
        if (t < L){
          const float gi = gs[q][d], gf = gs[q][300+d], gg = gs[q][600+d], go = gs[q][900+d];
          const float cn = sigmf(gf)*c_s[q][d] + sigmf(gi)*tanhfast(gg);
          const float hn = sigmf(go)*tanhfast(cn);
          c_s[q][d] = cn;
          const u16 hb = f2us(hn);
          h_s[q][d] = hb;
          const int wpos = dir ? (L-1-t) : t;
          uo[(size_t)((r0 + q)*256 + wpos)*600 + dir*300 + d] = hb;
        }
      }
    }
    __syncthreads();
  }
  // persist state
  for (int i = tid; i < 16*328; i += 512){
    const int q = i / 328, d = i - q*328;
    hG[(size_t)(dir*256 + r0 + q)*328 + d] = h_s[q][d];
  }
  for (int i = tid; i < 16*300; i += 512){
    const int q = i / 300, d = i - q*300;
    cG[(size_t)(dir*256 + r0 + q)*304 + d] = c_s[q][d];
  }
}

// ---------------- softmax stats ----------------
__global__ __launch_bounds__(256) void k_row_stats(const float* __restrict__ S, const int* __restrict__ l2,
                                                   float* __restrict__ rmax, float* __restrict__ rinv)
{
  const int wid = threadIdx.x >> 6, lane = threadIdx.x & 63;
  const int row = blockIdx.x*4 + wid;
  const int b = row >> 8;
  const int L2b = l2[b];
  float4 v = *(const float4*)(S + (size_t)row*256 + lane*4);
  const int j = lane*4;
  float m = -INFINITY;
  if (j   < L2b) m = fmaxf(m, v.x);
  if (j+1 < L2b) m = fmaxf(m, v.y);
  if (j+2 < L2b) m = fmaxf(m, v.z);
  if (j+3 < L2b) m = fmaxf(m, v.w);
  for (int off = 32; off; off >>= 1) m = fmaxf(m, __shfl_xor(m, off));
  float s = 0.f;
  if (j   < L2b) s += __expf(v.x - m);
  if (j+1 < L2b) s += __expf(v.y - m);
  if (j+2 < L2b) s += __expf(v.z - m);
  if (j+3 < L2b) s += __expf(v.w - m);
  for (int off = 32; off; off >>= 1) s += __shfl_xor(s, off);
  if (lane == 0){ rmax[row] = m; rinv[row] = 1.0f/s; }
}

__global__ __launch_bounds__(256) void k_col_stats(const float* __restrict__ S, const int* __restrict__ l1,
                                                   float* __restrict__ cmax, float* __restrict__ cinv)
{
  const int b = blockIdx.x;
  const int j = threadIdx.x;
  const int L1b = l1[b];
  const float* Sb = S + (size_t)b*65536;
  float m = -INFINITY;
  for (int i = 0; i < L1b; ++i) m = fmaxf(m, Sb[(size_t)i*256 + j]);
  float s = 0.f;
  for (int i = 0; i < L1b; ++i) s += __expf(Sb[(size_t)i*256 + j] - m);
  cmax[b*256 + j] = m;
  cinv[b*256 + j] = 1.0f/s;
}

// ---------------- A1 = softmax_rows(S) @ u2 -> att bf16 ----------------
__global__ __launch_bounds__(256) void k_av_row(
    const float* __restrict__ S, const u16* __restrict__ U,
    const int* __restrict__ l1, const int* __restrict__ l2,
    const float* __restrict__ rmax, const float* __restrict__ rinv,
    u16* __restrict__ ATT)
{
  __shared__ float Ps[32][68];
  __shared__ float Us[32][68];
  const int tid = threadIdx.x;
  const int b = blockIdx.z;
  const int i0 = blockIdx.y << 6;
  const int d0 = blockIdx.x << 6;
  const int L1b = l1[b], L2b = l2[b];
  const float* Sb = S + (size_t)b*65536;
  const u16* u2 = U + (size_t)(128+b)*153600;
  const int tx = tid & 15, ty = tid >> 4;
  float acc[4][4];
#pragma unroll
  for (int i = 0; i < 4; ++i)
#pragma unroll
    for (int j = 0; j < 4; ++j) acc[i][j] = 0.0f;

  for (int kt = 0; kt < 8; ++kt){
    const int j0 = kt << 5;
#pragma unroll
    for (int q = 0; q < 2; ++q){
      const int f4 = tid + (q << 8);
      {
        const int row = f4 >> 3;
        const int c4 = (f4 & 7) << 2;
        const int i = i0 + row;
        float4 s4 = *(const float4*)(Sb + (size_t)i*256 + j0 + c4);
        const float rm = rmax[(b<<8) + i];
        const float ri = rinv[(b<<8) + i];
        const int jb = j0 + c4;
        Ps[c4  ][row] = (jb   < L2b) ? __expf(s4.x - rm)*ri : 0.0f;
        Ps[c4+1][row] = (jb+1 < L2b) ? __expf(s4.y - rm)*ri : 0.0f;
        Ps[c4+2][row] = (jb+2 < L2b) ? __expf(s4.z - rm)*ri : 0.0f;
        Ps[c4+3][row] = (jb+3 < L2b) ? __expf(s4.w - rm)*ri : 0.0f;
      }
      {
        const int row = f4 >> 4;
        const int c4 = (f4 & 15) << 2;
        const int d = d0 + c4;
        float4 v = make_float4(0.f,0.f,0.f,0.f);
        if (j0 + row < L2b){
          const u16* up = u2 + (size_t)(j0+row)*600 + d;
          if (d + 3 < 600){
            ushort4 t4 = *(const ushort4*)up;
            v.x=us2f(t4.x); v.y=us2f(t4.y); v.z=us2f(t4.z); v.w=us2f(t4.w);
          } else {
            if (d   < 600) v.x = us2f(up[0]);
            if (d+1 < 600) v.y = us2f(up[1]);
            if (d+2 < 600) v.z = us2f(up[2]);
          }
        }
        *(float4*)&Us[row][c4] = v;
      }
    }
    __syncthreads();
#pragma unroll
    for (int kk = 0; kk < 32; ++kk){
      float4 a = *(const float4*)&Ps[kk][ty<<2];
      float4 bb = *(const float4*)&Us[kk][tx<<2];
      float av[4] = {a.x,a.y,a.z,a.w};
      float bv[4] = {bb.x,bb.y,bb.z,bb.w};
#pragma unroll
      for (int ii = 0; ii < 4; ++ii)
#pragma unroll
        for (int jj = 0; jj < 4; ++jj)
          acc[ii][jj] = fmaf(av[ii], bv[jj], acc[ii][jj]);
    }
    __syncthreads();
  }
#pragma unroll
  for (int ii = 0; ii < 4; ++ii){
    const int i = i0 + (ty<<2) + ii;
#pragma unroll
    for (int jj = 0; jj < 4; ++jj){
      const int d = d0 + (tx<<2) + jj;
      if (d < 600)
        ATT[(size_t)b*153600 + (size_t)i*600 + d] = f2us((i < L1b) ? acc[ii][jj] : 0.0f);
    }
  }
}

// ---------------- A2 = softmax_cols(S)^T @ u1 -> att bf16 ----------------
__global__ __launch_bounds__(256) void k_av_col(
    const float* __restrict__ S, const u16* __restrict__ U,
    const int* __restrict__ l1, const int* __restrict__ l2,
    const float* __restrict__ cmax, const float* __restrict__ cinv,
    u16* __restrict__ ATT)
{
  __shared__ float Ps[32][68];
  __shared__ float Us[32][68];
  const int tid = threadIdx.x;
  const int b = blockIdx.z;
  const int j0v = blockIdx.y << 6;
  const int d0 = blockIdx.x << 6;
  const int L1b = l1[b], L2b = l2[b];
  const float* Sb = S + (size_t)b*65536;
  const u16* u1 = U + (size_t)b*153600;
  const int tx = tid & 15, ty = tid >> 4;
  float acc[4][4];
#pragma unroll
  for (int i = 0; i < 4; ++i)
#pragma unroll
    for (int j = 0; j < 4; ++j) acc[i][j] = 0.0f;

  for (int kt = 0; kt < 8; ++kt){
    const int i0k = kt << 5;
#pragma unroll
    for (int q = 0; q < 2; ++q){
      const int f4 = tid + (q << 8);
      const int row = f4 >> 4;
      const int c4 = (f4 & 15) << 2;
      {
        const int i = i0k + row;
        const int j = j0v + c4;
        float4 s4 = *(const float4*)(Sb + (size_t)i*256 + j);
        const bool iok = i < L1b;
        Ps[row][c4  ] = iok ? __expf(s4.x - cmax[(b<<8)+j  ])*cinv[(b<<8)+j  ] : 0.0f;
        Ps[row][c4+1] = iok ? __expf(s4.y - cmax[(b<<8)+j+1])*cinv[(b<<8)+j+1] : 0.0f;
        Ps[row][c4+2] = iok ? __expf(s4.z - cmax[(b<<8)+j+2])*cinv[(b<<8)+j+2] : 0.0f;
        Ps[row][c4+3] = iok ? __expf(s4.w - cmax[(b<<8)+j+3])*cinv[(b<<8)+j+3] : 0.0f;
      }
      {
        const int d = d0 + c4;
        float4 v = make_float4(0.f,0.f,0.f,0.f);
        if (i0k + row < L1b){
          const u16* up = u1 + (size_t)(i0k+row)*600 + d;
          if (d + 3 < 600){
            ushort4 t4 = *(const ushort4*)up;
            v.x=us2f(t4.x); v.y=us2f(t4.y); v.z=us2f(t4.z); v.w=us2f(t4.w);
          } else {
            if (d   < 600) v.x = us2f(up[0]);
            if (d+1 < 600) v.y = us2f(up[1]);
            if (d+2 < 600) v.z = us2f(up[2]);
          }
        }
        *(float4*)&Us[row][c4] = v;
      }
    }
    __syncthreads();
#pragma unroll
    for (int kk = 0; kk < 32; ++kk){
      float4 a = *(const float4*)&Ps[kk][ty<<2];
      float4 bb = *(const float4*)&Us[kk][tx<<2];
      float av[4] = {a.x,a.y,a.z,a.w};
      float bv[4] = {bb.x,bb.y,bb.z,bb.w};
#pragma unroll
      for (int ii = 0; ii < 4; ++ii)
#pragma unroll
        for (int jj = 0; jj < 4; ++jj)
          acc[ii][jj] = fmaf(av[ii], bv[jj], acc[ii][jj]);
    }
    __syncthreads();
  }
#pragma unroll
  for (int ii = 0; ii < 4; ++ii){
    const int j = j0v + (ty<<2) + ii;
#pragma unroll
    for (int jj = 0; jj < 4; ++jj){
      const int d = d0 + (tx<<2) + jj;
      if (d < 600)
        ATT[(size_t)(128+b)*153600 + (size_t)j*600 + d] = f2us((j < L2b) ? acc[ii][jj] : 0.0f);
    }
  }
}

// ---------------- masked max over time + feature build ----------------
__global__ __launch_bounds__(256) void k_maxfeat(const u16* __restrict__ y,
                                                 const int* __restrict__ l1, const int* __restrict__ l2,
                                                 float* __restrict__ feat)
{
  const int b = blockIdx.x;
  const int La = l1[b], Lb = l2[b];
  for (int c = threadIdx.x; c < 600; c += 256){
    float m1 = -INFINITY, m2 = -INFINITY;
    const u16* y1 = y + (size_t)b*153600 + c;
    for (int t = 0; t < La; ++t) m1 = fmaxf(m1, us2f(y1[(size_t)t*600]));
    const u16* y2 = y + (size_t)(128+b)*153600 + c;
    for (int t = 0; t < Lb; ++t) m2 = fmaxf(m2, us2f(y2[(size_t)t*600]));
    feat[(size_t)b*2400 + c]        = m1;
    feat[(size_t)b*2400 + 600 + c]  = m2;
    feat[(size_t)b*2400 + 1200 + c] = fabsf(m1 - m2);
    feat[(size_t)b*2400 + 1800 + c] = m1*m2;
  }
}

// ---------------- per-row MLP ----------------
__global__ __launch_bounds__(256) void k_rowgemm(const float* __restrict__ feat, const float* __restrict__ W,
                                                 const float* __restrict__ bias, float* __restrict__ out)
{
  const int b = blockIdx.x;
  __shared__ float ff[2400];
  for (int i = threadIdx.x; i < 2400; i += 256) ff[i] = feat[(size_t)b*2400 + i];
  __syncthreads();
  for (int n = threadIdx.x; n < 300; n += 256){
    const float* w = W + (size_t)n*2400;
    float acc = bias[n];
    for (int k = 0; k < 2400; k += 4){
      float4 wv = *(const float4*)(w + k);
      acc += ff[k]*wv.x + ff[k+1]*wv.y + ff[k+2]*wv.z + ff[k+3]*wv.w;
    }
    out[(size_t)b*300 + n] = fmaxf(acc, 0.0f);
  }
}

// ---------------- final ----------------
__global__ __launch_bounds__(192) void k_final(const float* __restrict__ h, const float* __restrict__ smW,
                                               const float* __restrict__ smB, float* __restrict__ out)
{
  const int b = blockIdx.x;
  const int n = threadIdx.x >> 6, lane = threadIdx.x & 63;
  float acc = 0.f;
  for (int k = lane; k < 300; k += 64) acc += h[(size_t)b*300 + k]*smW[(size_t)n*300 + k];
  for (int off = 32; off; off >>= 1) acc += __shfl_xor(acc, off);
  if (lane == 0) out[b*3 + n] = acc + smB[n];
}

extern "C" void kernel_launch(void* const* d_in, const int* in_sizes, int n_in,
                              void* d_out, int out_size, void* d_ws, size_t ws_size,
                              hipStream_t stream)
{
  (void)in_sizes; (void)n_in; (void)out_size;
  static const size_t OFF_P  = 0;             // p bf16 [65536][300]
  static const size_t OFF_B  = 39321600;      // xp1 / Smat / pc
  static const size_t OFF_U  = 78643200;      // uu/y bf16 [65536][600]
  static const size_t OFF_D  = 157286400;     // att / xp2
  static const size_t OFF_WT = 235929600;     // wih bf16 x4 (720000B each)
  static const size_t OFF_PJ = 238809600;     // projW bf16 (1440000B)
  static const size_t OFF_PK = 240249600;     // W_pack x4 (819200B each)
  static const size_t OFF_ST = 243526400;     // stats 4x32768 f32
  static const size_t OFF_FE = 244050688;     // feat
  static const size_t OFF_HM = 245279488;     // hml
  static const size_t OFF_HC = 245433088;     // hG bf16 (335872) + cG f32 (622592)
  static const size_t WS_NEEDED = 246391552;
  if (ws_size < WS_NEEDED) return;

  const int* s1 = (const int*)d_in[0];
  const int* l1 = (const int*)d_in[1];
  const int* s2 = (const int*)d_in[2];
  const int* l2 = (const int*)d_in[3];
  const float* emb    = (const float*)d_in[4];
  const float* w1f_ih = (const float*)d_in[5];
  const float* w1f_hh = (const float*)d_in[6];
  const float* b1f_ih = (const float*)d_in[7];
  const float* b1f_hh = (const float*)d_in[8];
  const float* w1b_ih = (const float*)d_in[9];
  const float* w1b_hh = (const float*)d_in[10];
  const float* b1b_ih = (const float*)d_in[11];
  const float* b1b_hh = (const float*)d_in[12];
  const float* w2f_ih = (const float*)d_in[13];
  const float* w2f_hh = (const float*)d_in[14];
  const float* b2f_ih = (const float*)d_in[15];
  const float* b2f_hh = (const float*)d_in[16];
  const float* w2b_ih = (const float*)d_in[17];
  const float* w2b_hh = (const float*)d_in[18];
  const float* b2b_ih = (const float*)d_in[19];
  const float* b2b_hh = (const float*)d_in[20];
  const float* projW  = (const float*)d_in[21];
  const float* projB  = (const float*)d_in[22];
  const float* mlpW   = (const float*)d_in[23];
  const float* mlpB   = (const float*)d_in[24];
  const float* smW    = (const float*)d_in[25];
  const float* smB    = (const float*)d_in[26];

  char* ws = (char*)d_ws;
  u16*   p    = (u16*)(ws + OFF_P);
  u16*   xp1  = (u16*)(ws + OFF_B);
  float* Smat = (float*)(ws + OFF_B);
  u16*   pc   = (u16*)(ws + OFF_B);
  u16*   uu   = (u16*)(ws + OFF_U);
  u16*   att  = (u16*)(ws + OFF_D);
  u16*   xp2  = (u16*)(ws + OFF_D);
  u16*   wih  = (u16*)(ws + OFF_WT);          // 4 x 360000 u16
  u16*   pjw  = (u16*)(ws + OFF_PJ);          // 720000 u16
  u16*   pk   = (u16*)(ws + OFF_PK);          // 4 x 409600 u16
  float* st   = (float*)(ws + OFF_ST);
  float* feat = (float*)(ws + OFF_FE);
  float* hml  = (float*)(ws + OFF_HM);
  u16*   hG   = (u16*)(ws + OFF_HC);
  float* cG   = (float*)(ws + OFF_HC + 335872);

  k_embed<<<19200, 256, 0, stream>>>(s1, s2, emb, p);
  k_cvt<<<1407, 256, 0, stream>>>(w1f_ih, wih,           360000);
  k_cvt<<<1407, 256, 0, stream>>>(w1b_ih, wih + 360000,  360000);
  k_cvt<<<1407, 256, 0, stream>>>(w2f_ih, wih + 720000,  360000);
  k_cvt<<<1407, 256, 0, stream>>>(w2b_ih, wih + 1080000, 360000);
  k_cvt<<<2813, 256, 0, stream>>>(projW,  pjw,           720000);
  k_pack<<<200, 256, 0, stream>>>(w1f_hh, pk);
  k_pack<<<200, 256, 0, stream>>>(w1b_hh, pk + 409600);
  k_pack<<<200, 256, 0, stream>>>(w2f_hh, pk + 819200);
  k_pack<<<200, 256, 0, stream>>>(w2b_hh, pk + 1228800);

  const dim3 gxp(10, 64, 2);
  for (int c = 0; c < 8; ++c){
    k_mm_xpc<<<gxp, 256, 0, stream>>>(p, wih, wih + 360000, b1f_ih, b1f_hh, b1b_ih, b1b_hh,
                                      l1, l2, xp1, c);
    k_scan_mf<<<32, 512, 0, stream>>>(xp1, pk, pk + 409600, l1, l2, uu, hG, cG, c);
  }

  k_mm_s<<<dim3(2,2,128), 256, 0, stream>>>(uu, Smat);
  k_row_stats<<<8192, 256, 0, stream>>>(Smat, l2, st, st + 32768);
  k_col_stats<<<128, 256, 0, stream>>>(Smat, l1, st + 65536, st + 98304);
  k_av_row<<<dim3(10,4,128), 256, 0, stream>>>(Smat, uu, l1, l2, st, st + 32768, att);
  k_av_col<<<dim3(10,4,128), 256, 0, stream>>>(Smat, uu, l1, l2, st + 65536, st + 98304, att);

  k_mm_proj<<<dim3(3,512,1), 256, 0, stream>>>(uu, att, pjw, projB, pc);

  for (int c = 0; c < 8; ++c){
    k_mm_xpc<<<gxp, 256, 0, stream>>>(pc, wih + 720000, wih + 1080000, b2f_ih, b2f_hh, b2b_ih, b2b_hh,
                                      l1, l2, xp2, c);
    k_scan_mf<<<32, 512, 0, stream>>>(xp2, pk + 819200, pk + 1228800, l1, l2, uu, hG, cG, c);
  }

  k_maxfeat<<<128, 256, 0, stream>>>(uu, l1, l2, feat);
  k_rowgemm<<<128, 256, 0, stream>>>(feat, mlpW, mlpB, hml);
  k_final<<<128, 192, 0, stream>>>(hml, smW, smB, (float*)d_out);
}

// Round 4
// 13849.219 us; speedup vs baseline: 3.1753x; 1.0788x over previous
//
#include <hip/hip_runtime.h>
#include <hip/hip_bf16.h>

// B=128, T=256, V=50000, D=300, H=300. 256 sample-rows (0..127 = s1, 128..255 = s2).
// MFMA bf16 pipeline; time-chunked (TC=32) xp + streaming-weight MFMA scan with
// register-dbuf weight pipeline + LDS xp staging.

typedef unsigned short u16;
typedef float fx4 __attribute__((ext_vector_type(4)));
typedef short s16x8 __attribute__((ext_vector_type(8)));

__device__ __forceinline__ float us2f(u16 u){
  unsigned int x = ((unsigned int)u) << 16;
  float f; __builtin_memcpy(&f, &x, 4); return f;
}
__device__ __forceinline__ u16 f2us(float f){
  unsigned int x; __builtin_memcpy(&x, &f, 4);
  unsigned int r = x + 0x7fffu + ((x >> 16) & 1u);
  return (u16)(r >> 16);
}
__device__ __forceinline__ float sigmf(float x){ return 1.0f/(1.0f + __expf(-x)); }
__device__ __forceinline__ float tanhfast(float x){ return 1.0f - 2.0f/(__expf(2.0f*x) + 1.0f); }

// ---------------- embedding gather -> p bf16 [65536][300] ----------------
__global__ __launch_bounds__(256) void k_embed(const int* __restrict__ s1, const int* __restrict__ s2,
                                               const float* __restrict__ emb, u16* __restrict__ p)
{
  int id = blockIdx.x*256 + threadIdx.x;
  if (id >= 65536*75) return;
  int row = id / 75;
  int c4 = (id - row*75) * 4;
  int tok = (row < 32768) ? s1[row] : s2[row - 32768];
  float4 v = *(const float4*)(emb + (size_t)tok*300 + c4);
  ushort4 o; o.x=f2us(v.x); o.y=f2us(v.y); o.z=f2us(v.z); o.w=f2us(v.w);
  *(ushort4*)(p + (size_t)row*300 + c4) = o;
}

// ---------------- f32 -> bf16 convert ----------------
__global__ __launch_bounds__(256) void k_cvt(const float* __restrict__ in, u16* __restrict__ out, int n)
{
  int id = blockIdx.x*256 + threadIdx.x;
  if (id < n) out[id] = f2us(in[id]);
}

// ---------------- pack Whh [1200][300] f32 into MFMA B-fragment stream ----------------
// pack[ntile(80)][ktile(10)][lane(64)][8] : value = W^T[k][n] = whh[n][k], zeros beyond.
__global__ __launch_bounds__(256) void k_pack(const float* __restrict__ W, u16* __restrict__ pack)
{
  int id = blockIdx.x*256 + threadIdx.x;       // 51200 total
  if (id >= 51200) return;
  const int lane = id & 63;
  const int kt2 = (id >> 6) % 10;
  const int nt2 = id / 640;
  const int n = nt2*16 + (lane & 15);
  u16 tmp[8];
#pragma unroll
  for (int j = 0; j < 8; ++j){
    const int k = kt2*32 + (lane >> 4)*8 + j;
    tmp[j] = (n < 1200 && k < 300) ? f2us(W[(size_t)n*300 + k]) : (u16)0;
  }
  *(s16x8*)(pack + (size_t)id*8) = *(const s16x8*)tmp;
}

// ---------------- MFMA GEMM: xp chunk ----------------
__global__ __launch_bounds__(256) void k_mm_xpc(
    const u16* __restrict__ A,                 // [65536][300] bf16 (p or pc)
    const u16* __restrict__ WFb, const u16* __restrict__ WBb,  // [1200][300] bf16
    const float* __restrict__ bF1, const float* __restrict__ bF2,
    const float* __restrict__ bB1, const float* __restrict__ bB2,
    const int* __restrict__ l1, const int* __restrict__ l2,
    u16* __restrict__ xp, int c)
{
  const int dir = blockIdx.z;
  const u16* Bw = dir ? WBb : WFb;
  const float* b1 = dir ? bB1 : bF1;
  const float* b2 = dir ? bB2 : bF2;
  u16* xpd = xp + (size_t)dir*9830400;
  __shared__ u16 As[128][40];
  __shared__ u16 Bs[128][40];
  const int tid = threadIdx.x;
  const int m0 = blockIdx.y << 7;
  const int n0 = blockIdx.x << 7;
  const int srow0 = tid >> 2;                  // 0..63
  const int kcol = (tid & 3) << 3;             // 0,8,16,24
  int src[2];
#pragma unroll
  for (int p = 0; p < 2; ++p){
    const int row = srow0 + (p << 6);
    const int ml = m0 + row;
    const int r = ml >> 5, tl = ml & 31;
    const int L = (r < 128) ? l1[r] : l2[r-128];
    const int tg = (c << 5) + tl;
    const int s = dir ? ((tg < L) ? (L-1-tg) : tg) : tg;
    src[p] = r*256 + s;
  }
  const int wv = tid >> 6;
  const int wm = (wv >> 1) << 6, wn = (wv & 1) << 6;
  const int lq = (tid >> 4) & 3;
  const int lr = tid & 15;
  fx4 acc[4][4];
#pragma unroll
  for (int i = 0; i < 4; ++i)
#pragma unroll
    for (int j = 0; j < 4; ++j) acc[i][j] = (fx4){0.f,0.f,0.f,0.f};

  for (int kt = 0; kt < 10; ++kt){
    const int k = (kt << 5) + kcol;
#pragma unroll
    for (int p = 0; p < 2; ++p){
      u16 tmp[8];
      const u16* ap = A + (size_t)src[p]*300 + k;
      if (k + 8 <= 300){
        *(ushort4*)&tmp[0] = *(const ushort4*)ap;
        *(ushort4*)&tmp[4] = *(const ushort4*)(ap + 4);
      } else {
#pragma unroll
        for (int j = 0; j < 8; ++j) tmp[j] = (k + j < 300) ? ap[j] : (u16)0;
      }
      *(s16x8*)&As[srow0 + (p << 6)][kcol] = *(const s16x8*)tmp;

      const int n = n0 + srow0 + (p << 6);
      u16 tmb[8] = {0,0,0,0,0,0,0,0};
      if (n < 1200){
        const u16* bp = Bw + (size_t)n*300 + k;
        if (k + 8 <= 300){
          *(ushort4*)&tmb[0] = *(const ushort4*)bp;
          *(ushort4*)&tmb[4] = *(const ushort4*)(bp + 4);
        } else {
#pragma unroll
          for (int j = 0; j < 8; ++j) tmb[j] = (k + j < 300) ? bp[j] : (u16)0;
        }
      }
      *(s16x8*)&Bs[srow0 + (p << 6)][kcol] = *(const s16x8*)tmb;
    }
    __syncthreads();
    s16x8 af[4], bf[4];
#pragma unroll
    for (int mi = 0; mi < 4; ++mi) af[mi] = *(const s16x8*)&As[wm + mi*16 + lr][lq << 3];
#pragma unroll
    for (int ni = 0; ni < 4; ++ni) bf[ni] = *(const s16x8*)&Bs[wn + ni*16 + lr][lq << 3];
#pragma unroll
    for (int mi = 0; mi < 4; ++mi)
#pragma unroll
      for (int ni = 0; ni < 4; ++ni)
        acc[mi][ni] = __builtin_amdgcn_mfma_f32_16x16x32_bf16(af[mi], bf[ni], acc[mi][ni], 0, 0, 0);
    __syncthreads();
  }
#pragma unroll
  for (int ni = 0; ni < 4; ++ni){
    const int n = n0 + wn + ni*16 + lr;
    if (n < 1200){
      const float bias = b1[n] + b2[n];
#pragma unroll
      for (int mi = 0; mi < 4; ++mi){
        const int m = m0 + wm + mi*16 + (lq << 2);
#pragma unroll
        for (int reg = 0; reg < 4; ++reg)
          xpd[(size_t)(m + reg)*1200 + n] = f2us(acc[mi][ni][reg] + bias);
      }
    }
  }
}

// ---------------- MFMA GEMM: S = u1 @ u2^T per b ----------------
__global__ __launch_bounds__(256) void k_mm_s(const u16* __restrict__ U, float* __restrict__ S)
{
  __shared__ u16 As[128][40];
  __shared__ u16 Bs[128][40];
  const int tid = threadIdx.x;
  const int bz = blockIdx.z;
  const u16* Ap = U + (size_t)bz*153600;
  const u16* Bp = U + (size_t)(128+bz)*153600;
  float* C = S + (size_t)bz*65536;
  const int m0 = blockIdx.y << 7;
  const int n0 = blockIdx.x << 7;
  const int srow0 = tid >> 2;
  const int kcol = (tid & 3) << 3;
  const int wv = tid >> 6;
  const int wm = (wv >> 1) << 6, wn = (wv & 1) << 6;
  const int lq = (tid >> 4) & 3;
  const int lr = tid & 15;
  fx4 acc[4][4];
#pragma unroll
  for (int i = 0; i < 4; ++i)
#pragma unroll
    for (int j = 0; j < 4; ++j) acc[i][j] = (fx4){0.f,0.f,0.f,0.f};

  for (int kt = 0; kt < 19; ++kt){
    const int k = (kt << 5) + kcol;
#pragma unroll
    for (int p = 0; p < 2; ++p){
      const int row = srow0 + (p << 6);
      u16 tma[8] = {0,0,0,0,0,0,0,0};
      u16 tmb[8] = {0,0,0,0,0,0,0,0};
      if (k + 8 <= 600){
        *(s16x8*)tma = *(const s16x8*)(Ap + (size_t)(m0 + row)*600 + k);
        *(s16x8*)tmb = *(const s16x8*)(Bp + (size_t)(n0 + row)*600 + k);
      }
      *(s16x8*)&As[row][kcol] = *(const s16x8*)tma;
      *(s16x8*)&Bs[row][kcol] = *(const s16x8*)tmb;
    }
    __syncthreads();
    s16x8 af[4], bf[4];
#pragma unroll
    for (int mi = 0; mi < 4; ++mi) af[mi] = *(const s16x8*)&As[wm + mi*16 + lr][lq << 3];
#pragma unroll
    for (int ni = 0; ni < 4; ++ni) bf[ni] = *(const s16x8*)&Bs[wn + ni*16 + lr][lq << 3];
#pragma unroll
    for (int mi = 0; mi < 4; ++mi)
#pragma unroll
      for (int ni = 0; ni < 4; ++ni)
        acc[mi][ni] = __builtin_amdgcn_mfma_f32_16x16x32_bf16(af[mi], bf[ni], acc[mi][ni], 0, 0, 0);
    __syncthreads();
  }
#pragma unroll
  for (int mi = 0; mi < 4; ++mi){
    const int m = m0 + wm + mi*16 + (lq << 2);
#pragma unroll
    for (int ni = 0; ni < 4; ++ni){
      const int n = n0 + wn + ni*16 + lr;
#pragma unroll
      for (int reg = 0; reg < 4; ++reg)
        C[(size_t)(m + reg)*256 + n] = acc[mi][ni][reg];
    }
  }
}

// ---------------- MFMA GEMM: pc = relu([u,A,u-A,u*A] @ projW^T + projB) ----------------
__global__ __launch_bounds__(256) void k_mm_proj(
    const u16* __restrict__ U, const u16* __restrict__ ATT,
    const u16* __restrict__ Bw,                // projW bf16 [300][2400]
    const float* __restrict__ bias,
    u16* __restrict__ C)
{
  __shared__ u16 As[128][40];
  __shared__ u16 Bs[128][40];
  const int tid = threadIdx.x;
  const int m0 = blockIdx.y << 7;
  const int n0 = blockIdx.x << 7;
  const int srow0 = tid >> 2;
  const int kcol = (tid & 3) << 3;
  const int wv = tid >> 6;
  const int wm = (wv >> 1) << 6, wn = (wv & 1) << 6;
  const int lq = (tid >> 4) & 3;
  const int lr = tid & 15;
  fx4 acc[4][4];
#pragma unroll
  for (int i = 0; i < 4; ++i)
#pragma unroll
    for (int j = 0; j < 4; ++j) acc[i][j] = (fx4){0.f,0.f,0.f,0.f};

  for (int kt = 0; kt < 75; ++kt){
    const int k = (kt << 5) + kcol;
    const int seg = k / 600;
    const int off = k - seg*600;
#pragma unroll
    for (int p = 0; p < 2; ++p){
      const int row = srow0 + (p << 6);
      const size_t base = (size_t)(m0 + row)*600 + off;
      u16 uu8[8], aa8[8], tma[8];
      *(s16x8*)uu8 = *(const s16x8*)(U + base);
      *(s16x8*)aa8 = *(const s16x8*)(ATT + base);
      if (seg == 0){
#pragma unroll
        for (int j = 0; j < 8; ++j) tma[j] = uu8[j];
      } else if (seg == 1){
#pragma unroll
        for (int j = 0; j < 8; ++j) tma[j] = aa8[j];
      } else if (seg == 2){
#pragma unroll
        for (int j = 0; j < 8; ++j) tma[j] = f2us(us2f(uu8[j]) - us2f(aa8[j]));
      } else {
#pragma unroll
        for (int j = 0; j < 8; ++j) tma[j] = f2us(us2f(uu8[j]) * us2f(aa8[j]));
      }
      *(s16x8*)&As[row][kcol] = *(const s16x8*)tma;

      const int n = n0 + row;
      u16 tmb[8] = {0,0,0,0,0,0,0,0};
      if (n < 300)
        *(s16x8*)tmb = *(const s16x8*)(Bw + (size_t)n*2400 + k);
      *(s16x8*)&Bs[row][kcol] = *(const s16x8*)tmb;
    }
    __syncthreads();
    s16x8 af[4], bf[4];
#pragma unroll
    for (int mi = 0; mi < 4; ++mi) af[mi] = *(const s16x8*)&As[wm + mi*16 + lr][lq << 3];
#pragma unroll
    for (int ni = 0; ni < 4; ++ni) bf[ni] = *(const s16x8*)&Bs[wn + ni*16 + lr][lq << 3];
#pragma unroll
    for (int mi = 0; mi < 4; ++mi)
#pragma unroll
      for (int ni = 0; ni < 4; ++ni)
        acc[mi][ni] = __builtin_amdgcn_mfma_f32_16x16x32_bf16(af[mi], bf[ni], acc[mi][ni], 0, 0, 0);
    __syncthreads();
  }
#pragma unroll
  for (int ni = 0; ni < 4; ++ni){
    const int n = n0 + wn + ni*16 + lr;
    if (n < 300){
      const float bs = bias[n];
#pragma unroll
      for (int mi = 0; mi < 4; ++mi){
        const int m = m0 + wm + mi*16 + (lq << 2);
#pragma unroll
        for (int reg = 0; reg < 4; ++reg)
          C[(size_t)(m + reg)*300 + n] = f2us(fmaxf(acc[mi][ni][reg] + bs, 0.0f));
      }
    }
  }
}

// ---------------- MFMA streaming scan (pipelined): 32 WGs x 512 thr, 16 samples x 1 dir ----------------
__global__ __launch_bounds__(512) void k_scan_mf(
    const u16* __restrict__ xp,                // [2][8192][1200] bf16 (chunk-gathered)
    const u16* __restrict__ packF, const u16* __restrict__ packB, // [80][10][64][8]
    const int* __restrict__ l1, const int* __restrict__ l2,
    u16* __restrict__ uo,                      // [65536][600] bf16
    u16* __restrict__ hG, float* __restrict__ cG,  // [2][256][328] bf16 ; [2][256][304] f32
    int c)
{
  __shared__ u16 h_s[16][328];
  __shared__ float c_s[16][304];
  __shared__ float gs[16][1200];
  __shared__ u16 xstage[16][1200];
  __shared__ int L_s[16];
  const int bid = blockIdx.x;
  const int dir = bid & 1, sg = bid >> 1;
  const int r0 = sg << 4;
  const u16* pack = dir ? packB : packF;
  const u16* xpd = xp + (size_t)dir*9830400;
  const int tid = threadIdx.x;
  if (tid < 16) L_s[tid] = (r0 + tid < 128) ? l1[r0 + tid] : l2[r0 + tid - 128];
  for (int i = tid; i < 16*328; i += 512){
    const int q = i / 328, d = i - q*328;
    h_s[q][d] = (c > 0) ? hG[(size_t)(dir*256 + r0 + q)*328 + d] : (u16)0;
  }
  for (int i = tid; i < 16*300; i += 512){
    const int q = i / 300, d = i - q*300;
    c_s[q][d] = (c > 0) ? cG[(size_t)(dir*256 + r0 + q)*304 + d] : 0.0f;
  }
  __syncthreads();
  int Lmax = 0;
#pragma unroll
  for (int q = 0; q < 16; ++q) Lmax = max(Lmax, L_s[q]);
  const int t0 = c << 5;
  int nts = Lmax - t0; if (nts > 32) nts = 32;
  if (nts <= 0) return;                         // nothing to do; state in hG/cG still valid

  const int w = tid >> 6, lane = tid & 63;
  const int lq = lane >> 4, lr = lane & 15;
  const int tile0 = w * 10;
  const u16* pw = pack + (size_t)tile0*5120 + (size_t)lane*8;

  // xp staging map: i = tid + 512*j < 2400 ; q = i/150 ; col8 = (i%150)*8
  int xq[5], xc[5]; bool xv[5];
#pragma unroll
  for (int j = 0; j < 5; ++j){
    const int i = tid + (j << 9);
    xv[j] = (i < 2400);
    const int q = i / 150;
    xq[j] = q < 16 ? q : 15;
    xc[j] = (i - (q < 16 ? q : 15)*150) * 8;
  }

  // prologue: stage xp for step 0
  {
#pragma unroll
    for (int j = 0; j < 5; ++j){
      if (xv[j]){
        s16x8 v = *(const s16x8*)(xpd + (size_t)((r0 + xq[j])*32 + 0)*1200 + xc[j]);
        *(s16x8*)&xstage[xq[j]][xc[j]] = v;
      }
    }
  }
  __syncthreads();

  for (int tl = 0; tl < nts; ++tl){
    const int t = t0 + tl;
    const bool pf = (tl + 1 < nts);
    // prefetch next step's xp into regs (latency hidden under MFMA phase)
    s16x8 xr0, xr1, xr2, xr3, xr4;
    if (pf){
      if (xv[0]) xr0 = *(const s16x8*)(xpd + (size_t)((r0 + xq[0])*32 + tl + 1)*1200 + xc[0]);
      if (xv[1]) xr1 = *(const s16x8*)(xpd + (size_t)((r0 + xq[1])*32 + tl + 1)*1200 + xc[1]);
      if (xv[2]) xr2 = *(const s16x8*)(xpd + (size_t)((r0 + xq[2])*32 + tl + 1)*1200 + xc[2]);
      if (xv[3]) xr3 = *(const s16x8*)(xpd + (size_t)((r0 + xq[3])*32 + tl + 1)*1200 + xc[3]);
      if (xv[4]) xr4 = *(const s16x8*)(xpd + (size_t)((r0 + xq[4])*32 + tl + 1)*1200 + xc[4]);
    }
    // A-frags from h (10 x ds_read_b128)
    s16x8 af[10];
#pragma unroll
    for (int kt = 0; kt < 10; ++kt)
      af[kt] = *(const s16x8*)&h_s[lr][kt*32 + (lq << 3)];
    // weight-dbuf MFMA pipeline
    fx4 acc[10];
#pragma unroll
    for (int nt = 0; nt < 10; ++nt) acc[nt] = (fx4){0.f,0.f,0.f,0.f};
    s16x8 b0[10], b1[10];
#pragma unroll
    for (int nt = 0; nt < 10; ++nt) b0[nt] = *(const s16x8*)(pw + (size_t)(nt*10)*512);
#pragma unroll
    for (int kt = 0; kt < 10; ++kt){
      if (kt & 1){
        if (kt < 9){
#pragma unroll
          for (int nt = 0; nt < 10; ++nt) b0[nt] = *(const s16x8*)(pw + (size_t)(nt*10 + kt + 1)*512);
        }
#pragma unroll
        for (int nt = 0; nt < 10; ++nt)
          acc[nt] = __builtin_amdgcn_mfma_f32_16x16x32_bf16(af[kt], b1[nt], acc[nt], 0, 0, 0);
      } else {
        if (kt < 9){
#pragma unroll
          for (int nt = 0; nt < 10; ++nt) b1[nt] = *(const s16x8*)(pw + (size_t)(nt*10 + kt + 1)*512);
        }
#pragma unroll
        for (int nt = 0; nt < 10; ++nt)
          acc[nt] = __builtin_amdgcn_mfma_f32_16x16x32_bf16(af[kt], b0[nt], acc[nt], 0, 0, 0);
      }
    }
    // acc -> gs
#pragma unroll
    for (int nt = 0; nt < 10; ++nt){
      const int n = (tile0 + nt)*16 + lr;
      if (n < 1200){
#pragma unroll
        for (int reg = 0; reg < 4; ++reg)
          gs[(lq << 2) + reg][n] = acc[nt][reg];
      }
    }
    __syncthreads();
    // nonlinearity + state update + output (gate = gs + xstage)
#pragma unroll
    for (int j = 0; j < 10; ++j){
      const int u0 = tid + (j << 9);
      if (u0 < 4800){
        const int q = u0 / 300, d = u0 - q*300;
        const int L = L_s[q];
        if (t < L){
          const float gi = gs[q][d]       + us2f(xstage[q][d]);
          const float gf = gs[q][300 + d] + us2f(xstage[q][300 + d]);
          const float gg = gs[q][600 + d] + us2f(xstage[q][600 + d]);
          const float go = gs[q][900 + d] + us2f(xstage[q][900 + d]);
          const float cn = sigmf(gf)*c_s[q][d] + sigmf(gi)*tanhfast(gg);
          const float hn = sigmf(go)*tanhfast(cn);
          c_s[q][d] = cn;
          const u16 hb = f2us(hn);
          h_s[q][d] = hb;
          const int wpos = dir ? (L-1-t) : t;
          uo[(size_t)((r0 + q)*256 + wpos)*600 + dir*300 + d] = hb;
        }
      }
    }
    __syncthreads();
    // write prefetched xp regs into xstage for step tl+1
    if (pf){
      if (xv[0]) *(s16x8*)&xstage[xq[0]][xc[0]] = xr0;
      if (xv[1]) *(s16x8*)&xstage[xq[1]][xc[1]] = xr1;
      if (xv[2]) *(s16x8*)&xstage[xq[2]][xc[2]] = xr2;
      if (xv[3]) *(s16x8*)&xstage[xq[3]][xc[3]] = xr3;
      if (xv[4]) *(s16x8*)&xstage[xq[4]][xc[4]] = xr4;
    }
  }
  // persist state
  for (int i = tid; i < 16*328; i += 512){
    const int q = i / 328, d = i - q*328;
    hG[(size_t)(dir*256 + r0 + q)*328 + d] = h_s[q][d];
  }
  for (int i = tid; i < 16*300; i += 512){
    const int q = i / 300, d = i - q*300;
    cG[(size_t)(dir*256 + r0 + q)*304 + d] = c_s[q][d];
  }
}

// ---------------- softmax stats ----------------
__global__ __launch_bounds__(256) void k_row_stats(const float* __restrict__ S, const int* __restrict__ l2,
                                                   float* __restrict__ rmax, float* __restrict__ rinv)
{
  const int wid = threadIdx.x >> 6, lane = threadIdx.x & 63;
  const int row = blockIdx.x*4 + wid;
  const int b = row >> 8;
  const int L2b = l2[b];
  float4 v = *(const float4*)(S + (size_t)row*256 + lane*4);
  const int j = lane*4;
  float m = -INFINITY;
  if (j   < L2b) m = fmaxf(m, v.x);
  if (j+1 < L2b) m = fmaxf(m, v.y);
  if (j+2 < L2b) m = fmaxf(m, v.z);
  if (j+3 < L2b) m = fmaxf(m, v.w);
  for (int off = 32; off; off >>= 1) m = fmaxf(m, __shfl_xor(m, off));
  float s = 0.f;
  if (j   < L2b) s += __expf(v.x - m);
  if (j+1 < L2b) s += __expf(v.y - m);
  if (j+2 < L2b) s += __expf(v.z - m);
  if (j+3 < L2b) s += __expf(v.w - m);
  for (int off = 32; off; off >>= 1) s += __shfl_xor(s, off);
  if (lane == 0){ rmax[row] = m; rinv[row] = 1.0f/s; }
}

__global__ __launch_bounds__(256) void k_col_stats(const float* __restrict__ S, const int* __restrict__ l1,
                                                   float* __restrict__ cmax, float* __restrict__ cinv)
{
  const int b = blockIdx.x;
  const int j = threadIdx.x;
  const int L1b = l1[b];
  const float* Sb = S + (size_t)b*65536;
  float m = -INFINITY;
  for (int i = 0; i < L1b; ++i) m = fmaxf(m, Sb[(size_t)i*256 + j]);
  float s = 0.f;
  for (int i = 0; i < L1b; ++i) s += __expf(Sb[(size_t)i*256 + j] - m);
  cmax[b*256 + j] = m;
  cinv[b*256 + j] = 1.0f/s;
}

// ---------------- A1 = softmax_rows(S) @ u2 -> att bf16 ----------------
__global__ __launch_bounds__(256) void k_av_row(
    const float* __restrict__ S, const u16* __restrict__ U,
    const int* __restrict__ l1, const int* __restrict__ l2,
    const float* __restrict__ rmax, const float* __restrict__ rinv,
    u16* __restrict__ ATT)
{
  __shared__ float Ps[32][68];
  __shared__ float Us[32][68];
  const int tid = threadIdx.x;
  const int b = blockIdx.z;
  const int i0 = blockIdx.y << 6;
  const int d0 = blockIdx.x << 6;
  const int L1b = l1[b], L2b = l2[b];
  const float* Sb = S + (size_t)b*65536;
  const u16* u2 = U + (size_t)(128+b)*153600;
  const int tx = tid & 15, ty = tid >> 4;
  float acc[4][4];
#pragma unroll
  for (int i = 0; i < 4; ++i)
#pragma unroll
    for (int j = 0; j < 4; ++j) acc[i][j] = 0.0f;

  for (int kt = 0; kt < 8; ++kt){
    const int j0 = kt << 5;
#pragma unroll
    for (int q = 0; q < 2; ++q){
      const int f4 = tid + (q << 8);
      {
        const int row = f4 >> 3;
        const int c4 = (f4 & 7) << 2;
        const int i = i0 + row;
        float4 s4 = *(const float4*)(Sb + (size_t)i*256 + j0 + c4);
        const float rm = rmax[(b<<8) + i];
        const float ri = rinv[(b<<8) + i];
        const int jb = j0 + c4;
        Ps[c4  ][row] = (jb   < L2b) ? __expf(s4.x - rm)*ri : 0.0f;
        Ps[c4+1][row] = (jb+1 < L2b) ? __expf(s4.y - rm)*ri : 0.0f;
        Ps[c4+2][row] = (jb+2 < L2b) ? __expf(s4.z - rm)*ri : 0.0f;
        Ps[c4+3][row] = (jb+3 < L2b) ? __expf(s4.w - rm)*ri : 0.0f;
      }
      {
        const int row = f4 >> 4;
        const int c4 = (f4 & 15) << 2;
        const int d = d0 + c4;
        float4 v = make_float4(0.f,0.f,0.f,0.f);
        if (j0 + row < L2b){
          const u16* up = u2 + (size_t)(j0+row)*600 + d;
          if (d + 3 < 600){
            ushort4 t4 = *(const ushort4*)up;
            v.x=us2f(t4.x); v.y=us2f(t4.y); v.z=us2f(t4.z); v.w=us2f(t4.w);
          } else {
            if (d   < 600) v.x = us2f(up[0]);
            if (d+1 < 600) v.y = us2f(up[1]);
            if (d+2 < 600) v.z = us2f(up[2]);
          }
        }
        *(float4*)&Us[row][c4] = v;
      }
    }
    __syncthreads();
#pragma unroll
    for (int kk = 0; kk < 32; ++kk){
      float4 a = *(const float4*)&Ps[kk][ty<<2];
      float4 bb = *(const float4*)&Us[kk][tx<<2];
      float av[4] = {a.x,a.y,a.z,a.w};
      float bv[4] = {bb.x,bb.y,bb.z,bb.w};
#pragma unroll
      for (int ii = 0; ii < 4; ++ii)
#pragma unroll
        for (int jj = 0; jj < 4; ++jj)
          acc[ii][jj] = fmaf(av[ii], bv[jj], acc[ii][jj]);
    }
    __syncthreads();
  }
#pragma unroll
  for (int ii = 0; ii < 4; ++ii){
    const int i = i0 + (ty<<2) + ii;
#pragma unroll
    for (int jj = 0; jj < 4; ++jj){
      const int d = d0 + (tx<<2) + jj;
      if (d < 600)
        ATT[(size_t)b*153600 + (size_t)i*600 + d] = f2us((i < L1b) ? acc[ii][jj] : 0.0f);
    }
  }
}

// ---------------- A2 = softmax_cols(S)^T @ u1 -> att bf16 ----------------
__global__ __launch_bounds__(256) void k_av_col(
    const float* __restrict__ S, const u16* __restrict__ U,
    const int* __restrict__ l1, const int* __restrict__ l2,
    const float* __restrict__ cmax, const float* __restrict__ cinv,
    u16* __restrict__ ATT)
{
  __shared__ float Ps[32][68];
  __shared__ float Us[32][68];
  const int tid = threadIdx.x;
  const int b = blockIdx.z;
  const int j0v = blockIdx.y << 6;
  const int d0 = blockIdx.x << 6;
  const int L1b = l1[b], L2b = l2[b];
  const float* Sb = S + (size_t)b*65536;
  const u16* u1 = U + (size_t)b*153600;
  const int tx = tid & 15, ty = tid >> 4;
  float acc[4][4];
#pragma unroll
  for (int i = 0; i < 4; ++i)
#pragma unroll
    for (int j = 0; j < 4; ++j) acc[i][j] = 0.0f;

  for (int kt = 0; kt < 8; ++kt){
    const int i0k = kt << 5;
#pragma unroll
    for (int q = 0; q < 2; ++q){
      const int f4 = tid + (q << 8);
      const int row = f4 >> 4;
      const int c4 = (f4 & 15) << 2;
      {
        const int i = i0k + row;
        const int j = j0v + c4;
        float4 s4 = *(const float4*)(Sb + (size_t)i*256 + j);
        const bool iok = i < L1b;
        Ps[row][c4  ] = iok ? __expf(s4.x - cmax[(b<<8)+j  ])*cinv[(b<<8)+j  ] : 0.0f;
        Ps[row][c4+1] = iok ? __expf(s4.y - cmax[(b<<8)+j+1])*cinv[(b<<8)+j+1] : 0.0f;
        Ps[row][c4+2] = iok ? __expf(s4.z - cmax[(b<<8)+j+2])*cinv[(b<<8)+j+2] : 0.0f;
        Ps[row][c4+3] = iok ? __expf(s4.w - cmax[(b<<8)+j+3])*cinv[(b<<8)+j+3] : 0.0f;
      }
      {
        const int d = d0 + c4;
        float4 v = make_float4(0.f,0.f,0.f,0.f);
        if (i0k + row < L1b){
          const u16* up = u1 + (size_t)(i0k+row)*600 + d;
          if (d + 3 < 600){
            ushort4 t4 = *(const ushort4*)up;
            v.x=us2f(t4.x); v.y=us2f(t4.y); v.z=us2f(t4.z); v.w=us2f(t4.w);
          } else {
            if (d   < 600) v.x = us2f(up[0]);
            if (d+1 < 600) v.y = us2f(up[1]);
            if (d+2 < 600) v.z = us2f(up[2]);
          }
        }
        *(float4*)&Us[row][c4] = v;
      }
    }
    __syncthreads();
#pragma unroll
    for (int kk = 0; kk < 32; ++kk){
      float4 a = *(const float4*)&Ps[kk][ty<<2];
      float4 bb = *(const float4*)&Us[kk][tx<<2];
      float av[4] = {a.x,a.y,a.z,a.w};
      float bv[4] = {bb.x,bb.y,bb.z,bb.w};
#pragma unroll
      for (int ii = 0; ii < 4; ++ii)
#pragma unroll
        for (int jj = 0; jj < 4; ++jj)
          acc[ii][jj] = fmaf(av[ii], bv[jj], acc[ii][jj]);
    }
    __syncthreads();
  }
#pragma unroll
  for (int ii = 0; ii < 4; ++ii){
    const int j = j0v + (ty<<2) + ii;
#pragma unroll
    for (int jj = 0; jj < 4; ++jj){
      const int d = d0 + (tx<<2) + jj;
      if (d < 600)
        ATT[(size_t)(128+b)*153600 + (size_t)j*600 + d] = f2us((j < L2b) ? acc[ii][jj] : 0.0f);
    }
  }
}

// ---------------- masked max over time + feature build ----------------
__global__ __launch_bounds__(256) void k_maxfeat(const u16* __restrict__ y,
                                                 const int* __restrict__ l1, const int* __restrict__ l2,
                                                 float* __restrict__ feat)
{
  const int b = blockIdx.x;
  const int La = l1[b], Lb = l2[b];
  for (int c = threadIdx.x; c < 600; c += 256){
    float m1 = -INFINITY, m2 = -INFINITY;
    const u16* y1 = y + (size_t)b*153600 + c;
    for (int t = 0; t < La; ++t) m1 = fmaxf(m1, us2f(y1[(size_t)t*600]));
    const u16* y2 = y + (size_t)(128+b)*153600 + c;
    for (int t = 0; t < Lb; ++t) m2 = fmaxf(m2, us2f(y2[(size_t)t*600]));
    feat[(size_t)b*2400 + c]        = m1;
    feat[(size_t)b*2400 + 600 + c]  = m2;
    feat[(size_t)b*2400 + 1200 + c] = fabsf(m1 - m2);
    feat[(size_t)b*2400 + 1800 + c] = m1*m2;
  }
}

// ---------------- per-row MLP ----------------
__global__ __launch_bounds__(256) void k_rowgemm(const float* __restrict__ feat, const float* __restrict__ W,
                                                 const float* __restrict__ bias, float* __restrict__ out)
{
  const int b = blockIdx.x;
  __shared__ float ff[2400];
  for (int i = threadIdx.x; i < 2400; i += 256) ff[i] = feat[(size_t)b*2400 + i];
  __syncthreads();
  for (int n = threadIdx.x; n < 300; n += 256){
    const float* w = W + (size_t)n*2400;
    float acc = bias[n];
    for (int k = 0; k < 2400; k += 4){
      float4 wv = *(const float4*)(w + k);
      acc += ff[k]*wv.x + ff[k+1]*wv.y + ff[k+2]*wv.z + ff[k+3]*wv.w;
    }
    out[(size_t)b*300 + n] = fmaxf(acc, 0.0f);
  }
}

// ---------------- final ----------------
__global__ __launch_bounds__(192) void k_final(const float* __restrict__ h, const float* __restrict__ smW,
                                               const float* __restrict__ smB, float* __restrict__ out)
{
  const int b = blockIdx.x;
  const int n = threadIdx.x >> 6, lane = threadIdx.x & 63;
  float acc = 0.f;
  for (int k = lane; k < 300; k += 64) acc += h[(size_t)b*300 + k]*smW[(size_t)n*300 + k];
  for (int off = 32; off; off >>= 1) acc += __shfl_xor(acc, off);
  if (lane == 0) out[b*3 + n] = acc + smB[n];
}

extern "C" void kernel_launch(void* const* d_in, const int* in_sizes, int n_in,
                              void* d_out, int out_size, void* d_ws, size_t ws_size,
                              hipStream_t stream)
{
  (void)in_sizes; (void)n_in; (void)out_size;
  static const size_t OFF_P  = 0;             // p bf16 [65536][300]
  static const size_t OFF_B  = 39321600;      // xp1 / Smat / pc
  static const size_t OFF_U  = 78643200;      // uu/y bf16 [65536][600]
  static const size_t OFF_D  = 157286400;     // att / xp2
  static const size_t OFF_WT = 235929600;     // wih bf16 x4 (720000B each)
  static const size_t OFF_PJ = 238809600;     // projW bf16 (1440000B)
  static const size_t OFF_PK = 240249600;     // W_pack x4 (819200B each)
  static const size_t OFF_ST = 243526400;     // stats 4x32768 f32
  static const size_t OFF_FE = 244050688;     // feat
  static const size_t OFF_HM = 245279488;     // hml
  static const size_t OFF_HC = 245433088;     // hG bf16 (335872) + cG f32 (622592)
  static const size_t WS_NEEDED = 246391552;
  if (ws_size < WS_NEEDED) return;

  const int* s1 = (const int*)d_in[0];
  const int* l1 = (const int*)d_in[1];
  const int* s2 = (const int*)d_in[2];
  const int* l2 = (const int*)d_in[3];
  const float* emb    = (const float*)d_in[4];
  const float* w1f_ih = (const float*)d_in[5];
  const float* w1f_hh = (const float*)d_in[6];
  const float* b1f_ih = (const float*)d_in[7];
  const float* b1f_hh = (const float*)d_in[8];
  const float* w1b_ih = (const float*)d_in[9];
  const float* w1b_hh = (const float*)d_in[10];
  const float* b1b_ih = (const float*)d_in[11];
  const float* b1b_hh = (const float*)d_in[12];
  const float* w2f_ih = (const float*)d_in[13];
  const float* w2f_hh = (const float*)d_in[14];
  const float* b2f_ih = (const float*)d_in[15];
  const float* b2f_hh = (const float*)d_in[16];
  const float* w2b_ih = (const float*)d_in[17];
  const float* w2b_hh = (const float*)d_in[18];
  const float* b2b_ih = (const float*)d_in[19];
  const float* b2b_hh = (const float*)d_in[20];
  const float* projW  = (const float*)d_in[21];
  const float* projB  = (const float*)d_in[22];
  const float* mlpW   = (const float*)d_in[23];
  const float* mlpB   = (const float*)d_in[24];
  const float* smW    = (const float*)d_in[25];
  const float* smB    = (const float*)d_in[26];

  char* ws = (char*)d_ws;
  u16*   p    = (u16*)(ws + OFF_P);
  u16*   xp1  = (u16*)(ws + OFF_B);
  float* Smat = (float*)(ws + OFF_B);
  u16*   pc   = (u16*)(ws + OFF_B);
  u16*   uu   = (u16*)(ws + OFF_U);
  u16*   att  = (u16*)(ws + OFF_D);
  u16*   xp2  = (u16*)(ws + OFF_D);
  u16*   wih  = (u16*)(ws + OFF_WT);
  u16*   pjw  = (u16*)(ws + OFF_PJ);
  u16*   pk   = (u16*)(ws + OFF_PK);
  float* st   = (float*)(ws + OFF_ST);
  float* feat = (float*)(ws + OFF_FE);
  float* hml  = (float*)(ws + OFF_HM);
  u16*   hG   = (u16*)(ws + OFF_HC);
  float* cG   = (float*)(ws + OFF_HC + 335872);

  k_embed<<<19200, 256, 0, stream>>>(s1, s2, emb, p);
  k_cvt<<<1407, 256, 0, stream>>>(w1f_ih, wih,           360000);
  k_cvt<<<1407, 256, 0, stream>>>(w1b_ih, wih + 360000,  360000);
  k_cvt<<<1407, 256, 0, stream>>>(w2f_ih, wih + 720000,  360000);
  k_cvt<<<1407, 256, 0, stream>>>(w2b_ih, wih + 1080000, 360000);
  k_cvt<<<2813, 256, 0, stream>>>(projW,  pjw,           720000);
  k_pack<<<200, 256, 0, stream>>>(w1f_hh, pk);
  k_pack<<<200, 256, 0, stream>>>(w1b_hh, pk + 409600);
  k_pack<<<200, 256, 0, stream>>>(w2f_hh, pk + 819200);
  k_pack<<<200, 256, 0, stream>>>(w2b_hh, pk + 1228800);

  const dim3 gxp(10, 64, 2);
  for (int c = 0; c < 8; ++c){
    k_mm_xpc<<<gxp, 256, 0, stream>>>(p, wih, wih + 360000, b1f_ih, b1f_hh, b1b_ih, b1b_hh,
                                      l1, l2, xp1, c);
    k_scan_mf<<<32, 512, 0, stream>>>(xp1, pk, pk + 409600, l1, l2, uu, hG, cG, c);
  }

  k_mm_s<<<dim3(2,2,128), 256, 0, stream>>>(uu, Smat);
  k_row_stats<<<8192, 256, 0, stream>>>(Smat, l2, st, st + 32768);
  k_col_stats<<<128, 256, 0, stream>>>(Smat, l1, st + 65536, st + 98304);
  k_av_row<<<dim3(10,4,128), 256, 0, stream>>>(Smat, uu, l1, l2, st, st + 32768, att);
  k_av_col<<<dim3(10,4,128), 256, 0, stream>>>(Smat, uu, l1, l2, st + 65536, st + 98304, att);

  k_mm_proj<<<dim3(3,512,1), 256, 0, stream>>>(uu, att, pjw, projB, pc);

  for (int c = 0; c < 8; ++c){
    k_mm_xpc<<<gxp, 256, 0, stream>>>(pc, wih + 720000, wih + 1080000, b2f_ih, b2f_hh, b2b_ih, b2b_hh,
                                      l1, l2, xp2, c);
    k_scan_mf<<<32, 512, 0, stream>>>(xp2, pk + 819200, pk + 1228800, l1, l2, uu, hG, cG, c);
  }

  k_maxfeat<<<128, 256, 0, stream>>>(uu, l1, l2, feat);
  k_rowgemm<<<128, 256, 0, stream>>>(feat, mlpW, mlpB, hml);
  k_final<<<128, 192, 0, stream>>>(hml, smW, smB, (float*)d_out);
}

// Round 5
// 13842.470 us; speedup vs baseline: 3.1768x; 1.0005x over previous
//
#include <hip/hip_runtime.h>
#include <hip/hip_bf16.h>

// B=128, T=256, V=50000, D=300, H=300. 256 sample-rows (0..127 = s1, 128..255 = s2).
// MFMA bf16 pipeline; time-chunked (TC=32) xp + streaming-weight MFMA scan with
// depth-2 register weight pipeline (256-VGPR budget) + LDS xp staging.

typedef unsigned short u16;
typedef float fx4 __attribute__((ext_vector_type(4)));
typedef short s16x8 __attribute__((ext_vector_type(8)));

__device__ __forceinline__ float us2f(u16 u){
  unsigned int x = ((unsigned int)u) << 16;
  float f; __builtin_memcpy(&f, &x, 4); return f;
}
__device__ __forceinline__ u16 f2us(float f){
  unsigned int x; __builtin_memcpy(&x, &f, 4);
  unsigned int r = x + 0x7fffu + ((x >> 16) & 1u);
  return (u16)(r >> 16);
}
__device__ __forceinline__ float sigmf(float x){ return 1.0f/(1.0f + __expf(-x)); }
__device__ __forceinline__ float tanhfast(float x){ return 1.0f - 2.0f/(__expf(2.0f*x) + 1.0f); }

// ---------------- embedding gather -> p bf16 [65536][300] ----------------
__global__ __launch_bounds__(256) void k_embed(const int* __restrict__ s1, const int* __restrict__ s2,
                                               const float* __restrict__ emb, u16* __restrict__ p)
{
  int id = blockIdx.x*256 + threadIdx.x;
  if (id >= 65536*75) return;
  int row = id / 75;
  int c4 = (id - row*75) * 4;
  int tok = (row < 32768) ? s1[row] : s2[row - 32768];
  float4 v = *(const float4*)(emb + (size_t)tok*300 + c4);
  ushort4 o; o.x=f2us(v.x); o.y=f2us(v.y); o.z=f2us(v.z); o.w=f2us(v.w);
  *(ushort4*)(p + (size_t)row*300 + c4) = o;
}

// ---------------- f32 -> bf16 convert ----------------
__global__ __launch_bounds__(256) void k_cvt(const float* __restrict__ in, u16* __restrict__ out, int n)
{
  int id = blockIdx.x*256 + threadIdx.x;
  if (id < n) out[id] = f2us(in[id]);
}

// ---------------- pack Whh [1200][300] f32 into MFMA B-fragment stream ----------------
// pack[ntile(80)][ktile(10)][lane(64)][8] : value = W^T[k][n] = whh[n][k], zeros beyond.
__global__ __launch_bounds__(256) void k_pack(const float* __restrict__ W, u16* __restrict__ pack)
{
  int id = blockIdx.x*256 + threadIdx.x;       // 51200 total
  if (id >= 51200) return;
  const int lane = id & 63;
  const int kt2 = (id >> 6) % 10;
  const int nt2 = id / 640;
  const int n = nt2*16 + (lane & 15);
  u16 tmp[8];
#pragma unroll
  for (int j = 0; j < 8; ++j){
    const int k = kt2*32 + (lane >> 4)*8 + j;
    tmp[j] = (n < 1200 && k < 300) ? f2us(W[(size_t)n*300 + k]) : (u16)0;
  }
  *(s16x8*)(pack + (size_t)id*8) = *(const s16x8*)tmp;
}

// ---------------- MFMA GEMM: xp chunk ----------------
__global__ __launch_bounds__(256) void k_mm_xpc(
    const u16* __restrict__ A,                 // [65536][300] bf16 (p or pc)
    const u16* __restrict__ WFb, const u16* __restrict__ WBb,  // [1200][300] bf16
    const float* __restrict__ bF1, const float* __restrict__ bF2,
    const float* __restrict__ bB1, const float* __restrict__ bB2,
    const int* __restrict__ l1, const int* __restrict__ l2,
    u16* __restrict__ xp, int c)
{
  const int dir = blockIdx.z;
  const u16* Bw = dir ? WBb : WFb;
  const float* b1 = dir ? bB1 : bF1;
  const float* b2 = dir ? bB2 : bF2;
  u16* xpd = xp + (size_t)dir*9830400;
  __shared__ u16 As[128][40];
  __shared__ u16 Bs[128][40];
  const int tid = threadIdx.x;
  const int m0 = blockIdx.y << 7;
  const int n0 = blockIdx.x << 7;
  const int srow0 = tid >> 2;                  // 0..63
  const int kcol = (tid & 3) << 3;             // 0,8,16,24
  int src[2];
#pragma unroll
  for (int p = 0; p < 2; ++p){
    const int row = srow0 + (p << 6);
    const int ml = m0 + row;
    const int r = ml >> 5, tl = ml & 31;
    const int L = (r < 128) ? l1[r] : l2[r-128];
    const int tg = (c << 5) + tl;
    const int s = dir ? ((tg < L) ? (L-1-tg) : tg) : tg;
    src[p] = r*256 + s;
  }
  const int wv = tid >> 6;
  const int wm = (wv >> 1) << 6, wn = (wv & 1) << 6;
  const int lq = (tid >> 4) & 3;
  const int lr = tid & 15;
  fx4 acc[4][4];
#pragma unroll
  for (int i = 0; i < 4; ++i)
#pragma unroll
    for (int j = 0; j < 4; ++j) acc[i][j] = (fx4){0.f,0.f,0.f,0.f};

  for (int kt = 0; kt < 10; ++kt){
    const int k = (kt << 5) + kcol;
#pragma unroll
    for (int p = 0; p < 2; ++p){
      u16 tmp[8];
      const u16* ap = A + (size_t)src[p]*300 + k;
      if (k + 8 <= 300){
        *(ushort4*)&tmp[0] = *(const ushort4*)ap;
        *(ushort4*)&tmp[4] = *(const ushort4*)(ap + 4);
      } else {
#pragma unroll
        for (int j = 0; j < 8; ++j) tmp[j] = (k + j < 300) ? ap[j] : (u16)0;
      }
      *(s16x8*)&As[srow0 + (p << 6)][kcol] = *(const s16x8*)tmp;

      const int n = n0 + srow0 + (p << 6);
      u16 tmb[8] = {0,0,0,0,0,0,0,0};
      if (n < 1200){
        const u16* bp = Bw + (size_t)n*300 + k;
        if (k + 8 <= 300){
          *(ushort4*)&tmb[0] = *(const ushort4*)bp;
          *(ushort4*)&tmb[4] = *(const ushort4*)(bp + 4);
        } else {
#pragma unroll
          for (int j = 0; j < 8; ++j) tmb[j] = (k + j < 300) ? bp[j] : (u16)0;
        }
      }
      *(s16x8*)&Bs[srow0 + (p << 6)][kcol] = *(const s16x8*)tmb;
    }
    __syncthreads();
    s16x8 af[4], bf[4];
#pragma unroll
    for (int mi = 0; mi < 4; ++mi) af[mi] = *(const s16x8*)&As[wm + mi*16 + lr][lq << 3];
#pragma unroll
    for (int ni = 0; ni < 4; ++ni) bf[ni] = *(const s16x8*)&Bs[wn + ni*16 + lr][lq << 3];
#pragma unroll
    for (int mi = 0; mi < 4; ++mi)
#pragma unroll
      for (int ni = 0; ni < 4; ++ni)
        acc[mi][ni] = __builtin_amdgcn_mfma_f32_16x16x32_bf16(af[mi], bf[ni], acc[mi][ni], 0, 0, 0);
    __syncthreads();
  }
#pragma unroll
  for (int ni = 0; ni < 4; ++ni){
    const int n = n0 + wn + ni*16 + lr;
    if (n < 1200){
      const float bias = b1[n] + b2[n];
#pragma unroll
      for (int mi = 0; mi < 4; ++mi){
        const int m = m0 + wm + mi*16 + (lq << 2);
#pragma unroll
        for (int reg = 0; reg < 4; ++reg)
          xpd[(size_t)(m + reg)*1200 + n] = f2us(acc[mi][ni][reg] + bias);
      }
    }
  }
}

// ---------------- MFMA GEMM: S = u1 @ u2^T per b ----------------
__global__ __launch_bounds__(256) void k_mm_s(const u16* __restrict__ U, float* __restrict__ S)
{
  __shared__ u16 As[128][40];
  __shared__ u16 Bs[128][40];
  const int tid = threadIdx.x;
  const int bz = blockIdx.z;
  const u16* Ap = U + (size_t)bz*153600;
  const u16* Bp = U + (size_t)(128+bz)*153600;
  float* C = S + (size_t)bz*65536;
  const int m0 = blockIdx.y << 7;
  const int n0 = blockIdx.x << 7;
  const int srow0 = tid >> 2;
  const int kcol = (tid & 3) << 3;
  const int wv = tid >> 6;
  const int wm = (wv >> 1) << 6, wn = (wv & 1) << 6;
  const int lq = (tid >> 4) & 3;
  const int lr = tid & 15;
  fx4 acc[4][4];
#pragma unroll
  for (int i = 0; i < 4; ++i)
#pragma unroll
    for (int j = 0; j < 4; ++j) acc[i][j] = (fx4){0.f,0.f,0.f,0.f};

  for (int kt = 0; kt < 19; ++kt){
    const int k = (kt << 5) + kcol;
#pragma unroll
    for (int p = 0; p < 2; ++p){
      const int row = srow0 + (p << 6);
      u16 tma[8] = {0,0,0,0,0,0,0,0};
      u16 tmb[8] = {0,0,0,0,0,0,0,0};
      if (k + 8 <= 600){
        *(s16x8*)tma = *(const s16x8*)(Ap + (size_t)(m0 + row)*600 + k);
        *(s16x8*)tmb = *(const s16x8*)(Bp + (size_t)(n0 + row)*600 + k);
      }
      *(s16x8*)&As[row][kcol] = *(const s16x8*)tma;
      *(s16x8*)&Bs[row][kcol] = *(const s16x8*)tmb;
    }
    __syncthreads();
    s16x8 af[4], bf[4];
#pragma unroll
    for (int mi = 0; mi < 4; ++mi) af[mi] = *(const s16x8*)&As[wm + mi*16 + lr][lq << 3];
#pragma unroll
    for (int ni = 0; ni < 4; ++ni) bf[ni] = *(const s16x8*)&Bs[wn + ni*16 + lr][lq << 3];
#pragma unroll
    for (int mi = 0; mi < 4; ++mi)
#pragma unroll
      for (int ni = 0; ni < 4; ++ni)
        acc[mi][ni] = __builtin_amdgcn_mfma_f32_16x16x32_bf16(af[mi], bf[ni], acc[mi][ni], 0, 0, 0);
    __syncthreads();
  }
#pragma unroll
  for (int mi = 0; mi < 4; ++mi){
    const int m = m0 + wm + mi*16 + (lq << 2);
#pragma unroll
    for (int ni = 0; ni < 4; ++ni){
      const int n = n0 + wn + ni*16 + lr;
#pragma unroll
      for (int reg = 0; reg < 4; ++reg)
        C[(size_t)(m + reg)*256 + n] = acc[mi][ni][reg];
    }
  }
}

// ---------------- MFMA GEMM: pc = relu([u,A,u-A,u*A] @ projW^T + projB) ----------------
__global__ __launch_bounds__(256) void k_mm_proj(
    const u16* __restrict__ U, const u16* __restrict__ ATT,
    const u16* __restrict__ Bw,                // projW bf16 [300][2400]
    const float* __restrict__ bias,
    u16* __restrict__ C)
{
  __shared__ u16 As[128][40];
  __shared__ u16 Bs[128][40];
  const int tid = threadIdx.x;
  const int m0 = blockIdx.y << 7;
  const int n0 = blockIdx.x << 7;
  const int srow0 = tid >> 2;
  const int kcol = (tid & 3) << 3;
  const int wv = tid >> 6;
  const int wm = (wv >> 1) << 6, wn = (wv & 1) << 6;
  const int lq = (tid >> 4) & 3;
  const int lr = tid & 15;
  fx4 acc[4][4];
#pragma unroll
  for (int i = 0; i < 4; ++i)
#pragma unroll
    for (int j = 0; j < 4; ++j) acc[i][j] = (fx4){0.f,0.f,0.f,0.f};

  for (int kt = 0; kt < 75; ++kt){
    const int k = (kt << 5) + kcol;
    const int seg = k / 600;
    const int off = k - seg*600;
#pragma unroll
    for (int p = 0; p < 2; ++p){
      const int row = srow0 + (p << 6);
      const size_t base = (size_t)(m0 + row)*600 + off;
      u16 uu8[8], aa8[8], tma[8];
      *(s16x8*)uu8 = *(const s16x8*)(U + base);
      *(s16x8*)aa8 = *(const s16x8*)(ATT + base);
      if (seg == 0){
#pragma unroll
        for (int j = 0; j < 8; ++j) tma[j] = uu8[j];
      } else if (seg == 1){
#pragma unroll
        for (int j = 0; j < 8; ++j) tma[j] = aa8[j];
      } else if (seg == 2){
#pragma unroll
        for (int j = 0; j < 8; ++j) tma[j] = f2us(us2f(uu8[j]) - us2f(aa8[j]));
      } else {
#pragma unroll
        for (int j = 0; j < 8; ++j) tma[j] = f2us(us2f(uu8[j]) * us2f(aa8[j]));
      }
      *(s16x8*)&As[row][kcol] = *(const s16x8*)tma;

      const int n = n0 + row;
      u16 tmb[8] = {0,0,0,0,0,0,0,0};
      if (n < 300)
        *(s16x8*)tmb = *(const s16x8*)(Bw + (size_t)n*2400 + k);
      *(s16x8*)&Bs[row][kcol] = *(const s16x8*)tmb;
    }
    __syncthreads();
    s16x8 af[4], bf[4];
#pragma unroll
    for (int mi = 0; mi < 4; ++mi) af[mi] = *(const s16x8*)&As[wm + mi*16 + lr][lq << 3];
#pragma unroll
    for (int ni = 0; ni < 4; ++ni) bf[ni] = *(const s16x8*)&Bs[wn + ni*16 + lr][lq << 3];
#pragma unroll
    for (int mi = 0; mi < 4; ++mi)
#pragma unroll
      for (int ni = 0; ni < 4; ++ni)
        acc[mi][ni] = __builtin_amdgcn_mfma_f32_16x16x32_bf16(af[mi], bf[ni], acc[mi][ni], 0, 0, 0);
    __syncthreads();
  }
#pragma unroll
  for (int ni = 0; ni < 4; ++ni){
    const int n = n0 + wn + ni*16 + lr;
    if (n < 300){
      const float bs = bias[n];
#pragma unroll
      for (int mi = 0; mi < 4; ++mi){
        const int m = m0 + wm + mi*16 + (lq << 2);
#pragma unroll
        for (int reg = 0; reg < 4; ++reg)
          C[(size_t)(m + reg)*300 + n] = f2us(fmaxf(acc[mi][ni][reg] + bs, 0.0f));
      }
    }
  }
}

// ---------------- MFMA streaming scan (depth-2 weight pipeline): 32 WGs x 512 thr ----------------
__global__ __launch_bounds__(512, 2) void k_scan_mf(
    const u16* __restrict__ xp,                // [2][8192][1200] bf16 (chunk-gathered)
    const u16* __restrict__ packF, const u16* __restrict__ packB, // [80][10][64][8]
    const int* __restrict__ l1, const int* __restrict__ l2,
    u16* __restrict__ uo,                      // [65536][600] bf16
    u16* __restrict__ hG, float* __restrict__ cG,  // [2][256][328] bf16 ; [2][256][304] f32
    int c)
{
  __shared__ u16 h_s[16][328];
  __shared__ float c_s[16][304];
  __shared__ float gs[16][1200];
  __shared__ u16 xstage[16][1200];
  __shared__ int L_s[16];
  const int bid = blockIdx.x;
  const int dir = bid & 1, sg = bid >> 1;
  const int r0 = sg << 4;
  const u16* pack = dir ? packB : packF;
  const u16* xpd = xp + (size_t)dir*9830400;
  const int tid = threadIdx.x;
  if (tid < 16) L_s[tid] = (r0 + tid < 128) ? l1[r0 + tid] : l2[r0 + tid - 128];
  for (int i = tid; i < 16*328; i += 512){
    const int q = i / 328, d = i - q*328;
    h_s[q][d] = (c > 0) ? hG[(size_t)(dir*256 + r0 + q)*328 + d] : (u16)0;
  }
  for (int i = tid; i < 16*300; i += 512){
    const int q = i / 300, d = i - q*300;
    c_s[q][d] = (c > 0) ? cG[(size_t)(dir*256 + r0 + q)*304 + d] : 0.0f;
  }
  __syncthreads();
  int Lmax = 0;
#pragma unroll
  for (int q = 0; q < 16; ++q) Lmax = max(Lmax, L_s[q]);
  const int t0 = c << 5;
  int nts = Lmax - t0; if (nts > 32) nts = 32;
  if (nts <= 0) return;                         // nothing to do; state in hG/cG still valid

  const int w = tid >> 6, lane = tid & 63;
  const int lq = lane >> 4, lr = lane & 15;
  const int tile0 = w * 10;
  const u16* pw = pack + (size_t)tile0*5120 + (size_t)lane*8;

  // xp staging map: i = tid + 512*j < 2400 ; q = i/150 ; col8 = (i%150)*8
  int xq[5], xc[5]; bool xv[5];
#pragma unroll
  for (int j = 0; j < 5; ++j){
    const int i = tid + (j << 9);
    xv[j] = (i < 2400);
    const int q = i / 150;
    xq[j] = q < 16 ? q : 15;
    xc[j] = (i - (q < 16 ? q : 15)*150) * 8;
  }

  // prologue: stage xp for step 0
  {
#pragma unroll
    for (int j = 0; j < 5; ++j){
      if (xv[j]){
        s16x8 v = *(const s16x8*)(xpd + (size_t)((r0 + xq[j])*32 + 0)*1200 + xc[j]);
        *(s16x8*)&xstage[xq[j]][xc[j]] = v;
      }
    }
  }
  __syncthreads();

  for (int tl = 0; tl < nts; ++tl){
    const int t = t0 + tl;
    const bool pf = (tl + 1 < nts);
    // prefetch next step's xp into regs (latency hidden under MFMA phase)
    s16x8 xr0, xr1, xr2, xr3, xr4;
    if (pf){
      if (xv[0]) xr0 = *(const s16x8*)(xpd + (size_t)((r0 + xq[0])*32 + tl + 1)*1200 + xc[0]);
      if (xv[1]) xr1 = *(const s16x8*)(xpd + (size_t)((r0 + xq[1])*32 + tl + 1)*1200 + xc[1]);
      if (xv[2]) xr2 = *(const s16x8*)(xpd + (size_t)((r0 + xq[2])*32 + tl + 1)*1200 + xc[2]);
      if (xv[3]) xr3 = *(const s16x8*)(xpd + (size_t)((r0 + xq[3])*32 + tl + 1)*1200 + xc[3]);
      if (xv[4]) xr4 = *(const s16x8*)(xpd + (size_t)((r0 + xq[4])*32 + tl + 1)*1200 + xc[4]);
    }
    // depth-2 weight pipeline: 3 rotating 10-fragment buffers, fully unrolled kt loop
    fx4 acc[10];
#pragma unroll
    for (int nt = 0; nt < 10; ++nt) acc[nt] = (fx4){0.f,0.f,0.f,0.f};
    s16x8 wb[3][10];
#pragma unroll
    for (int nt = 0; nt < 10; ++nt) wb[0][nt] = *(const s16x8*)(pw + (size_t)(nt*10 + 0)*512);
#pragma unroll
    for (int nt = 0; nt < 10; ++nt) wb[1][nt] = *(const s16x8*)(pw + (size_t)(nt*10 + 1)*512);
#pragma unroll
    for (int kt = 0; kt < 10; ++kt){
      const int cur = kt % 3;
      const int nxt = (kt + 2) % 3;
      if (kt < 8){
#pragma unroll
        for (int nt = 0; nt < 10; ++nt) wb[nxt][nt] = *(const s16x8*)(pw + (size_t)(nt*10 + kt + 2)*512);
      }
      const s16x8 a = *(const s16x8*)&h_s[lr][kt*32 + (lq << 3)];
#pragma unroll
      for (int nt = 0; nt < 10; ++nt)
        acc[nt] = __builtin_amdgcn_mfma_f32_16x16x32_bf16(a, wb[cur][nt], acc[nt], 0, 0, 0);
    }
    // acc -> gs
#pragma unroll
    for (int nt = 0; nt < 10; ++nt){
      const int n = (tile0 + nt)*16 + lr;
      if (n < 1200){
#pragma unroll
        for (int reg = 0; reg < 4; ++reg)
          gs[(lq << 2) + reg][n] = acc[nt][reg];
      }
    }
    __syncthreads();
    // nonlinearity + state update + output (gate = gs + xstage)
#pragma unroll
    for (int j = 0; j < 10; ++j){
      const int u0 = tid + (j << 9);
      if (u0 < 4800){
        const int q = u0 / 300, d = u0 - q*300;
        const int L = L_s[q];
        if (t < L){
          const float gi = gs[q][d]       + us2f(xstage[q][d]);
          const float gf = gs[q][300 + d] + us2f(xstage[q][300 + d]);
          const float gg = gs[q][600 + d] + us2f(xstage[q][600 + d]);
          const float go = gs[q][900 + d] + us2f(xstage[q][900 + d]);
          const float cn = sigmf(gf)*c_s[q][d] + sigmf(gi)*tanhfast(gg);
          const float hn = sigmf(go)*tanhfast(cn);
          c_s[q][d] = cn;
          const u16 hb = f2us(hn);
          h_s[q][d] = hb;
          const int wpos = dir ? (L-1-t) : t;
          uo[(size_t)((r0 + q)*256 + wpos)*600 + dir*300 + d] = hb;
        }
      }
    }
    __syncthreads();
    // write prefetched xp regs into xstage for step tl+1
    if (pf){
      if (xv[0]) *(s16x8*)&xstage[xq[0]][xc[0]] = xr0;
      if (xv[1]) *(s16x8*)&xstage[xq[1]][xc[1]] = xr1;
      if (xv[2]) *(s16x8*)&xstage[xq[2]][xc[2]] = xr2;
      if (xv[3]) *(s16x8*)&xstage[xq[3]][xc[3]] = xr3;
      if (xv[4]) *(s16x8*)&xstage[xq[4]][xc[4]] = xr4;
    }
  }
  // persist state
  for (int i = tid; i < 16*328; i += 512){
    const int q = i / 328, d = i - q*328;
    hG[(size_t)(dir*256 + r0 + q)*328 + d] = h_s[q][d];
  }
  for (int i = tid; i < 16*300; i += 512){
    const int q = i / 300, d = i - q*300;
    cG[(size_t)(dir*256 + r0 + q)*304 + d] = c_s[q][d];
  }
}

// ---------------- softmax stats ----------------
__global__ __launch_bounds__(256) void k_row_stats(const float* __restrict__ S, const int* __restrict__ l2,
                                                   float* __restrict__ rmax, float* __restrict__ rinv)
{
  const int wid = threadIdx.x >> 6, lane = threadIdx.x & 63;
  const int row = blockIdx.x*4 + wid;
  const int b = row >> 8;
  const int L2b = l2[b];
  float4 v = *(const float4*)(S + (size_t)row*256 + lane*4);
  const int j = lane*4;
  float m = -INFINITY;
  if (j   < L2b) m = fmaxf(m, v.x);
  if (j+1 < L2b) m = fmaxf(m, v.y);
  if (j+2 < L2b) m = fmaxf(m, v.z);
  if (j+3 < L2b) m = fmaxf(m, v.w);
  for (int off = 32; off; off >>= 1) m = fmaxf(m, __shfl_xor(m, off));
  float s = 0.f;
  if (j   < L2b) s += __expf(v.x - m);
  if (j+1 < L2b) s += __expf(v.y - m);
  if (j+2 < L2b) s += __expf(v.z - m);
  if (j+3 < L2b) s += __expf(v.w - m);
  for (int off = 32; off; off >>= 1) s += __shfl_xor(s, off);
  if (lane == 0){ rmax[row] = m; rinv[row] = 1.0f/s; }
}

__global__ __launch_bounds__(256) void k_col_stats(const float* __restrict__ S, const int* __restrict__ l1,
                                                   float* __restrict__ cmax, float* __restrict__ cinv)
{
  const int b = blockIdx.x;
  const int j = threadIdx.x;
  const int L1b = l1[b];
  const float* Sb = S + (size_t)b*65536;
  float m = -INFINITY;
  for (int i = 0; i < L1b; ++i) m = fmaxf(m, Sb[(size_t)i*256 + j]);
  float s = 0.f;
  for (int i = 0; i < L1b; ++i) s += __expf(Sb[(size_t)i*256 + j] - m);
  cmax[b*256 + j] = m;
  cinv[b*256 + j] = 1.0f/s;
}

// ---------------- A1 = softmax_rows(S) @ u2 -> att bf16 ----------------
__global__ __launch_bounds__(256) void k_av_row(
    const float* __restrict__ S, const u16* __restrict__ U,
    const int* __restrict__ l1, const int* __restrict__ l2,
    const float* __restrict__ rmax, const float* __restrict__ rinv,
    u16* __restrict__ ATT)
{
  __shared__ float Ps[32][68];
  __shared__ float Us[32][68];
  const int tid = threadIdx.x;
  const int b = blockIdx.z;
  const int i0 = blockIdx.y << 6;
  const int d0 = blockIdx.x << 6;
  const int L1b = l1[b], L2b = l2[b];
  const float* Sb = S + (size_t)b*65536;
  const u16* u2 = U + (size_t)(128+b)*153600;
  const int tx = tid & 15, ty = tid >> 4;
  float acc[4][4];
#pragma unroll
  for (int i = 0; i < 4; ++i)
#pragma unroll
    for (int j = 0; j < 4; ++j) acc[i][j] = 0.0f;

  for (int kt = 0; kt < 8; ++kt){
    const int j0 = kt << 5;
#pragma unroll
    for (int q = 0; q < 2; ++q){
      const int f4 = tid + (q << 8);
      {
        const int row = f4 >> 3;
        const int c4 = (f4 & 7) << 2;
        const int i = i0 + row;
        float4 s4 = *(const float4*)(Sb + (size_t)i*256 + j0 + c4);
        const float rm = rmax[(b<<8) + i];
        const float ri = rinv[(b<<8) + i];
        const int jb = j0 + c4;
        Ps[c4  ][row] = (jb   < L2b) ? __expf(s4.x - rm)*ri : 0.0f;
        Ps[c4+1][row] = (jb+1 < L2b) ? __expf(s4.y - rm)*ri : 0.0f;
        Ps[c4+2][row] = (jb+2 < L2b) ? __expf(s4.z - rm)*ri : 0.0f;
        Ps[c4+3][row] = (jb+3 < L2b) ? __expf(s4.w - rm)*ri : 0.0f;
      }
      {
        const int row = f4 >> 4;
        const int c4 = (f4 & 15) << 2;
        const int d = d0 + c4;
        float4 v = make_float4(0.f,0.f,0.f,0.f);
        if (j0 + row < L2b){
          const u16* up = u2 + (size_t)(j0+row)*600 + d;
          if (d + 3 < 600){
            ushort4 t4 = *(const ushort4*)up;
            v.x=us2f(t4.x); v.y=us2f(t4.y); v.z=us2f(t4.z); v.w=us2f(t4.w);
          } else {
            if (d   < 600) v.x = us2f(up[0]);
            if (d+1 < 600) v.y = us2f(up[1]);
            if (d+2 < 600) v.z = us2f(up[2]);
          }
        }
        *(float4*)&Us[row][c4] = v;
      }
    }
    __syncthreads();
#pragma unroll
    for (int kk = 0; kk < 32; ++kk){
      float4 a = *(const float4*)&Ps[kk][ty<<2];
      float4 bb = *(const float4*)&Us[kk][tx<<2];
      float av[4] = {a.x,a.y,a.z,a.w};
      float bv[4] = {bb.x,bb.y,bb.z,bb.w};
#pragma unroll
      for (int ii = 0; ii < 4; ++ii)
#pragma unroll
        for (int jj = 0; jj < 4; ++jj)
          acc[ii][jj] = fmaf(av[ii], bv[jj], acc[ii][jj]);
    }
    __syncthreads();
  }
#pragma unroll
  for (int ii = 0; ii < 4; ++ii){
    const int i = i0 + (ty<<2) + ii;
#pragma unroll
    for (int jj = 0; jj < 4; ++jj){
      const int d = d0 + (tx<<2) + jj;
      if (d < 600)
        ATT[(size_t)b*153600 + (size_t)i*600 + d] = f2us((i < L1b) ? acc[ii][jj] : 0.0f);
    }
  }
}

// ---------------- A2 = softmax_cols(S)^T @ u1 -> att bf16 ----------------
__global__ __launch_bounds__(256) void k_av_col(
    const float* __restrict__ S, const u16* __restrict__ U,
    const int* __restrict__ l1, const int* __restrict__ l2,
    const float* __restrict__ cmax, const float* __restrict__ cinv,
    u16* __restrict__ ATT)
{
  __shared__ float Ps[32][68];
  __shared__ float Us[32][68];
  const int tid = threadIdx.x;
  const int b = blockIdx.z;
  const int j0v = blockIdx.y << 6;
  const int d0 = blockIdx.x << 6;
  const int L1b = l1[b], L2b = l2[b];
  const float* Sb = S + (size_t)b*65536;
  const u16* u1 = U + (size_t)b*153600;
  const int tx = tid & 15, ty = tid >> 4;
  float acc[4][4];
#pragma unroll
  for (int i = 0; i < 4; ++i)
#pragma unroll
    for (int j = 0; j < 4; ++j) acc[i][j] = 0.0f;

  for (int kt = 0; kt < 8; ++kt){
    const int i0k = kt << 5;
#pragma unroll
    for (int q = 0; q < 2; ++q){
      const int f4 = tid + (q << 8);
      const int row = f4 >> 4;
      const int c4 = (f4 & 15) << 2;
      {
        const int i = i0k + row;
        const int j = j0v + c4;
        float4 s4 = *(const float4*)(Sb + (size_t)i*256 + j);
        const bool iok = i < L1b;
        Ps[row][c4  ] = iok ? __expf(s4.x - cmax[(b<<8)+j  ])*cinv[(b<<8)+j  ] : 0.0f;
        Ps[row][c4+1] = iok ? __expf(s4.y - cmax[(b<<8)+j+1])*cinv[(b<<8)+j+1] : 0.0f;
        Ps[row][c4+2] = iok ? __expf(s4.z - cmax[(b<<8)+j+2])*cinv[(b<<8)+j+2] : 0.0f;
        Ps[row][c4+3] = iok ? __expf(s4.w - cmax[(b<<8)+j+3])*cinv[(b<<8)+j+3] : 0.0f;
      }
      {
        const int d = d0 + c4;
        float4 v = make_float4(0.f,0.f,0.f,0.f);
        if (i0k + row < L1b){
          const u16* up = u1 + (size_t)(i0k+row)*600 + d;
          if (d + 3 < 600){
            ushort4 t4 = *(const ushort4*)up;
            v.x=us2f(t4.x); v.y=us2f(t4.y); v.z=us2f(t4.z); v.w=us2f(t4.w);
          } else {
            if (d   < 600) v.x = us2f(up[0]);
            if (d+1 < 600) v.y = us2f(up[1]);
            if (d+2 < 600) v.z = us2f(up[2]);
          }
        }
        *(float4*)&Us[row][c4] = v;
      }
    }
    __syncthreads();
#pragma unroll
    for (int kk = 0; kk < 32; ++kk){
      float4 a = *(const float4*)&Ps[kk][ty<<2];
      float4 bb = *(const float4*)&Us[kk][tx<<2];
      float av[4] = {a.x,a.y,a.z,a.w};
      float bv[4] = {bb.x,bb.y,bb.z,bb.w};
#pragma unroll
      for (int ii = 0; ii < 4; ++ii)
#pragma unroll
        for (int jj = 0; jj < 4; ++jj)
          acc[ii][jj] = fmaf(av[ii], bv[jj], acc[ii][jj]);
    }
    __syncthreads();
  }
#pragma unroll
  for (int ii = 0; ii < 4; ++ii){
    const int j = j0v + (ty<<2) + ii;
#pragma unroll
    for (int jj = 0; jj < 4; ++jj){
      const int d = d0 + (tx<<2) + jj;
      if (d < 600)
        ATT[(size_t)(128+b)*153600 + (size_t)j*600 + d] = f2us((j < L2b) ? acc[ii][jj] : 0.0f);
    }
  }
}

// ---------------- masked max over time + feature build ----------------
__global__ __launch_bounds__(256) void k_maxfeat(const u16* __restrict__ y,
                                                 const int* __restrict__ l1, const int* __restrict__ l2,
                                                 float* __restrict__ feat)
{
  const int b = blockIdx.x;
  const int La = l1[b], Lb = l2[b];
  for (int c = threadIdx.x; c < 600; c += 256){
    float m1 = -INFINITY, m2 = -INFINITY;
    const u16* y1 = y + (size_t)b*153600 + c;
    for (int t = 0; t < La; ++t) m1 = fmaxf(m1, us2f(y1[(size_t)t*600]));
    const u16* y2 = y + (size_t)(128+b)*153600 + c;
    for (int t = 0; t < Lb; ++t) m2 = fmaxf(m2, us2f(y2[(size_t)t*600]));
    feat[(size_t)b*2400 + c]        = m1;
    feat[(size_t)b*2400 + 600 + c]  = m2;
    feat[(size_t)b*2400 + 1200 + c] = fabsf(m1 - m2);
    feat[(size_t)b*2400 + 1800 + c] = m1*m2;
  }
}

// ---------------- per-row MLP ----------------
__global__ __launch_bounds__(256) void k_rowgemm(const float* __restrict__ feat, const float* __restrict__ W,
                                                 const float* __restrict__ bias, float* __restrict__ out)
{
  const int b = blockIdx.x;
  __shared__ float ff[2400];
  for (int i = threadIdx.x; i < 2400; i += 256) ff[i] = feat[(size_t)b*2400 + i];
  __syncthreads();
  for (int n = threadIdx.x; n < 300; n += 256){
    const float* w = W + (size_t)n*2400;
    float acc = bias[n];
    for (int k = 0; k < 2400; k += 4){
      float4 wv = *(const float4*)(w + k);
      acc += ff[k]*wv.x + ff[k+1]*wv.y + ff[k+2]*wv.z + ff[k+3]*wv.w;
    }
    out[(size_t)b*300 + n] = fmaxf(acc, 0.0f);
  }
}

// ---------------- final ----------------
__global__ __launch_bounds__(192) void k_final(const float* __restrict__ h, const float* __restrict__ smW,
                                               const float* __restrict__ smB, float* __restrict__ out)
{
  const int b = blockIdx.x;
  const int n = threadIdx.x >> 6, lane = threadIdx.x & 63;
  float acc = 0.f;
  for (int k = lane; k < 300; k += 64) acc += h[(size_t)b*300 + k]*smW[(size_t)n*300 + k];
  for (int off = 32; off; off >>= 1) acc += __shfl_xor(acc, off);
  if (lane == 0) out[b*3 + n] = acc + smB[n];
}

extern "C" void kernel_launch(void* const* d_in, const int* in_sizes, int n_in,
                              void* d_out, int out_size, void* d_ws, size_t ws_size,
                              hipStream_t stream)
{
  (void)in_sizes; (void)n_in; (void)out_size;
  static const size_t OFF_P  = 0;             // p bf16 [65536][300]
  static const size_t OFF_B  = 39321600;      // xp1 / Smat / pc
  static const size_t OFF_U  = 78643200;      // uu/y bf16 [65536][600]
  static const size_t OFF_D  = 157286400;     // att / xp2
  static const size_t OFF_WT = 235929600;     // wih bf16 x4 (720000B each)
  static const size_t OFF_PJ = 238809600;     // projW bf16 (1440000B)
  static const size_t OFF_PK = 240249600;     // W_pack x4 (819200B each)
  static const size_t OFF_ST = 243526400;     // stats 4x32768 f32
  static const size_t OFF_FE = 244050688;     // feat
  static const size_t OFF_HM = 245279488;     // hml
  static const size_t OFF_HC = 245433088;     // hG bf16 (335872) + cG f32 (622592)
  static const size_t WS_NEEDED = 246391552;
  if (ws_size < WS_NEEDED) return;

  const int* s1 = (const int*)d_in[0];
  const int* l1 = (const int*)d_in[1];
  const int* s2 = (const int*)d_in[2];
  const int* l2 = (const int*)d_in[3];
  const float* emb    = (const float*)d_in[4];
  const float* w1f_ih = (const float*)d_in[5];
  const float* w1f_hh = (const float*)d_in[6];
  const float* b1f_ih = (const float*)d_in[7];
  const float* b1f_hh = (const float*)d_in[8];
  const float* w1b_ih = (const float*)d_in[9];
  const float* w1b_hh = (const float*)d_in[10];
  const float* b1b_ih = (const float*)d_in[11];
  const float* b1b_hh = (const float*)d_in[12];
  const float* w2f_ih = (const float*)d_in[13];
  const float* w2f_hh = (const float*)d_in[14];
  const float* b2f_ih = (const float*)d_in[15];
  const float* b2f_hh = (const float*)d_in[16];
  const float* w2b_ih = (const float*)d_in[17];
  const float* w2b_hh = (const float*)d_in[18];
  const float* b2b_ih = (const float*)d_in[19];
  const float* b2b_hh = (const float*)d_in[20];
  const float* projW  = (const float*)d_in[21];
  const float* projB  = (const float*)d_in[22];
  const float* mlpW   = (const float*)d_in[23];
  const float* mlpB   = (const float*)d_in[24];
  const float* smW    = (const float*)d_in[25];
  const float* smB    = (const float*)d_in[26];

  char* ws = (char*)d_ws;
  u16*   p    = (u16*)(ws + OFF_P);
  u16*   xp1  = (u16*)(ws + OFF_B);
  float* Smat = (float*)(ws + OFF_B);
  u16*   pc   = (u16*)(ws + OFF_B);
  u16*   uu   = (u16*)(ws + OFF_U);
  u16*   att  = (u16*)(ws + OFF_D);
  u16*   xp2  = (u16*)(ws + OFF_D);
  u16*   wih  = (u16*)(ws + OFF_WT);
  u16*   pjw  = (u16*)(ws + OFF_PJ);
  u16*   pk   = (u16*)(ws + OFF_PK);
  float* st   = (float*)(ws + OFF_ST);
  float* feat = (float*)(ws + OFF_FE);
  float* hml  = (float*)(ws + OFF_HM);
  u16*   hG   = (u16*)(ws + OFF_HC);
  float* cG   = (float*)(ws + OFF_HC + 335872);

  k_embed<<<19200, 256, 0, stream>>>(s1, s2, emb, p);
  k_cvt<<<1407, 256, 0, stream>>>(w1f_ih, wih,           360000);
  k_cvt<<<1407, 256, 0, stream>>>(w1b_ih, wih + 360000,  360000);
  k_cvt<<<1407, 256, 0, stream>>>(w2f_ih, wih + 720000,  360000);
  k_cvt<<<1407, 256, 0, stream>>>(w2b_ih, wih + 1080000, 360000);
  k_cvt<<<2813, 256, 0, stream>>>(projW,  pjw,           720000);
  k_pack<<<200, 256, 0, stream>>>(w1f_hh, pk);
  k_pack<<<200, 256, 0, stream>>>(w1b_hh, pk + 409600);
  k_pack<<<200, 256, 0, stream>>>(w2f_hh, pk + 819200);
  k_pack<<<200, 256, 0, stream>>>(w2b_hh, pk + 1228800);

  const dim3 gxp(10, 64, 2);
  for (int c = 0; c < 8; ++c){
    k_mm_xpc<<<gxp, 256, 0, stream>>>(p, wih, wih + 360000, b1f_ih, b1f_hh, b1b_ih, b1b_hh,
                                      l1, l2, xp1, c);
    k_scan_mf<<<32, 512, 0, stream>>>(xp1, pk, pk + 409600, l1, l2, uu, hG, cG, c);
  }

  k_mm_s<<<dim3(2,2,128), 256, 0, stream>>>(uu, Smat);
  k_row_stats<<<8192, 256, 0, stream>>>(Smat, l2, st, st + 32768);
  k_col_stats<<<128, 256, 0, stream>>>(Smat, l1, st + 65536, st + 98304);
  k_av_row<<<dim3(10,4,128), 256, 0, stream>>>(Smat, uu, l1, l2, st, st + 32768, att);
  k_av_col<<<dim3(10,4,128), 256, 0, stream>>>(Smat, uu, l1, l2, st + 65536, st + 98304, att);

  k_mm_proj<<<dim3(3,512,1), 256, 0, stream>>>(uu, att, pjw, projB, pc);

  for (int c = 0; c < 8; ++c){
    k_mm_xpc<<<gxp, 256, 0, stream>>>(pc, wih + 720000, wih + 1080000, b2f_ih, b2f_hh, b2b_ih, b2b_hh,
                                      l1, l2, xp2, c);
    k_scan_mf<<<32, 512, 0, stream>>>(xp2, pk + 819200, pk + 1228800, l1, l2, uu, hG, cG, c);
  }

  k_maxfeat<<<128, 256, 0, stream>>>(uu, l1, l2, feat);
  k_rowgemm<<<128, 256, 0, stream>>>(feat, mlpW, mlpB, hml);
  k_final<<<128, 192, 0, stream>>>(hml, smW, smB, (float*)d_out);
}

// Round 6
// 13840.796 us; speedup vs baseline: 3.1772x; 1.0001x over previous
//
#include <hip/hip_runtime.h>
#include <hip/hip_bf16.h>

// B=128, T=256, V=50000, D=300, H=300. 256 sample-rows (0..127 = s1, 128..255 = s2).
// MFMA bf16 pipeline; time-chunked (TC=32) xp + streaming-weight MFMA scan with
// even/odd register weight double-buffer (256-VGPR budget) + LDS xp staging.

typedef unsigned short u16;
typedef float fx4 __attribute__((ext_vector_type(4)));
typedef short s16x8 __attribute__((ext_vector_type(8)));

__device__ __forceinline__ float us2f(u16 u){
  unsigned int x = ((unsigned int)u) << 16;
  float f; __builtin_memcpy(&f, &x, 4); return f;
}
__device__ __forceinline__ u16 f2us(float f){
  unsigned int x; __builtin_memcpy(&x, &f, 4);
  unsigned int r = x + 0x7fffu + ((x >> 16) & 1u);
  return (u16)(r >> 16);
}
__device__ __forceinline__ float sigmf(float x){ return 1.0f/(1.0f + __expf(-x)); }
__device__ __forceinline__ float tanhfast(float x){ return 1.0f - 2.0f/(__expf(2.0f*x) + 1.0f); }

// ---------------- embedding gather -> p bf16 [65536][300] ----------------
__global__ __launch_bounds__(256) void k_embed(const int* __restrict__ s1, const int* __restrict__ s2,
                                               const float* __restrict__ emb, u16* __restrict__ p)
{
  int id = blockIdx.x*256 + threadIdx.x;
  if (id >= 65536*75) return;
  int row = id / 75;
  int c4 = (id - row*75) * 4;
  int tok = (row < 32768) ? s1[row] : s2[row - 32768];
  float4 v = *(const float4*)(emb + (size_t)tok*300 + c4);
  ushort4 o; o.x=f2us(v.x); o.y=f2us(v.y); o.z=f2us(v.z); o.w=f2us(v.w);
  *(ushort4*)(p + (size_t)row*300 + c4) = o;
}

// ---------------- f32 -> bf16 convert ----------------
__global__ __launch_bounds__(256) void k_cvt(const float* __restrict__ in, u16* __restrict__ out, int n)
{
  int id = blockIdx.x*256 + threadIdx.x;
  if (id < n) out[id] = f2us(in[id]);
}

// ---------------- pack Whh [1200][300] f32 into MFMA B-fragment stream ----------------
// pack[ntile(80)][ktile(10)][lane(64)][8] : value = W^T[k][n] = whh[n][k], zeros beyond.
__global__ __launch_bounds__(256) void k_pack(const float* __restrict__ W, u16* __restrict__ pack)
{
  int id = blockIdx.x*256 + threadIdx.x;       // 51200 total
  if (id >= 51200) return;
  const int lane = id & 63;
  const int kt2 = (id >> 6) % 10;
  const int nt2 = id / 640;
  const int n = nt2*16 + (lane & 15);
  u16 tmp[8];
#pragma unroll
  for (int j = 0; j < 8; ++j){
    const int k = kt2*32 + (lane >> 4)*8 + j;
    tmp[j] = (n < 1200 && k < 300) ? f2us(W[(size_t)n*300 + k]) : (u16)0;
  }
  *(s16x8*)(pack + (size_t)id*8) = *(const s16x8*)tmp;
}

// ---------------- MFMA GEMM: xp chunk ----------------
__global__ __launch_bounds__(256) void k_mm_xpc(
    const u16* __restrict__ A,                 // [65536][300] bf16 (p or pc)
    const u16* __restrict__ WFb, const u16* __restrict__ WBb,  // [1200][300] bf16
    const float* __restrict__ bF1, const float* __restrict__ bF2,
    const float* __restrict__ bB1, const float* __restrict__ bB2,
    const int* __restrict__ l1, const int* __restrict__ l2,
    u16* __restrict__ xp, int c)
{
  const int dir = blockIdx.z;
  const u16* Bw = dir ? WBb : WFb;
  const float* b1 = dir ? bB1 : bF1;
  const float* b2 = dir ? bB2 : bF2;
  u16* xpd = xp + (size_t)dir*9830400;
  __shared__ u16 As[128][40];
  __shared__ u16 Bs[128][40];
  const int tid = threadIdx.x;
  const int m0 = blockIdx.y << 7;
  const int n0 = blockIdx.x << 7;
  const int srow0 = tid >> 2;                  // 0..63
  const int kcol = (tid & 3) << 3;             // 0,8,16,24
  int src[2];
#pragma unroll
  for (int p = 0; p < 2; ++p){
    const int row = srow0 + (p << 6);
    const int ml = m0 + row;
    const int r = ml >> 5, tl = ml & 31;
    const int L = (r < 128) ? l1[r] : l2[r-128];
    const int tg = (c << 5) + tl;
    const int s = dir ? ((tg < L) ? (L-1-tg) : tg) : tg;
    src[p] = r*256 + s;
  }
  const int wv = tid >> 6;
  const int wm = (wv >> 1) << 6, wn = (wv & 1) << 6;
  const int lq = (tid >> 4) & 3;
  const int lr = tid & 15;
  fx4 acc[4][4];
#pragma unroll
  for (int i = 0; i < 4; ++i)
#pragma unroll
    for (int j = 0; j < 4; ++j) acc[i][j] = (fx4){0.f,0.f,0.f,0.f};

  for (int kt = 0; kt < 10; ++kt){
    const int k = (kt << 5) + kcol;
#pragma unroll
    for (int p = 0; p < 2; ++p){
      u16 tmp[8];
      const u16* ap = A + (size_t)src[p]*300 + k;
      if (k + 8 <= 300){
        *(ushort4*)&tmp[0] = *(const ushort4*)ap;
        *(ushort4*)&tmp[4] = *(const ushort4*)(ap + 4);
      } else {
#pragma unroll
        for (int j = 0; j < 8; ++j) tmp[j] = (k + j < 300) ? ap[j] : (u16)0;
      }
      *(s16x8*)&As[srow0 + (p << 6)][kcol] = *(const s16x8*)tmp;

      const int n = n0 + srow0 + (p << 6);
      u16 tmb[8] = {0,0,0,0,0,0,0,0};
      if (n < 1200){
        const u16* bp = Bw + (size_t)n*300 + k;
        if (k + 8 <= 300){
          *(ushort4*)&tmb[0] = *(const ushort4*)bp;
          *(ushort4*)&tmb[4] = *(const ushort4*)(bp + 4);
        } else {
#pragma unroll
          for (int j = 0; j < 8; ++j) tmb[j] = (k + j < 300) ? bp[j] : (u16)0;
        }
      }
      *(s16x8*)&Bs[srow0 + (p << 6)][kcol] = *(const s16x8*)tmb;
    }
    __syncthreads();
    s16x8 af[4], bf[4];
#pragma unroll
    for (int mi = 0; mi < 4; ++mi) af[mi] = *(const s16x8*)&As[wm + mi*16 + lr][lq << 3];
#pragma unroll
    for (int ni = 0; ni < 4; ++ni) bf[ni] = *(const s16x8*)&Bs[wn + ni*16 + lr][lq << 3];
#pragma unroll
    for (int mi = 0; mi < 4; ++mi)
#pragma unroll
      for (int ni = 0; ni < 4; ++ni)
        acc[mi][ni] = __builtin_amdgcn_mfma_f32_16x16x32_bf16(af[mi], bf[ni], acc[mi][ni], 0, 0, 0);
    __syncthreads();
  }
#pragma unroll
  for (int ni = 0; ni < 4; ++ni){
    const int n = n0 + wn + ni*16 + lr;
    if (n < 1200){
      const float bias = b1[n] + b2[n];
#pragma unroll
      for (int mi = 0; mi < 4; ++mi){
        const int m = m0 + wm + mi*16 + (lq << 2);
#pragma unroll
        for (int reg = 0; reg < 4; ++reg)
          xpd[(size_t)(m + reg)*1200 + n] = f2us(acc[mi][ni][reg] + bias);
      }
    }
  }
}

// ---------------- MFMA GEMM: S = u1 @ u2^T per b ----------------
__global__ __launch_bounds__(256) void k_mm_s(const u16* __restrict__ U, float* __restrict__ S)
{
  __shared__ u16 As[128][40];
  __shared__ u16 Bs[128][40];
  const int tid = threadIdx.x;
  const int bz = blockIdx.z;
  const u16* Ap = U + (size_t)bz*153600;
  const u16* Bp = U + (size_t)(128+bz)*153600;
  float* C = S + (size_t)bz*65536;
  const int m0 = blockIdx.y << 7;
  const int n0 = blockIdx.x << 7;
  const int srow0 = tid >> 2;
  const int kcol = (tid & 3) << 3;
  const int wv = tid >> 6;
  const int wm = (wv >> 1) << 6, wn = (wv & 1) << 6;
  const int lq = (tid >> 4) & 3;
  const int lr = tid & 15;
  fx4 acc[4][4];
#pragma unroll
  for (int i = 0; i < 4; ++i)
#pragma unroll
    for (int j = 0; j < 4; ++j) acc[i][j] = (fx4){0.f,0.f,0.f,0.f};

  for (int kt = 0; kt < 19; ++kt){
    const int k = (kt << 5) + kcol;
#pragma unroll
    for (int p = 0; p < 2; ++p){
      const int row = srow0 + (p << 6);
      u16 tma[8] = {0,0,0,0,0,0,0,0};
      u16 tmb[8] = {0,0,0,0,0,0,0,0};
      if (k + 8 <= 600){
        *(s16x8*)tma = *(const s16x8*)(Ap + (size_t)(m0 + row)*600 + k);
        *(s16x8*)tmb = *(const s16x8*)(Bp + (size_t)(n0 + row)*600 + k);
      }
      *(s16x8*)&As[row][kcol] = *(const s16x8*)tma;
      *(s16x8*)&Bs[row][kcol] = *(const s16x8*)tmb;
    }
    __syncthreads();
    s16x8 af[4], bf[4];
#pragma unroll
    for (int mi = 0; mi < 4; ++mi) af[mi] = *(const s16x8*)&As[wm + mi*16 + lr][lq << 3];
#pragma unroll
    for (int ni = 0; ni < 4; ++ni) bf[ni] = *(const s16x8*)&Bs[wn + ni*16 + lr][lq << 3];
#pragma unroll
    for (int mi = 0; mi < 4; ++mi)
#pragma unroll
      for (int ni = 0; ni < 4; ++ni)
        acc[mi][ni] = __builtin_amdgcn_mfma_f32_16x16x32_bf16(af[mi], bf[ni], acc[mi][ni], 0, 0, 0);
    __syncthreads();
  }
#pragma unroll
  for (int mi = 0; mi < 4; ++mi){
    const int m = m0 + wm + mi*16 + (lq << 2);
#pragma unroll
    for (int ni = 0; ni < 4; ++ni){
      const int n = n0 + wn + ni*16 + lr;
#pragma unroll
      for (int reg = 0; reg < 4; ++reg)
        C[(size_t)(m + reg)*256 + n] = acc[mi][ni][reg];
    }
  }
}

// ---------------- MFMA GEMM: pc = relu([u,A,u-A,u*A] @ projW^T + projB) ----------------
__global__ __launch_bounds__(256) void k_mm_proj(
    const u16* __restrict__ U, const u16* __restrict__ ATT,
    const u16* __restrict__ Bw,                // projW bf16 [300][2400]
    const float* __restrict__ bias,
    u16* __restrict__ C)
{
  __shared__ u16 As[128][40];
  __shared__ u16 Bs[128][40];
  const int tid = threadIdx.x;
  const int m0 = blockIdx.y << 7;
  const int n0 = blockIdx.x << 7;
  const int srow0 = tid >> 2;
  const int kcol = (tid & 3) << 3;
  const int wv = tid >> 6;
  const int wm = (wv >> 1) << 6, wn = (wv & 1) << 6;
  const int lq = (tid >> 4) & 3;
  const int lr = tid & 15;
  fx4 acc[4][4];
#pragma unroll
  for (int i = 0; i < 4; ++i)
#pragma unroll
    for (int j = 0; j < 4; ++j) acc[i][j] = (fx4){0.f,0.f,0.f,0.f};

  for (int kt = 0; kt < 75; ++kt){
    const int k = (kt << 5) + kcol;
    const int seg = k / 600;
    const int off = k - seg*600;
#pragma unroll
    for (int p = 0; p < 2; ++p){
      const int row = srow0 + (p << 6);
      const size_t base = (size_t)(m0 + row)*600 + off;
      u16 uu8[8], aa8[8], tma[8];
      *(s16x8*)uu8 = *(const s16x8*)(U + base);
      *(s16x8*)aa8 = *(const s16x8*)(ATT + base);
      if (seg == 0){
#pragma unroll
        for (int j = 0; j < 8; ++j) tma[j] = uu8[j];
      } else if (seg == 1){
#pragma unroll
        for (int j = 0; j < 8; ++j) tma[j] = aa8[j];
      } else if (seg == 2){
#pragma unroll
        for (int j = 0; j < 8; ++j) tma[j] = f2us(us2f(uu8[j]) - us2f(aa8[j]));
      } else {
#pragma unroll
        for (int j = 0; j < 8; ++j) tma[j] = f2us(us2f(uu8[j]) * us2f(aa8[j]));
      }
      *(s16x8*)&As[row][kcol] = *(const s16x8*)tma;

      const int n = n0 + row;
      u16 tmb[8] = {0,0,0,0,0,0,0,0};
      if (n < 300)
        *(s16x8*)tmb = *(const s16x8*)(Bw + (size_t)n*2400 + k);
      *(s16x8*)&Bs[row][kcol] = *(const s16x8*)tmb;
    }
    __syncthreads();
    s16x8 af[4], bf[4];
#pragma unroll
    for (int mi = 0; mi < 4; ++mi) af[mi] = *(const s16x8*)&As[wm + mi*16 + lr][lq << 3];
#pragma unroll
    for (int ni = 0; ni < 4; ++ni) bf[ni] = *(const s16x8*)&Bs[wn + ni*16 + lr][lq << 3];
#pragma unroll
    for (int mi = 0; mi < 4; ++mi)
#pragma unroll
      for (int ni = 0; ni < 4; ++ni)
        acc[mi][ni] = __builtin_amdgcn_mfma_f32_16x16x32_bf16(af[mi], bf[ni], acc[mi][ni], 0, 0, 0);
    __syncthreads();
  }
#pragma unroll
  for (int ni = 0; ni < 4; ++ni){
    const int n = n0 + wn + ni*16 + lr;
    if (n < 300){
      const float bs = bias[n];
#pragma unroll
      for (int mi = 0; mi < 4; ++mi){
        const int m = m0 + wm + mi*16 + (lq << 2);
#pragma unroll
        for (int reg = 0; reg < 4; ++reg)
          C[(size_t)(m + reg)*300 + n] = f2us(fmaxf(acc[mi][ni][reg] + bs, 0.0f));
      }
    }
  }
}

// ---------------- MFMA streaming scan (even/odd weight dbuf): 32 WGs x 512 thr ----------------
__global__ __launch_bounds__(512, 1) void k_scan_mf(
    const u16* __restrict__ xp,                // [2][8192][1200] bf16 (chunk-gathered)
    const u16* __restrict__ packF, const u16* __restrict__ packB, // [80][10][64][8]
    const int* __restrict__ l1, const int* __restrict__ l2,
    u16* __restrict__ uo,                      // [65536][600] bf16
    u16* __restrict__ hG, float* __restrict__ cG,  // [2][256][328] bf16 ; [2][256][304] f32
    int c)
{
  __shared__ u16 h_s[16][328];
  __shared__ float c_s[16][304];
  __shared__ float gs[16][1200];
  __shared__ u16 xstage[16][1200];
  __shared__ int L_s[16];
  const int bid = blockIdx.x;
  const int dir = bid & 1, sg = bid >> 1;
  const int r0 = sg << 4;
  const u16* pack = dir ? packB : packF;
  const u16* xpd = xp + (size_t)dir*9830400;
  const int tid = threadIdx.x;
  if (tid < 16) L_s[tid] = (r0 + tid < 128) ? l1[r0 + tid] : l2[r0 + tid - 128];
  for (int i = tid; i < 16*328; i += 512){
    const int q = i / 328, d = i - q*328;
    h_s[q][d] = (c > 0) ? hG[(size_t)(dir*256 + r0 + q)*328 + d] : (u16)0;
  }
  for (int i = tid; i < 16*300; i += 512){
    const int q = i / 300, d = i - q*300;
    c_s[q][d] = (c > 0) ? cG[(size_t)(dir*256 + r0 + q)*304 + d] : 0.0f;
  }
  __syncthreads();
  int Lmax = 0;
#pragma unroll
  for (int q = 0; q < 16; ++q) Lmax = max(Lmax, L_s[q]);
  const int t0 = c << 5;
  int nts = Lmax - t0; if (nts > 32) nts = 32;
  if (nts <= 0) return;                         // nothing to do; state in hG/cG still valid

  const int w = tid >> 6, lane = tid & 63;
  const int lq = lane >> 4, lr = lane & 15;
  const int tile0 = w * 10;
  const u16* pw = pack + (size_t)tile0*5120 + (size_t)lane*8;

  // xp staging map: i = tid + 512*j < 2400 ; q = i/150 ; col8 = (i%150)*8
  int xq[5], xc[5]; bool xv[5];
#pragma unroll
  for (int j = 0; j < 5; ++j){
    const int i = tid + (j << 9);
    xv[j] = (i < 2400);
    const int q = i / 150;
    xq[j] = q < 16 ? q : 15;
    xc[j] = (i - (q < 16 ? q : 15)*150) * 8;
  }

  // prologue: stage xp for step 0
  {
#pragma unroll
    for (int j = 0; j < 5; ++j){
      if (xv[j]){
        s16x8 v = *(const s16x8*)(xpd + (size_t)((r0 + xq[j])*32 + 0)*1200 + xc[j]);
        *(s16x8*)&xstage[xq[j]][xc[j]] = v;
      }
    }
  }
  __syncthreads();

  for (int tl = 0; tl < nts; ++tl){
    const int t = t0 + tl;
    const bool pf = (tl + 1 < nts);
    // prefetch next step's xp into regs (latency hidden under MFMA phase)
    s16x8 xr0, xr1, xr2, xr3, xr4;
    if (pf){
      if (xv[0]) xr0 = *(const s16x8*)(xpd + (size_t)((r0 + xq[0])*32 + tl + 1)*1200 + xc[0]);
      if (xv[1]) xr1 = *(const s16x8*)(xpd + (size_t)((r0 + xq[1])*32 + tl + 1)*1200 + xc[1]);
      if (xv[2]) xr2 = *(const s16x8*)(xpd + (size_t)((r0 + xq[2])*32 + tl + 1)*1200 + xc[2]);
      if (xv[3]) xr3 = *(const s16x8*)(xpd + (size_t)((r0 + xq[3])*32 + tl + 1)*1200 + xc[3]);
      if (xv[4]) xr4 = *(const s16x8*)(xpd + (size_t)((r0 + xq[4])*32 + tl + 1)*1200 + xc[4]);
    }
    // even/odd double-buffered weight pipeline; all indices static
    fx4 acc[10];
#pragma unroll
    for (int nt = 0; nt < 10; ++nt) acc[nt] = (fx4){0.f,0.f,0.f,0.f};
    s16x8 wbA[10], wbB[10];
#pragma unroll
    for (int nt = 0; nt < 10; ++nt) wbA[nt] = *(const s16x8*)(pw + (size_t)(nt*10 + 0)*512);
#pragma unroll
    for (int ktp = 0; ktp < 5; ++ktp){
      const int ktE = 2*ktp, ktO = 2*ktp + 1;
      // load odd column while even column computes
#pragma unroll
      for (int nt = 0; nt < 10; ++nt) wbB[nt] = *(const s16x8*)(pw + (size_t)(nt*10 + ktO)*512);
      {
        const s16x8 a = *(const s16x8*)&h_s[lr][ktE*32 + (lq << 3)];
#pragma unroll
        for (int nt = 0; nt < 10; ++nt)
          acc[nt] = __builtin_amdgcn_mfma_f32_16x16x32_bf16(a, wbA[nt], acc[nt], 0, 0, 0);
      }
      if (ktp < 4){
#pragma unroll
        for (int nt = 0; nt < 10; ++nt) wbA[nt] = *(const s16x8*)(pw + (size_t)(nt*10 + ktE + 2)*512);
      }
      {
        const s16x8 a = *(const s16x8*)&h_s[lr][ktO*32 + (lq << 3)];
#pragma unroll
        for (int nt = 0; nt < 10; ++nt)
          acc[nt] = __builtin_amdgcn_mfma_f32_16x16x32_bf16(a, wbB[nt], acc[nt], 0, 0, 0);
      }
    }
    // acc -> gs
#pragma unroll
    for (int nt = 0; nt < 10; ++nt){
      const int n = (tile0 + nt)*16 + lr;
      if (n < 1200){
#pragma unroll
        for (int reg = 0; reg < 4; ++reg)
          gs[(lq << 2) + reg][n] = acc[nt][reg];
      }
    }
    __syncthreads();
    // nonlinearity + state update + output (gate = gs + xstage)
#pragma unroll
    for (int j = 0; j < 10; ++j){
      const int u0 = tid + (j << 9);
      if (u0 < 4800){
        const int q = u0 / 300, d = u0 - q*300;
        const int L = L_s[q];
        if (t < L){
          const float gi = gs[q][d]       + us2f(xstage[q][d]);
          const float gf = gs[q][300 + d] + us2f(xstage[q][300 + d]);
          const float gg = gs[q][600 + d] + us2f(xstage[q][600 + d]);
          const float go = gs[q][900 + d] + us2f(xstage[q][900 + d]);
          const float cn = sigmf(gf)*c_s[q][d] + sigmf(gi)*tanhfast(gg);
          const float hn = sigmf(go)*tanhfast(cn);
          c_s[q][d] = cn;
          const u16 hb = f2us(hn);
          h_s[q][d] = hb;
          const int wpos = dir ? (L-1-t) : t;
          uo[(size_t)((r0 + q)*256 + wpos)*600 + dir*300 + d] = hb;
        }
      }
    }
    __syncthreads();
    // write prefetched xp regs into xstage for step tl+1
    if (pf){
      if (xv[0]) *(s16x8*)&xstage[xq[0]][xc[0]] = xr0;
      if (xv[1]) *(s16x8*)&xstage[xq[1]][xc[1]] = xr1;
      if (xv[2]) *(s16x8*)&xstage[xq[2]][xc[2]] = xr2;
      if (xv[3]) *(s16x8*)&xstage[xq[3]][xc[3]] = xr3;
      if (xv[4]) *(s16x8*)&xstage[xq[4]][xc[4]] = xr4;
    }
  }
  // persist state
  for (int i = tid; i < 16*328; i += 512){
    const int q = i / 328, d = i - q*328;
    hG[(size_t)(dir*256 + r0 + q)*328 + d] = h_s[q][d];
  }
  for (int i = tid; i < 16*300; i += 512){
    const int q = i / 300, d = i - q*300;
    cG[(size_t)(dir*256 + r0 + q)*304 + d] = c_s[q][d];
  }
}

// ---------------- softmax stats ----------------
__global__ __launch_bounds__(256) void k_row_stats(const float* __restrict__ S, const int* __restrict__ l2,
                                                   float* __restrict__ rmax, float* __restrict__ rinv)
{
  const int wid = threadIdx.x >> 6, lane = threadIdx.x & 63;
  const int row = blockIdx.x*4 + wid;
  const int b = row >> 8;
  const int L2b = l2[b];
  float4 v = *(const float4*)(S + (size_t)row*256 + lane*4);
  const int j = lane*4;
  float m = -INFINITY;
  if (j   < L2b) m = fmaxf(m, v.x);
  if (j+1 < L2b) m = fmaxf(m, v.y);
  if (j+2 < L2b) m = fmaxf(m, v.z);
  if (j+3 < L2b) m = fmaxf(m, v.w);
  for (int off = 32; off; off >>= 1) m = fmaxf(m, __shfl_xor(m, off));
  float s = 0.f;
  if (j   < L2b) s += __expf(v.x - m);
  if (j+1 < L2b) s += __expf(v.y - m);
  if (j+2 < L2b) s += __expf(v.z - m);
  if (j+3 < L2b) s += __expf(v.w - m);
  for (int off = 32; off; off >>= 1) s += __shfl_xor(s, off);
  if (lane == 0){ rmax[row] = m; rinv[row] = 1.0f/s; }
}

__global__ __launch_bounds__(256) void k_col_stats(const float* __restrict__ S, const int* __restrict__ l1,
                                                   float* __restrict__ cmax, float* __restrict__ cinv)
{
  const int b = blockIdx.x;
  const int j = threadIdx.x;
  const int L1b = l1[b];
  const float* Sb = S + (size_t)b*65536;
  float m = -INFINITY;
  for (int i = 0; i < L1b; ++i) m = fmaxf(m, Sb[(size_t)i*256 + j]);
  float s = 0.f;
  for (int i = 0; i < L1b; ++i) s += __expf(Sb[(size_t)i*256 + j] - m);
  cmax[b*256 + j] = m;
  cinv[b*256 + j] = 1.0f/s;
}

// ---------------- A1 = softmax_rows(S) @ u2 -> att bf16 ----------------
__global__ __launch_bounds__(256) void k_av_row(
    const float* __restrict__ S, const u16* __restrict__ U,
    const int* __restrict__ l1, const int* __restrict__ l2,
    const float* __restrict__ rmax, const float* __restrict__ rinv,
    u16* __restrict__ ATT)
{
  __shared__ float Ps[32][68];
  __shared__ float Us[32][68];
  const int tid = threadIdx.x;
  const int b = blockIdx.z;
  const int i0 = blockIdx.y << 6;
  const int d0 = blockIdx.x << 6;
  const int L1b = l1[b], L2b = l2[b];
  const float* Sb = S + (size_t)b*65536;
  const u16* u2 = U + (size_t)(128+b)*153600;
  const int tx = tid & 15, ty = tid >> 4;
  float acc[4][4];
#pragma unroll
  for (int i = 0; i < 4; ++i)
#pragma unroll
    for (int j = 0; j < 4; ++j) acc[i][j] = 0.0f;

  for (int kt = 0; kt < 8; ++kt){
    const int j0 = kt << 5;
#pragma unroll
    for (int q = 0; q < 2; ++q){
      const int f4 = tid + (q << 8);
      {
        const int row = f4 >> 3;
        const int c4 = (f4 & 7) << 2;
        const int i = i0 + row;
        float4 s4 = *(const float4*)(Sb + (size_t)i*256 + j0 + c4);
        const float rm = rmax[(b<<8) + i];
        const float ri = rinv[(b<<8) + i];
        const int jb = j0 + c4;
        Ps[c4  ][row] = (jb   < L2b) ? __expf(s4.x - rm)*ri : 0.0f;
        Ps[c4+1][row] = (jb+1 < L2b) ? __expf(s4.y - rm)*ri : 0.0f;
        Ps[c4+2][row] = (jb+2 < L2b) ? __expf(s4.z - rm)*ri : 0.0f;
        Ps[c4+3][row] = (jb+3 < L2b) ? __expf(s4.w - rm)*ri : 0.0f;
      }
      {
        const int row = f4 >> 4;
        const int c4 = (f4 & 15) << 2;
        const int d = d0 + c4;
        float4 v = make_float4(0.f,0.f,0.f,0.f);
        if (j0 + row < L2b){
          const u16* up = u2 + (size_t)(j0+row)*600 + d;
          if (d + 3 < 600){
            ushort4 t4 = *(const ushort4*)up;
            v.x=us2f(t4.x); v.y=us2f(t4.y); v.z=us2f(t4.z); v.w=us2f(t4.w);
          } else {
            if (d   < 600) v.x = us2f(up[0]);
            if (d+1 < 600) v.y = us2f(up[1]);
            if (d+2 < 600) v.z = us2f(up[2]);
          }
        }
        *(float4*)&Us[row][c4] = v;
      }
    }
    __syncthreads();
#pragma unroll
    for (int kk = 0; kk < 32; ++kk){
      float4 a = *(const float4*)&Ps[kk][ty<<2];
      float4 bb = *(const float4*)&Us[kk][tx<<2];
      float av[4] = {a.x,a.y,a.z,a.w};
      float bv[4] = {bb.x,bb.y,bb.z,bb.w};
#pragma unroll
      for (int ii = 0; ii < 4; ++ii)
#pragma unroll
        for (int jj = 0; jj < 4; ++jj)
          acc[ii][jj] = fmaf(av[ii], bv[jj], acc[ii][jj]);
    }
    __syncthreads();
  }
#pragma unroll
  for (int ii = 0; ii < 4; ++ii){
    const int i = i0 + (ty<<2) + ii;
#pragma unroll
    for (int jj = 0; jj < 4; ++jj){
      const int d = d0 + (tx<<2) + jj;
      if (d < 600)
        ATT[(size_t)b*153600 + (size_t)i*600 + d] = f2us((i < L1b) ? acc[ii][jj] : 0.0f);
    }
  }
}

// ---------------- A2 = softmax_cols(S)^T @ u1 -> att bf16 ----------------
__global__ __launch_bounds__(256) void k_av_col(
    const float* __restrict__ S, const u16* __restrict__ U,
    const int* __restrict__ l1, const int* __restrict__ l2,
    const float* __restrict__ cmax, const float* __restrict__ cinv,
    u16* __restrict__ ATT)
{
  __shared__ float Ps[32][68];
  __shared__ float Us[32][68];
  const int tid = threadIdx.x;
  const int b = blockIdx.z;
  const int j0v = blockIdx.y << 6;
  const int d0 = blockIdx.x << 6;
  const int L1b = l1[b], L2b = l2[b];
  const float* Sb = S + (size_t)b*65536;
  const u16* u1 = U + (size_t)b*153600;
  const int tx = tid & 15, ty = tid >> 4;
  float acc[4][4];
#pragma unroll
  for (int i = 0; i < 4; ++i)
#pragma unroll
    for (int j = 0; j < 4; ++j) acc[i][j] = 0.0f;

  for (int kt = 0; kt < 8; ++kt){
    const int i0k = kt << 5;
#pragma unroll
    for (int q = 0; q < 2; ++q){
      const int f4 = tid + (q << 8);
      const int row = f4 >> 4;
      const int c4 = (f4 & 15) << 2;
      {
        const int i = i0k + row;
        const int j = j0v + c4;
        float4 s4 = *(const float4*)(Sb + (size_t)i*256 + j);
        const bool iok = i < L1b;
        Ps[row][c4  ] = iok ? __expf(s4.x - cmax[(b<<8)+j  ])*cinv[(b<<8)+j  ] : 0.0f;
        Ps[row][c4+1] = iok ? __expf(s4.y - cmax[(b<<8)+j+1])*cinv[(b<<8)+j+1] : 0.0f;
        Ps[row][c4+2] = iok ? __expf(s4.z - cmax[(b<<8)+j+2])*cinv[(b<<8)+j+2] : 0.0f;
        Ps[row][c4+3] = iok ? __expf(s4.w - cmax[(b<<8)+j+3])*cinv[(b<<8)+j+3] : 0.0f;
      }
      {
        const int d = d0 + c4;
        float4 v = make_float4(0.f,0.f,0.f,0.f);
        if (i0k + row < L1b){
          const u16* up = u1 + (size_t)(i0k+row)*600 + d;
          if (d + 3 < 600){
            ushort4 t4 = *(const ushort4*)up;
            v.x=us2f(t4.x); v.y=us2f(t4.y); v.z=us2f(t4.z); v.w=us2f(t4.w);
          } else {
            if (d   < 600) v.x = us2f(up[0]);
            if (d+1 < 600) v.y = us2f(up[1]);
            if (d+2 < 600) v.z = us2f(up[2]);
          }
        }
        *(float4*)&Us[row][c4] = v;
      }
    }
    __syncthreads();
#pragma unroll
    for (int kk = 0; kk < 32; ++kk){
      float4 a = *(const float4*)&Ps[kk][ty<<2];
      float4 bb = *(const float4*)&Us[kk][tx<<2];
      float av[4] = {a.x,a.y,a.z,a.w};
      float bv[4] = {bb.x,bb.y,bb.z,bb.w};
#pragma unroll
      for (int ii = 0; ii < 4; ++ii)
#pragma unroll
        for (int jj = 0; jj < 4; ++jj)
          acc[ii][jj] = fmaf(av[ii], bv[jj], acc[ii][jj]);
    }
    __syncthreads();
  }
#pragma unroll
  for (int ii = 0; ii < 4; ++ii){
    const int j = j0v + (ty<<2) + ii;
#pragma unroll
    for (int jj = 0; jj < 4; ++jj){
      const int d = d0 + (tx<<2) + jj;
      if (d < 600)
        ATT[(size_t)(128+b)*153600 + (size_t)j*600 + d] = f2us((j < L2b) ? acc[ii][jj] : 0.0f);
    }
  }
}

// ---------------- masked max over time + feature build ----------------
__global__ __launch_bounds__(256) void k_maxfeat(const u16* __restrict__ y,
                                                 const int* __restrict__ l1, const int* __restrict__ l2,
                                                 float* __restrict__ feat)
{
  const int b = blockIdx.x;
  const int La = l1[b], Lb = l2[b];
  for (int c = threadIdx.x; c < 600; c += 256){
    float m1 = -INFINITY, m2 = -INFINITY;
    const u16* y1 = y + (size_t)b*153600 + c;
    for (int t = 0; t < La; ++t) m1 = fmaxf(m1, us2f(y1[(size_t)t*600]));
    const u16* y2 = y + (size_t)(128+b)*153600 + c;
    for (int t = 0; t < Lb; ++t) m2 = fmaxf(m2, us2f(y2[(size_t)t*600]));
    feat[(size_t)b*2400 + c]        = m1;
    feat[(size_t)b*2400 + 600 + c]  = m2;
    feat[(size_t)b*2400 + 1200 + c] = fabsf(m1 - m2);
    feat[(size_t)b*2400 + 1800 + c] = m1*m2;
  }
}

// ---------------- per-row MLP ----------------
__global__ __launch_bounds__(256) void k_rowgemm(const float* __restrict__ feat, const float* __restrict__ W,
                                                 const float* __restrict__ bias, float* __restrict__ out)
{
  const int b = blockIdx.x;
  __shared__ float ff[2400];
  for (int i = threadIdx.x; i < 2400; i += 256) ff[i] = feat[(size_t)b*2400 + i];
  __syncthreads();
  for (int n = threadIdx.x; n < 300; n += 256){
    const float* w = W + (size_t)n*2400;
    float acc = bias[n];
    for (int k = 0; k < 2400; k += 4){
      float4 wv = *(const float4*)(w + k);
      acc += ff[k]*wv.x + ff[k+1]*wv.y + ff[k+2]*wv.z + ff[k+3]*wv.w;
    }
    out[(size_t)b*300 + n] = fmaxf(acc, 0.0f);
  }
}

// ---------------- final ----------------
__global__ __launch_bounds__(192) void k_final(const float* __restrict__ h, const float* __restrict__ smW,
                                               const float* __restrict__ smB, float* __restrict__ out)
{
  const int b = blockIdx.x;
  const int n = threadIdx.x >> 6, lane = threadIdx.x & 63;
  float acc = 0.f;
  for (int k = lane; k < 300; k += 64) acc += h[(size_t)b*300 + k]*smW[(size_t)n*300 + k];
  for (int off = 32; off; off >>= 1) acc += __shfl_xor(acc, off);
  if (lane == 0) out[b*3 + n] = acc + smB[n];
}

extern "C" void kernel_launch(void* const* d_in, const int* in_sizes, int n_in,
                              void* d_out, int out_size, void* d_ws, size_t ws_size,
                              hipStream_t stream)
{
  (void)in_sizes; (void)n_in; (void)out_size;
  static const size_t OFF_P  = 0;             // p bf16 [65536][300]
  static const size_t OFF_B  = 39321600;      // xp1 / Smat / pc
  static const size_t OFF_U  = 78643200;      // uu/y bf16 [65536][600]
  static const size_t OFF_D  = 157286400;     // att / xp2
  static const size_t OFF_WT = 235929600;     // wih bf16 x4 (720000B each)
  static const size_t OFF_PJ = 238809600;     // projW bf16 (1440000B)
  static const size_t OFF_PK = 240249600;     // W_pack x4 (819200B each)
  static const size_t OFF_ST = 243526400;     // stats 4x32768 f32
  static const size_t OFF_FE = 244050688;     // feat
  static const size_t OFF_HM = 245279488;     // hml
  static const size_t OFF_HC = 245433088;     // hG bf16 (335872) + cG f32 (622592)
  static const size_t WS_NEEDED = 246391552;
  if (ws_size < WS_NEEDED) return;

  const int* s1 = (const int*)d_in[0];
  const int* l1 = (const int*)d_in[1];
  const int* s2 = (const int*)d_in[2];
  const int* l2 = (const int*)d_in[3];
  const float* emb    = (const float*)d_in[4];
  const float* w1f_ih = (const float*)d_in[5];
  const float* w1f_hh = (const float*)d_in[6];
  const float* b1f_ih = (const float*)d_in[7];
  const float* b1f_hh = (const float*)d_in[8];
  const float* w1b_ih = (const float*)d_in[9];
  const float* w1b_hh = (const float*)d_in[10];
  const float* b1b_ih = (const float*)d_in[11];
  const float* b1b_hh = (const float*)d_in[12];
  const float* w2f_ih = (const float*)d_in[13];
  const float* w2f_hh = (const float*)d_in[14];
  const float* b2f_ih = (const float*)d_in[15];
  const float* b2f_hh = (const float*)d_in[16];
  const float* w2b_ih = (const float*)d_in[17];
  const float* w2b_hh = (const float*)d_in[18];
  const float* b2b_ih = (const float*)d_in[19];
  const float* b2b_hh = (const float*)d_in[20];
  const float* projW  = (const float*)d_in[21];
  const float* projB  = (const float*)d_in[22];
  const float* mlpW   = (const float*)d_in[23];
  const float* mlpB   = (const float*)d_in[24];
  const float* smW    = (const float*)d_in[25];
  const float* smB    = (const float*)d_in[26];

  char* ws = (char*)d_ws;
  u16*   p    = (u16*)(ws + OFF_P);
  u16*   xp1  = (u16*)(ws + OFF_B);
  float* Smat = (float*)(ws + OFF_B);
  u16*   pc   = (u16*)(ws + OFF_B);
  u16*   uu   = (u16*)(ws + OFF_U);
  u16*   att  = (u16*)(ws + OFF_D);
  u16*   xp2  = (u16*)(ws + OFF_D);
  u16*   wih  = (u16*)(ws + OFF_WT);
  u16*   pjw  = (u16*)(ws + OFF_PJ);
  u16*   pk   = (u16*)(ws + OFF_PK);
  float* st   = (float*)(ws + OFF_ST);
  float* feat = (float*)(ws + OFF_FE);
  float* hml  = (float*)(ws + OFF_HM);
  u16*   hG   = (u16*)(ws + OFF_HC);
  float* cG   = (float*)(ws + OFF_HC + 335872);

  k_embed<<<19200, 256, 0, stream>>>(s1, s2, emb, p);
  k_cvt<<<1407, 256, 0, stream>>>(w1f_ih, wih,           360000);
  k_cvt<<<1407, 256, 0, stream>>>(w1b_ih, wih + 360000,  360000);
  k_cvt<<<1407, 256, 0, stream>>>(w2f_ih, wih + 720000,  360000);
  k_cvt<<<1407, 256, 0, stream>>>(w2b_ih, wih + 1080000, 360000);
  k_cvt<<<2813, 256, 0, stream>>>(projW,  pjw,           720000);
  k_pack<<<200, 256, 0, stream>>>(w1f_hh, pk);
  k_pack<<<200, 256, 0, stream>>>(w1b_hh, pk + 409600);
  k_pack<<<200, 256, 0, stream>>>(w2f_hh, pk + 819200);
  k_pack<<<200, 256, 0, stream>>>(w2b_hh, pk + 1228800);

  const dim3 gxp(10, 64, 2);
  for (int c = 0; c < 8; ++c){
    k_mm_xpc<<<gxp, 256, 0, stream>>>(p, wih, wih + 360000, b1f_ih, b1f_hh, b1b_ih, b1b_hh,
                                      l1, l2, xp1, c);
    k_scan_mf<<<32, 512, 0, stream>>>(xp1, pk, pk + 409600, l1, l2, uu, hG, cG, c);
  }

  k_mm_s<<<dim3(2,2,128), 256, 0, stream>>>(uu, Smat);
  k_row_stats<<<8192, 256, 0, stream>>>(Smat, l2, st, st + 32768);
  k_col_stats<<<128, 256, 0, stream>>>(Smat, l1, st + 65536, st + 98304);
  k_av_row<<<dim3(10,4,128), 256, 0, stream>>>(Smat, uu, l1, l2, st, st + 32768, att);
  k_av_col<<<dim3(10,4,128), 256, 0, stream>>>(Smat, uu, l1, l2, st + 65536, st + 98304, att);

  k_mm_proj<<<dim3(3,512,1), 256, 0, stream>>>(uu, att, pjw, projB, pc);

  for (int c = 0; c < 8; ++c){
    k_mm_xpc<<<gxp, 256, 0, stream>>>(pc, wih + 720000, wih + 1080000, b2f_ih, b2f_hh, b2b_ih, b2b_hh,
                                      l1, l2, xp2, c);
    k_scan_mf<<<32, 512, 0, stream>>>(xp2, pk + 819200, pk + 1228800, l1, l2, uu, hG, cG, c);
  }

  k_maxfeat<<<128, 256, 0, stream>>>(uu, l1, l2, feat);
  k_rowgemm<<<128, 256, 0, stream>>>(feat, mlpW, mlpB, hml);
  k_final<<<128, 192, 0, stream>>>(hml, smW, smB, (float*)d_out);
}

// Round 7
// 8934.509 us; speedup vs baseline: 4.9219x; 1.5491x over previous
//
#include <hip/hip_runtime.h>
#include <hip/hip_bf16.h>

// B=128, T=256, V=50000, D=300, H=300. 256 sample-rows (0..127 = s1, 128..255 = s2).
// MFMA bf16 pipeline; time-chunked (TC=32) xp + streaming-weight MFMA scan using a
// VGPR-free global_load_lds weight ring with counted vmcnt (in-order retirement).

typedef unsigned short u16;
typedef float fx4 __attribute__((ext_vector_type(4)));
typedef short s16x8 __attribute__((ext_vector_type(8)));

__device__ __forceinline__ float us2f(u16 u){
  unsigned int x = ((unsigned int)u) << 16;
  float f; __builtin_memcpy(&f, &x, 4); return f;
}
__device__ __forceinline__ u16 f2us(float f){
  unsigned int x; __builtin_memcpy(&x, &f, 4);
  unsigned int r = x + 0x7fffu + ((x >> 16) & 1u);
  return (u16)(r >> 16);
}
__device__ __forceinline__ float sigmf(float x){ return 1.0f/(1.0f + __expf(-x)); }
__device__ __forceinline__ float tanhfast(float x){ return 1.0f - 2.0f/(__expf(2.0f*x) + 1.0f); }

// ---------------- embedding gather -> p bf16 [65536][300] ----------------
__global__ __launch_bounds__(256) void k_embed(const int* __restrict__ s1, const int* __restrict__ s2,
                                               const float* __restrict__ emb, u16* __restrict__ p)
{
  int id = blockIdx.x*256 + threadIdx.x;
  if (id >= 65536*75) return;
  int row = id / 75;
  int c4 = (id - row*75) * 4;
  int tok = (row < 32768) ? s1[row] : s2[row - 32768];
  float4 v = *(const float4*)(emb + (size_t)tok*300 + c4);
  ushort4 o; o.x=f2us(v.x); o.y=f2us(v.y); o.z=f2us(v.z); o.w=f2us(v.w);
  *(ushort4*)(p + (size_t)row*300 + c4) = o;
}

// ---------------- f32 -> bf16 convert ----------------
__global__ __launch_bounds__(256) void k_cvt(const float* __restrict__ in, u16* __restrict__ out, int n)
{
  int id = blockIdx.x*256 + threadIdx.x;
  if (id < n) out[id] = f2us(in[id]);
}

// ---------------- pack Whh [1200][300] f32 into MFMA B-fragment stream ----------------
// pack[ntile(80)][ktile(10)][lane(64)][8] : value = W^T[k][n] = whh[n][k], zeros beyond.
__global__ __launch_bounds__(256) void k_pack(const float* __restrict__ W, u16* __restrict__ pack)
{
  int id = blockIdx.x*256 + threadIdx.x;       // 51200 total
  if (id >= 51200) return;
  const int lane = id & 63;
  const int kt2 = (id >> 6) % 10;
  const int nt2 = id / 640;
  const int n = nt2*16 + (lane & 15);
  u16 tmp[8];
#pragma unroll
  for (int j = 0; j < 8; ++j){
    const int k = kt2*32 + (lane >> 4)*8 + j;
    tmp[j] = (n < 1200 && k < 300) ? f2us(W[(size_t)n*300 + k]) : (u16)0;
  }
  *(s16x8*)(pack + (size_t)id*8) = *(const s16x8*)tmp;
}

// ---------------- MFMA GEMM: xp chunk ----------------
__global__ __launch_bounds__(256) void k_mm_xpc(
    const u16* __restrict__ A,                 // [65536][300] bf16 (p or pc)
    const u16* __restrict__ WFb, const u16* __restrict__ WBb,  // [1200][300] bf16
    const float* __restrict__ bF1, const float* __restrict__ bF2,
    const float* __restrict__ bB1, const float* __restrict__ bB2,
    const int* __restrict__ l1, const int* __restrict__ l2,
    u16* __restrict__ xp, int c)
{
  const int dir = blockIdx.z;
  const u16* Bw = dir ? WBb : WFb;
  const float* b1 = dir ? bB1 : bF1;
  const float* b2 = dir ? bB2 : bF2;
  u16* xpd = xp + (size_t)dir*9830400;
  __shared__ u16 As[128][40];
  __shared__ u16 Bs[128][40];
  const int tid = threadIdx.x;
  const int m0 = blockIdx.y << 7;
  const int n0 = blockIdx.x << 7;
  const int srow0 = tid >> 2;                  // 0..63
  const int kcol = (tid & 3) << 3;             // 0,8,16,24
  int src[2];
#pragma unroll
  for (int p = 0; p < 2; ++p){
    const int row = srow0 + (p << 6);
    const int ml = m0 + row;
    const int r = ml >> 5, tl = ml & 31;
    const int L = (r < 128) ? l1[r] : l2[r-128];
    const int tg = (c << 5) + tl;
    const int s = dir ? ((tg < L) ? (L-1-tg) : tg) : tg;
    src[p] = r*256 + s;
  }
  const int wv = tid >> 6;
  const int wm = (wv >> 1) << 6, wn = (wv & 1) << 6;
  const int lq = (tid >> 4) & 3;
  const int lr = tid & 15;
  fx4 acc[4][4];
#pragma unroll
  for (int i = 0; i < 4; ++i)
#pragma unroll
    for (int j = 0; j < 4; ++j) acc[i][j] = (fx4){0.f,0.f,0.f,0.f};

  for (int kt = 0; kt < 10; ++kt){
    const int k = (kt << 5) + kcol;
#pragma unroll
    for (int p = 0; p < 2; ++p){
      u16 tmp[8];
      const u16* ap = A + (size_t)src[p]*300 + k;
      if (k + 8 <= 300){
        *(ushort4*)&tmp[0] = *(const ushort4*)ap;
        *(ushort4*)&tmp[4] = *(const ushort4*)(ap + 4);
      } else {
#pragma unroll
        for (int j = 0; j < 8; ++j) tmp[j] = (k + j < 300) ? ap[j] : (u16)0;
      }
      *(s16x8*)&As[srow0 + (p << 6)][kcol] = *(const s16x8*)tmp;

      const int n = n0 + srow0 + (p << 6);
      u16 tmb[8] = {0,0,0,0,0,0,0,0};
      if (n < 1200){
        const u16* bp = Bw + (size_t)n*300 + k;
        if (k + 8 <= 300){
          *(ushort4*)&tmb[0] = *(const ushort4*)bp;
          *(ushort4*)&tmb[4] = *(const ushort4*)(bp + 4);
        } else {
#pragma unroll
          for (int j = 0; j < 8; ++j) tmb[j] = (k + j < 300) ? bp[j] : (u16)0;
        }
      }
      *(s16x8*)&Bs[srow0 + (p << 6)][kcol] = *(const s16x8*)tmb;
    }
    __syncthreads();
    s16x8 af[4], bf[4];
#pragma unroll
    for (int mi = 0; mi < 4; ++mi) af[mi] = *(const s16x8*)&As[wm + mi*16 + lr][lq << 3];
#pragma unroll
    for (int ni = 0; ni < 4; ++ni) bf[ni] = *(const s16x8*)&Bs[wn + ni*16 + lr][lq << 3];
#pragma unroll
    for (int mi = 0; mi < 4; ++mi)
#pragma unroll
      for (int ni = 0; ni < 4; ++ni)
        acc[mi][ni] = __builtin_amdgcn_mfma_f32_16x16x32_bf16(af[mi], bf[ni], acc[mi][ni], 0, 0, 0);
    __syncthreads();
  }
#pragma unroll
  for (int ni = 0; ni < 4; ++ni){
    const int n = n0 + wn + ni*16 + lr;
    if (n < 1200){
      const float bias = b1[n] + b2[n];
#pragma unroll
      for (int mi = 0; mi < 4; ++mi){
        const int m = m0 + wm + mi*16 + (lq << 2);
#pragma unroll
        for (int reg = 0; reg < 4; ++reg)
          xpd[(size_t)(m + reg)*1200 + n] = f2us(acc[mi][ni][reg] + bias);
      }
    }
  }
}

// ---------------- MFMA GEMM: S = u1 @ u2^T per b ----------------
__global__ __launch_bounds__(256) void k_mm_s(const u16* __restrict__ U, float* __restrict__ S)
{
  __shared__ u16 As[128][40];
  __shared__ u16 Bs[128][40];
  const int tid = threadIdx.x;
  const int bz = blockIdx.z;
  const u16* Ap = U + (size_t)bz*153600;
  const u16* Bp = U + (size_t)(128+bz)*153600;
  float* C = S + (size_t)bz*65536;
  const int m0 = blockIdx.y << 7;
  const int n0 = blockIdx.x << 7;
  const int srow0 = tid >> 2;
  const int kcol = (tid & 3) << 3;
  const int wv = tid >> 6;
  const int wm = (wv >> 1) << 6, wn = (wv & 1) << 6;
  const int lq = (tid >> 4) & 3;
  const int lr = tid & 15;
  fx4 acc[4][4];
#pragma unroll
  for (int i = 0; i < 4; ++i)
#pragma unroll
    for (int j = 0; j < 4; ++j) acc[i][j] = (fx4){0.f,0.f,0.f,0.f};

  for (int kt = 0; kt < 19; ++kt){
    const int k = (kt << 5) + kcol;
#pragma unroll
    for (int p = 0; p < 2; ++p){
      const int row = srow0 + (p << 6);
      u16 tma[8] = {0,0,0,0,0,0,0,0};
      u16 tmb[8] = {0,0,0,0,0,0,0,0};
      if (k + 8 <= 600){
        *(s16x8*)tma = *(const s16x8*)(Ap + (size_t)(m0 + row)*600 + k);
        *(s16x8*)tmb = *(const s16x8*)(Bp + (size_t)(n0 + row)*600 + k);
      }
      *(s16x8*)&As[row][kcol] = *(const s16x8*)tma;
      *(s16x8*)&Bs[row][kcol] = *(const s16x8*)tmb;
    }
    __syncthreads();
    s16x8 af[4], bf[4];
#pragma unroll
    for (int mi = 0; mi < 4; ++mi) af[mi] = *(const s16x8*)&As[wm + mi*16 + lr][lq << 3];
#pragma unroll
    for (int ni = 0; ni < 4; ++ni) bf[ni] = *(const s16x8*)&Bs[wn + ni*16 + lr][lq << 3];
#pragma unroll
    for (int mi = 0; mi < 4; ++mi)
#pragma unroll
      for (int ni = 0; ni < 4; ++ni)
        acc[mi][ni] = __builtin_amdgcn_mfma_f32_16x16x32_bf16(af[mi], bf[ni], acc[mi][ni], 0, 0, 0);
    __syncthreads();
  }
#pragma unroll
  for (int mi = 0; mi < 4; ++mi){
    const int m = m0 + wm + mi*16 + (lq << 2);
#pragma unroll
    for (int ni = 0; ni < 4; ++ni){
      const int n = n0 + wn + ni*16 + lr;
#pragma unroll
      for (int reg = 0; reg < 4; ++reg)
        C[(size_t)(m + reg)*256 + n] = acc[mi][ni][reg];
    }
  }
}

// ---------------- MFMA GEMM: pc = relu([u,A,u-A,u*A] @ projW^T + projB) ----------------
__global__ __launch_bounds__(256) void k_mm_proj(
    const u16* __restrict__ U, const u16* __restrict__ ATT,
    const u16* __restrict__ Bw,                // projW bf16 [300][2400]
    const float* __restrict__ bias,
    u16* __restrict__ C)
{
  __shared__ u16 As[128][40];
  __shared__ u16 Bs[128][40];
  const int tid = threadIdx.x;
  const int m0 = blockIdx.y << 7;
  const int n0 = blockIdx.x << 7;
  const int srow0 = tid >> 2;
  const int kcol = (tid & 3) << 3;
  const int wv = tid >> 6;
  const int wm = (wv >> 1) << 6, wn = (wv & 1) << 6;
  const int lq = (tid >> 4) & 3;
  const int lr = tid & 15;
  fx4 acc[4][4];
#pragma unroll
  for (int i = 0; i < 4; ++i)
#pragma unroll
    for (int j = 0; j < 4; ++j) acc[i][j] = (fx4){0.f,0.f,0.f,0.f};

  for (int kt = 0; kt < 75; ++kt){
    const int k = (kt << 5) + kcol;
    const int seg = k / 600;
    const int off = k - seg*600;
#pragma unroll
    for (int p = 0; p < 2; ++p){
      const int row = srow0 + (p << 6);
      const size_t base = (size_t)(m0 + row)*600 + off;
      u16 uu8[8], aa8[8], tma[8];
      *(s16x8*)uu8 = *(const s16x8*)(U + base);
      *(s16x8*)aa8 = *(const s16x8*)(ATT + base);
      if (seg == 0){
#pragma unroll
        for (int j = 0; j < 8; ++j) tma[j] = uu8[j];
      } else if (seg == 1){
#pragma unroll
        for (int j = 0; j < 8; ++j) tma[j] = aa8[j];
      } else if (seg == 2){
#pragma unroll
        for (int j = 0; j < 8; ++j) tma[j] = f2us(us2f(uu8[j]) - us2f(aa8[j]));
      } else {
#pragma unroll
        for (int j = 0; j < 8; ++j) tma[j] = f2us(us2f(uu8[j]) * us2f(aa8[j]));
      }
      *(s16x8*)&As[row][kcol] = *(const s16x8*)tma;

      const int n = n0 + row;
      u16 tmb[8] = {0,0,0,0,0,0,0,0};
      if (n < 300)
        *(s16x8*)tmb = *(const s16x8*)(Bw + (size_t)n*2400 + k);
      *(s16x8*)&Bs[row][kcol] = *(const s16x8*)tmb;
    }
    __syncthreads();
    s16x8 af[4], bf[4];
#pragma unroll
    for (int mi = 0; mi < 4; ++mi) af[mi] = *(const s16x8*)&As[wm + mi*16 + lr][lq << 3];
#pragma unroll
    for (int ni = 0; ni < 4; ++ni) bf[ni] = *(const s16x8*)&Bs[wn + ni*16 + lr][lq << 3];
#pragma unroll
    for (int mi = 0; mi < 4; ++mi)
#pragma unroll
      for (int ni = 0; ni < 4; ++ni)
        acc[mi][ni] = __builtin_amdgcn_mfma_f32_16x16x32_bf16(af[mi], bf[ni], acc[mi][ni], 0, 0, 0);
    __syncthreads();
  }
#pragma unroll
  for (int ni = 0; ni < 4; ++ni){
    const int n = n0 + wn + ni*16 + lr;
    if (n < 300){
      const float bs = bias[n];
#pragma unroll
      for (int mi = 0; mi < 4; ++mi){
        const int m = m0 + wm + mi*16 + (lq << 2);
#pragma unroll
        for (int reg = 0; reg < 4; ++reg)
          C[(size_t)(m + reg)*300 + n] = f2us(fmaxf(acc[mi][ni][reg] + bs, 0.0f));
      }
    }
  }
}

// ---------------- MFMA streaming scan (global_load_lds weight ring): 64 WGs x 512 thr ----------------
// 8 samples x 1 dir per WG. Per-wave LDS ring: 2 bufs x 5 frags x 1KB; counted vmcnt(5).
__global__ __launch_bounds__(512) void k_scan_mf(
    const u16* __restrict__ xp,                // [2][8192][1200] bf16 (chunk-gathered)
    const u16* __restrict__ packF, const u16* __restrict__ packB, // [80][10][64][8]
    const int* __restrict__ l1, const int* __restrict__ l2,
    u16* __restrict__ uo,                      // [65536][600] bf16
    u16* __restrict__ hG, float* __restrict__ cG,  // [2][256][328] bf16 ; [2][256][304] f32
    int c)
{
  __shared__ u16 h_s[16][328];                 // rows 8..15 stay zero (MFMA M=16 padding)
  __shared__ float c_s[8][304];
  __shared__ float gs[8][1200];
  __shared__ u16 xstage[8][1200];
  __shared__ u16 wring[8][2][5][512];          // [wave][buf][frag][1KB]
  __shared__ int L_s[8];
  const int bid = blockIdx.x;                  // 64
  const int dir = bid & 1, sg = bid >> 1;      // sg 0..31
  const int r0 = sg << 3;
  const u16* pack = dir ? packB : packF;
  const u16* xpd = xp + (size_t)dir*9830400;
  const int tid = threadIdx.x;
  if (tid < 8) L_s[tid] = (r0 + tid < 128) ? l1[r0 + tid] : l2[r0 + tid - 128];
  for (int i = tid; i < 16*328; i += 512){
    const int q = i / 328, d = i - q*328;
    u16 v = 0;
    if (q < 8 && c > 0) v = hG[(size_t)(dir*256 + r0 + q)*328 + d];
    h_s[q][d] = v;
  }
  for (int i = tid; i < 8*304; i += 512){
    const int q = i / 304, d = i - q*304;
    c_s[q][d] = (c > 0) ? cG[(size_t)(dir*256 + r0 + q)*304 + d] : 0.0f;
  }
  const int w = tid >> 6, lane = tid & 63;
  const int lq = lane >> 4, lr = lane & 15;
  const int tile0 = w * 10;
  const u16* pw = pack + (size_t)tile0*5120;   // wave's 100 contiguous fragments

  // xp staging map: 1200 s16x8-groups over 512 threads (3 per thread max)
  int xq[3], xc[3]; bool xv[3];
#pragma unroll
  for (int j = 0; j < 3; ++j){
    const int i = tid + (j << 9);
    xv[j] = (i < 1200);
    const int qq = (i < 1200) ? (i / 150) : 0;
    xq[j] = qq;
    xc[j] = (i - qq*150) * 8;
  }
  // stage xp for step 0
#pragma unroll
  for (int j = 0; j < 3; ++j){
    if (xv[j]){
      s16x8 v = *(const s16x8*)(xpd + (size_t)((r0 + xq[j])*32 + 0)*1200 + xc[j]);
      *(s16x8*)&xstage[xq[j]][xc[j]] = v;
    }
  }
  __syncthreads();
  int Lmax = 0;
#pragma unroll
  for (int q = 0; q < 8; ++q) Lmax = max(Lmax, L_s[q]);
  const int t0 = c << 5;
  int nts = Lmax - t0; if (nts > 32) nts = 32;
  if (nts <= 0) return;

  // weight ring issue: phase ph -> buf=ph&1, kt=ph>>1, half=ph&1
#define WISSUE(PH)                                                                       \
  {                                                                                      \
    const int buf_ = (PH) & 1, kt_ = (PH) >> 1, hh_ = (PH) & 1;                          \
    _Pragma("unroll")                                                                    \
    for (int nt2 = 0; nt2 < 5; ++nt2){                                                   \
      const u16* ga = pw + ((size_t)((hh_*5 + nt2)*10 + kt_))*512 + (size_t)lane*8;      \
      __builtin_amdgcn_global_load_lds(                                                  \
        (const __attribute__((address_space(1))) void*)ga,                               \
        (__attribute__((address_space(3))) void*)&wring[w][buf_][nt2][0], 16, 0, 0);     \
    }                                                                                    \
  }

  // prologue: fill both ring buffers (phases 0 and 1)
  WISSUE(0)
  WISSUE(1)

  for (int tl = 0; tl < nts; ++tl){
    const int t = t0 + tl;
    const bool pf = (tl + 1 < nts);
    // prefetch next step's xp into regs (consumed after nonlinearity barrier)
    s16x8 xr0, xr1, xr2;
    if (pf){
      if (xv[0]) xr0 = *(const s16x8*)(xpd + (size_t)((r0 + xq[0])*32 + tl + 1)*1200 + xc[0]);
      if (xv[1]) xr1 = *(const s16x8*)(xpd + (size_t)((r0 + xq[1])*32 + tl + 1)*1200 + xc[1]);
      if (xv[2]) xr2 = *(const s16x8*)(xpd + (size_t)((r0 + xq[2])*32 + tl + 1)*1200 + xc[2]);
    }
    fx4 acc[10];
#pragma unroll
    for (int nt = 0; nt < 10; ++nt) acc[nt] = (fx4){0.f,0.f,0.f,0.f};

#pragma unroll
    for (int ph = 0; ph < 20; ++ph){
      const int kt = ph >> 1, hh = ph & 1, buf = ph & 1;
      // wait for this phase's 5 fragments (vmcnt retires in issue order; the only
      // newer ops are the next phase's 5 loads -> vmcnt(5) is always safe)
      asm volatile("s_waitcnt vmcnt(5)" ::: "memory");
      __builtin_amdgcn_sched_barrier(0);
      const s16x8 a = *(const s16x8*)&h_s[lr][kt*32 + (lq << 3)];
      s16x8 b0 = *(const s16x8*)&wring[w][buf][0][lane*8];
      s16x8 b1 = *(const s16x8*)&wring[w][buf][1][lane*8];
      s16x8 b2 = *(const s16x8*)&wring[w][buf][2][lane*8];
      s16x8 b3 = *(const s16x8*)&wring[w][buf][3][lane*8];
      s16x8 b4 = *(const s16x8*)&wring[w][buf][4][lane*8];
      acc[hh*5+0] = __builtin_amdgcn_mfma_f32_16x16x32_bf16(a, b0, acc[hh*5+0], 0, 0, 0);
      acc[hh*5+1] = __builtin_amdgcn_mfma_f32_16x16x32_bf16(a, b1, acc[hh*5+1], 0, 0, 0);
      acc[hh*5+2] = __builtin_amdgcn_mfma_f32_16x16x32_bf16(a, b2, acc[hh*5+2], 0, 0, 0);
      acc[hh*5+3] = __builtin_amdgcn_mfma_f32_16x16x32_bf16(a, b3, acc[hh*5+3], 0, 0, 0);
      acc[hh*5+4] = __builtin_amdgcn_mfma_f32_16x16x32_bf16(a, b4, acc[hh*5+4], 0, 0, 0);
      // ds_reads complete before reusing the buffer for the next-next phase
      asm volatile("s_waitcnt lgkmcnt(0)" ::: "memory");
      __builtin_amdgcn_sched_barrier(0);
      WISSUE((ph + 2) % 20)                    // wraps to next step (weights step-invariant)
    }
    // acc -> gs (valid output rows m<8)
    if (lq < 2){
#pragma unroll
      for (int nt = 0; nt < 10; ++nt){
        const int n = (tile0 + nt)*16 + lr;
        if (n < 1200){
#pragma unroll
          for (int reg = 0; reg < 4; ++reg)
            gs[(lq << 2) + reg][n] = acc[nt][reg];
        }
      }
    }
    __syncthreads();
    // nonlinearity + state update + output (gate = gs + xstage)
#pragma unroll
    for (int j = 0; j < 5; ++j){
      const int u0 = tid + (j << 9);
      if (u0 < 2400){
        const int q = u0 / 300, d = u0 - q*300;
        const int L = L_s[q];
        if (t < L){
          const float gi = gs[q][d]       + us2f(xstage[q][d]);
          const float gf = gs[q][300 + d] + us2f(xstage[q][300 + d]);
          const float gg = gs[q][600 + d] + us2f(xstage[q][600 + d]);
          const float go = gs[q][900 + d] + us2f(xstage[q][900 + d]);
          const float cn = sigmf(gf)*c_s[q][d] + sigmf(gi)*tanhfast(gg);
          const float hn = sigmf(go)*tanhfast(cn);
          c_s[q][d] = cn;
          const u16 hb = f2us(hn);
          h_s[q][d] = hb;
          const int wpos = dir ? (L-1-t) : t;
          uo[(size_t)((r0 + q)*256 + wpos)*600 + dir*300 + d] = hb;
        }
      }
    }
    __syncthreads();
    // write prefetched xp regs into xstage for step tl+1
    if (pf){
      if (xv[0]) *(s16x8*)&xstage[xq[0]][xc[0]] = xr0;
      if (xv[1]) *(s16x8*)&xstage[xq[1]][xc[1]] = xr1;
      if (xv[2]) *(s16x8*)&xstage[xq[2]][xc[2]] = xr2;
    }
  }
#undef WISSUE
  // persist state
  for (int i = tid; i < 8*328; i += 512){
    const int q = i / 328, d = i - q*328;
    hG[(size_t)(dir*256 + r0 + q)*328 + d] = h_s[q][d];
  }
  for (int i = tid; i < 8*304; i += 512){
    const int q = i / 304, d = i - q*304;
    cG[(size_t)(dir*256 + r0 + q)*304 + d] = c_s[q][d];
  }
}

// ---------------- softmax stats ----------------
__global__ __launch_bounds__(256) void k_row_stats(const float* __restrict__ S, const int* __restrict__ l2,
                                                   float* __restrict__ rmax, float* __restrict__ rinv)
{
  const int wid = threadIdx.x >> 6, lane = threadIdx.x & 63;
  const int row = blockIdx.x*4 + wid;
  const int b = row >> 8;
  const int L2b = l2[b];
  float4 v = *(const float4*)(S + (size_t)row*256 + lane*4);
  const int j = lane*4;
  float m = -INFINITY;
  if (j   < L2b) m = fmaxf(m, v.x);
  if (j+1 < L2b) m = fmaxf(m, v.y);
  if (j+2 < L2b) m = fmaxf(m, v.z);
  if (j+3 < L2b) m = fmaxf(m, v.w);
  for (int off = 32; off; off >>= 1) m = fmaxf(m, __shfl_xor(m, off));
  float s = 0.f;
  if (j   < L2b) s += __expf(v.x - m);
  if (j+1 < L2b) s += __expf(v.y - m);
  if (j+2 < L2b) s += __expf(v.z - m);
  if (j+3 < L2b) s += __expf(v.w - m);
  for (int off = 32; off; off >>= 1) s += __shfl_xor(s, off);
  if (lane == 0){ rmax[row] = m; rinv[row] = 1.0f/s; }
}

__global__ __launch_bounds__(256) void k_col_stats(const float* __restrict__ S, const int* __restrict__ l1,
                                                   float* __restrict__ cmax, float* __restrict__ cinv)
{
  const int b = blockIdx.x;
  const int j = threadIdx.x;
  const int L1b = l1[b];
  const float* Sb = S + (size_t)b*65536;
  float m = -INFINITY;
  for (int i = 0; i < L1b; ++i) m = fmaxf(m, Sb[(size_t)i*256 + j]);
  float s = 0.f;
  for (int i = 0; i < L1b; ++i) s += __expf(Sb[(size_t)i*256 + j] - m);
  cmax[b*256 + j] = m;
  cinv[b*256 + j] = 1.0f/s;
}

// ---------------- A1 = softmax_rows(S) @ u2 -> att bf16 ----------------
__global__ __launch_bounds__(256) void k_av_row(
    const float* __restrict__ S, const u16* __restrict__ U,
    const int* __restrict__ l1, const int* __restrict__ l2,
    const float* __restrict__ rmax, const float* __restrict__ rinv,
    u16* __restrict__ ATT)
{
  __shared__ float Ps[32][68];
  __shared__ float Us[32][68];
  const int tid = threadIdx.x;
  const int b = blockIdx.z;
  const int i0 = blockIdx.y << 6;
  const int d0 = blockIdx.x << 6;
  const int L1b = l1[b], L2b = l2[b];
  const float* Sb = S + (size_t)b*65536;
  const u16* u2 = U + (size_t)(128+b)*153600;
  const int tx = tid & 15, ty = tid >> 4;
  float acc[4][4];
#pragma unroll
  for (int i = 0; i < 4; ++i)
#pragma unroll
    for (int j = 0; j < 4; ++j) acc[i][j] = 0.0f;

  for (int kt = 0; kt < 8; ++kt){
    const int j0 = kt << 5;
#pragma unroll
    for (int q = 0; q < 2; ++q){
      const int f4 = tid + (q << 8);
      {
        const int row = f4 >> 3;
        const int c4 = (f4 & 7) << 2;
        const int i = i0 + row;
        float4 s4 = *(const float4*)(Sb + (size_t)i*256 + j0 + c4);
        const float rm = rmax[(b<<8) + i];
        const float ri = rinv[(b<<8) + i];
        const int jb = j0 + c4;
        Ps[c4  ][row] = (jb   < L2b) ? __expf(s4.x - rm)*ri : 0.0f;
        Ps[c4+1][row] = (jb+1 < L2b) ? __expf(s4.y - rm)*ri : 0.0f;
        Ps[c4+2][row] = (jb+2 < L2b) ? __expf(s4.z - rm)*ri : 0.0f;
        Ps[c4+3][row] = (jb+3 < L2b) ? __expf(s4.w - rm)*ri : 0.0f;
      }
      {
        const int row = f4 >> 4;
        const int c4 = (f4 & 15) << 2;
        const int d = d0 + c4;
        float4 v = make_float4(0.f,0.f,0.f,0.f);
        if (j0 + row < L2b){
          const u16* up = u2 + (size_t)(j0+row)*600 + d;
          if (d + 3 < 600){
            ushort4 t4 = *(const ushort4*)up;
            v.x=us2f(t4.x); v.y=us2f(t4.y); v.z=us2f(t4.z); v.w=us2f(t4.w);
          } else {
            if (d   < 600) v.x = us2f(up[0]);
            if (d+1 < 600) v.y = us2f(up[1]);
            if (d+2 < 600) v.z = us2f(up[2]);
          }
        }
        *(float4*)&Us[row][c4] = v;
      }
    }
    __syncthreads();
#pragma unroll
    for (int kk = 0; kk < 32; ++kk){
      float4 a = *(const float4*)&Ps[kk][ty<<2];
      float4 bb = *(const float4*)&Us[kk][tx<<2];
      float av[4] = {a.x,a.y,a.z,a.w};
      float bv[4] = {bb.x,bb.y,bb.z,bb.w};
#pragma unroll
      for (int ii = 0; ii < 4; ++ii)
#pragma unroll
        for (int jj = 0; jj < 4; ++jj)
          acc[ii][jj] = fmaf(av[ii], bv[jj], acc[ii][jj]);
    }
    __syncthreads();
  }
#pragma unroll
  for (int ii = 0; ii < 4; ++ii){
    const int i = i0 + (ty<<2) + ii;
#pragma unroll
    for (int jj = 0; jj < 4; ++jj){
      const int d = d0 + (tx<<2) + jj;
      if (d < 600)
        ATT[(size_t)b*153600 + (size_t)i*600 + d] = f2us((i < L1b) ? acc[ii][jj] : 0.0f);
    }
  }
}

// ---------------- A2 = softmax_cols(S)^T @ u1 -> att bf16 ----------------
__global__ __launch_bounds__(256) void k_av_col(
    const float* __restrict__ S, const u16* __restrict__ U,
    const int* __restrict__ l1, const int* __restrict__ l2,
    const float* __restrict__ cmax, const float* __restrict__ cinv,
    u16* __restrict__ ATT)
{
  __shared__ float Ps[32][68];
  __shared__ float Us[32][68];
  const int tid = threadIdx.x;
  const int b = blockIdx.z;
  const int j0v = blockIdx.y << 6;
  const int d0 = blockIdx.x << 6;
  const int L1b = l1[b], L2b = l2[b];
  const float* Sb = S + (size_t)b*65536;
  const u16* u1 = U + (size_t)b*153600;
  const int tx = tid & 15, ty = tid >> 4;
  float acc[4][4];
#pragma unroll
  for (int i = 0; i < 4; ++i)
#pragma unroll
    for (int j = 0; j < 4; ++j) acc[i][j] = 0.0f;

  for (int kt = 0; kt < 8; ++kt){
    const int i0k = kt << 5;
#pragma unroll
    for (int q = 0; q < 2; ++q){
      const int f4 = tid + (q << 8);
      const int row = f4 >> 4;
      const int c4 = (f4 & 15) << 2;
      {
        const int i = i0k + row;
        const int j = j0v + c4;
        float4 s4 = *(const float4*)(Sb + (size_t)i*256 + j);
        const bool iok = i < L1b;
        Ps[row][c4  ] = iok ? __expf(s4.x - cmax[(b<<8)+j  ])*cinv[(b<<8)+j  ] : 0.0f;
        Ps[row][c4+1] = iok ? __expf(s4.y - cmax[(b<<8)+j+1])*cinv[(b<<8)+j+1] : 0.0f;
        Ps[row][c4+2] = iok ? __expf(s4.z - cmax[(b<<8)+j+2])*cinv[(b<<8)+j+2] : 0.0f;
        Ps[row][c4+3] = iok ? __expf(s4.w - cmax[(b<<8)+j+3])*cinv[(b<<8)+j+3] : 0.0f;
      }
      {
        const int d = d0 + c4;
        float4 v = make_float4(0.f,0.f,0.f,0.f);
        if (i0k + row < L1b){
          const u16* up = u1 + (size_t)(i0k+row)*600 + d;
          if (d + 3 < 600){
            ushort4 t4 = *(const ushort4*)up;
            v.x=us2f(t4.x); v.y=us2f(t4.y); v.z=us2f(t4.z); v.w=us2f(t4.w);
          } else {
            if (d   < 600) v.x = us2f(up[0]);
            if (d+1 < 600) v.y = us2f(up[1]);
            if (d+2 < 600) v.z = us2f(up[2]);
          }
        }
        *(float4*)&Us[row][c4] = v;
      }
    }
    __syncthreads();
#pragma unroll
    for (int kk = 0; kk < 32; ++kk){
      float4 a = *(const float4*)&Ps[kk][ty<<2];
      float4 bb = *(const float4*)&Us[kk][tx<<2];
      float av[4] = {a.x,a.y,a.z,a.w};
      float bv[4] = {bb.x,bb.y,bb.z,bb.w};
#pragma unroll
      for (int ii = 0; ii < 4; ++ii)
#pragma unroll
        for (int jj = 0; jj < 4; ++jj)
          acc[ii][jj] = fmaf(av[ii], bv[jj], acc[ii][jj]);
    }
    __syncthreads();
  }
#pragma unroll
  for (int ii = 0; ii < 4; ++ii){
    const int j = j0v + (ty<<2) + ii;
#pragma unroll
    for (int jj = 0; jj < 4; ++jj){
      const int d = d0 + (tx<<2) + jj;
      if (d < 600)
        ATT[(size_t)(128+b)*153600 + (size_t)j*600 + d] = f2us((j < L2b) ? acc[ii][jj] : 0.0f);
    }
  }
}

// ---------------- masked max over time + feature build ----------------
__global__ __launch_bounds__(256) void k_maxfeat(const u16* __restrict__ y,
                                                 const int* __restrict__ l1, const int* __restrict__ l2,
                                                 float* __restrict__ feat)
{
  const int b = blockIdx.x;
  const int La = l1[b], Lb = l2[b];
  for (int c = threadIdx.x; c < 600; c += 256){
    float m1 = -INFINITY, m2 = -INFINITY;
    const u16* y1 = y + (size_t)b*153600 + c;
    for (int t = 0; t < La; ++t) m1 = fmaxf(m1, us2f(y1[(size_t)t*600]));
    const u16* y2 = y + (size_t)(128+b)*153600 + c;
    for (int t = 0; t < Lb; ++t) m2 = fmaxf(m2, us2f(y2[(size_t)t*600]));
    feat[(size_t)b*2400 + c]        = m1;
    feat[(size_t)b*2400 + 600 + c]  = m2;
    feat[(size_t)b*2400 + 1200 + c] = fabsf(m1 - m2);
    feat[(size_t)b*2400 + 1800 + c] = m1*m2;
  }
}

// ---------------- per-row MLP ----------------
__global__ __launch_bounds__(256) void k_rowgemm(const float* __restrict__ feat, const float* __restrict__ W,
                                                 const float* __restrict__ bias, float* __restrict__ out)
{
  const int b = blockIdx.x;
  __shared__ float ff[2400];
  for (int i = threadIdx.x; i < 2400; i += 256) ff[i] = feat[(size_t)b*2400 + i];
  __syncthreads();
  for (int n = threadIdx.x; n < 300; n += 256){
    const float* w = W + (size_t)n*2400;
    float acc = bias[n];
    for (int k = 0; k < 2400; k += 4){
      float4 wv = *(const float4*)(w + k);
      acc += ff[k]*wv.x + ff[k+1]*wv.y + ff[k+2]*wv.z + ff[k+3]*wv.w;
    }
    out[(size_t)b*300 + n] = fmaxf(acc, 0.0f);
  }
}

// ---------------- final ----------------
__global__ __launch_bounds__(192) void k_final(const float* __restrict__ h, const float* __restrict__ smW,
                                               const float* __restrict__ smB, float* __restrict__ out)
{
  const int b = blockIdx.x;
  const int n = threadIdx.x >> 6, lane = threadIdx.x & 63;
  float acc = 0.f;
  for (int k = lane; k < 300; k += 64) acc += h[(size_t)b*300 + k]*smW[(size_t)n*300 + k];
  for (int off = 32; off; off >>= 1) acc += __shfl_xor(acc, off);
  if (lane == 0) out[b*3 + n] = acc + smB[n];
}

extern "C" void kernel_launch(void* const* d_in, const int* in_sizes, int n_in,
                              void* d_out, int out_size, void* d_ws, size_t ws_size,
                              hipStream_t stream)
{
  (void)in_sizes; (void)n_in; (void)out_size;
  static const size_t OFF_P  = 0;             // p bf16 [65536][300]
  static const size_t OFF_B  = 39321600;      // xp1 / Smat / pc
  static const size_t OFF_U  = 78643200;      // uu/y bf16 [65536][600]
  static const size_t OFF_D  = 157286400;     // att / xp2
  static const size_t OFF_WT = 235929600;     // wih bf16 x4 (720000B each)
  static const size_t OFF_PJ = 238809600;     // projW bf16 (1440000B)
  static const size_t OFF_PK = 240249600;     // W_pack x4 (819200B each)
  static const size_t OFF_ST = 243526400;     // stats 4x32768 f32
  static const size_t OFF_FE = 244050688;     // feat
  static const size_t OFF_HM = 245279488;     // hml
  static const size_t OFF_HC = 245433088;     // hG bf16 (335872) + cG f32 (622592)
  static const size_t WS_NEEDED = 246391552;
  if (ws_size < WS_NEEDED) return;

  const int* s1 = (const int*)d_in[0];
  const int* l1 = (const int*)d_in[1];
  const int* s2 = (const int*)d_in[2];
  const int* l2 = (const int*)d_in[3];
  const float* emb    = (const float*)d_in[4];
  const float* w1f_ih = (const float*)d_in[5];
  const float* w1f_hh = (const float*)d_in[6];
  const float* b1f_ih = (const float*)d_in[7];
  const float* b1f_hh = (const float*)d_in[8];
  const float* w1b_ih = (const float*)d_in[9];
  const float* w1b_hh = (const float*)d_in[10];
  const float* b1b_ih = (const float*)d_in[11];
  const float* b1b_hh = (const float*)d_in[12];
  const float* w2f_ih = (const float*)d_in[13];
  const float* w2f_hh = (const float*)d_in[14];
  const float* b2f_ih = (const float*)d_in[15];
  const float* b2f_hh = (const float*)d_in[16];
  const float* w2b_ih = (const float*)d_in[17];
  const float* w2b_hh = (const float*)d_in[18];
  const float* b2b_ih = (const float*)d_in[19];
  const float* b2b_hh = (const float*)d_in[20];
  const float* projW  = (const float*)d_in[21];
  const float* projB  = (const float*)d_in[22];
  const float* mlpW   = (const float*)d_in[23];
  const float* mlpB   = (const float*)d_in[24];
  const float* smW    = (const float*)d_in[25];
  const float* smB    = (const float*)d_in[26];

  char* ws = (char*)d_ws;
  u16*   p    = (u16*)(ws + OFF_P);
  u16*   xp1  = (u16*)(ws + OFF_B);
  float* Smat = (float*)(ws + OFF_B);
  u16*   pc   = (u16*)(ws + OFF_B);
  u16*   uu   = (u16*)(ws + OFF_U);
  u16*   att  = (u16*)(ws + OFF_D);
  u16*   xp2  = (u16*)(ws + OFF_D);
  u16*   wih  = (u16*)(ws + OFF_WT);
  u16*   pjw  = (u16*)(ws + OFF_PJ);
  u16*   pk   = (u16*)(ws + OFF_PK);
  float* st   = (float*)(ws + OFF_ST);
  float* feat = (float*)(ws + OFF_FE);
  float* hml  = (float*)(ws + OFF_HM);
  u16*   hG   = (u16*)(ws + OFF_HC);
  float* cG   = (float*)(ws + OFF_HC + 335872);

  k_embed<<<19200, 256, 0, stream>>>(s1, s2, emb, p);
  k_cvt<<<1407, 256, 0, stream>>>(w1f_ih, wih,           360000);
  k_cvt<<<1407, 256, 0, stream>>>(w1b_ih, wih + 360000,  360000);
  k_cvt<<<1407, 256, 0, stream>>>(w2f_ih, wih + 720000,  360000);
  k_cvt<<<1407, 256, 0, stream>>>(w2b_ih, wih + 1080000, 360000);
  k_cvt<<<2813, 256, 0, stream>>>(projW,  pjw,           720000);
  k_pack<<<200, 256, 0, stream>>>(w1f_hh, pk);
  k_pack<<<200, 256, 0, stream>>>(w1b_hh, pk + 409600);
  k_pack<<<200, 256, 0, stream>>>(w2f_hh, pk + 819200);
  k_pack<<<200, 256, 0, stream>>>(w2b_hh, pk + 1228800);

  const dim3 gxp(10, 64, 2);
  for (int c = 0; c < 8; ++c){
    k_mm_xpc<<<gxp, 256, 0, stream>>>(p, wih, wih + 360000, b1f_ih, b1f_hh, b1b_ih, b1b_hh,
                                      l1, l2, xp1, c);
    k_scan_mf<<<64, 512, 0, stream>>>(xp1, pk, pk + 409600, l1, l2, uu, hG, cG, c);
  }

  k_mm_s<<<dim3(2,2,128), 256, 0, stream>>>(uu, Smat);
  k_row_stats<<<8192, 256, 0, stream>>>(Smat, l2, st, st + 32768);
  k_col_stats<<<128, 256, 0, stream>>>(Smat, l1, st + 65536, st + 98304);
  k_av_row<<<dim3(10,4,128), 256, 0, stream>>>(Smat, uu, l1, l2, st, st + 32768, att);
  k_av_col<<<dim3(10,4,128), 256, 0, stream>>>(Smat, uu, l1, l2, st + 65536, st + 98304, att);

  k_mm_proj<<<dim3(3,512,1), 256, 0, stream>>>(uu, att, pjw, projB, pc);

  for (int c = 0; c < 8; ++c){
    k_mm_xpc<<<gxp, 256, 0, stream>>>(pc, wih + 720000, wih + 1080000, b2f_ih, b2f_hh, b2b_ih, b2b_hh,
                                      l1, l2, xp2, c);
    k_scan_mf<<<64, 512, 0, stream>>>(xp2, pk + 819200, pk + 1228800, l1, l2, uu, hG, cG, c);
  }

  k_maxfeat<<<128, 256, 0, stream>>>(uu, l1, l2, feat);
  k_rowgemm<<<128, 256, 0, stream>>>(feat, mlpW, mlpB, hml);
  k_final<<<128, 192, 0, stream>>>(hml, smW, smB, (float*)d_out);
}